// Round 3
// baseline (687.255 us; speedup 1.0000x reference)
//
#include <hip/hip_runtime.h>
#include <hip/hip_bf16.h>
#include <cstdint>

// ============================================================================
// Hybrid e2e STN pipeline, round 3:
//  - global_load_lds (16B) staged MFMA GEMMs (m97 structure)
//  - implicit-im2col conv GEMM reading bf16 image directly
//  - attention: q/k-split, broadcast K/V loads, no-max softmax, LDS combine
// ============================================================================

#define B_    16
#define HH    512
#define WW    512
#define NF_   1024
#define EMB_  768
#define HEADS_ 12
#define NTOK  256
#define M_    (B_*NTOK)      // 4096
#define KCONV 3072

typedef __bf16 bf16_t;
typedef __bf16 bf16x8 __attribute__((ext_vector_type(8)));
typedef float  f32x4  __attribute__((ext_vector_type(4)));

typedef __attribute__((address_space(1))) const void* gas_t;
typedef __attribute__((address_space(3))) void* las_t;

__device__ __forceinline__ void gload16(const bf16_t* g, bf16_t* l) {
    __builtin_amdgcn_global_load_lds((gas_t)g, (las_t)l, 16, 0, 0);
}

__device__ __forceinline__ float tanh_fast(float x) {
    return 1.0f - 2.0f / (__expf(2.0f * x) + 1.0f);
}

// ---------------------------------------------------------------------------
// rasterize (verified)
// ---------------------------------------------------------------------------
__global__ __launch_bounds__(128)
void raster_kernel(const float* __restrict__ lm, float* __restrict__ seg) {
    int b = blockIdx.x;
    int s = threadIdx.x;
    if (s >= 117) return;
    int seg0 = (s < 43) ? s : ((s < 92) ? s + 1 : s + 2);
    const float* p = lm + (size_t)b * 240;
    int p1x = min(max((int)(p[seg0*2 + 0] * 512.0f), 0), 511);
    int p1y = min(max((int)(p[seg0*2 + 1] * 512.0f), 0), 511);
    int p2x = min(max((int)(p[(seg0+1)*2 + 0] * 512.0f), 0), 511);
    int p2y = min(max((int)(p[(seg0+1)*2 + 1] * 512.0f), 0), 511);
    int dy = p2y - p1y, dx = p2x - p1x;
    int kmax = min(dy, dx);
    float* sb = seg + (size_t)b * (HH*WW);
    for (int k = 0; k < kmax; ++k) {
        int yi = min(p1y + k, 511);
        int xi = min(p1x + k, 511);
        sb[yi*WW + xi] = 1.0f;
    }
}

// ---------------------------------------------------------------------------
// pool + stn (verified)
// ---------------------------------------------------------------------------
__global__ __launch_bounds__(256)
void pool_kernel(const float* __restrict__ seg, float* __restrict__ pooled) {
    int idx = blockIdx.x * 256 + threadIdx.x;
    int ox = idx & 31, oy = (idx >> 5) & 31, b = idx >> 10;
    const float* sb = seg + (size_t)b * (HH*WW) + (oy*16)*WW + ox*16;
    float s = 0.0f;
    for (int dy = 0; dy < 16; ++dy) {
        #pragma unroll
        for (int dx = 0; dx < 16; ++dx) s += sb[dy*WW + dx];
    }
    pooled[idx] = s * (1.0f/256.0f);
}

__global__ __launch_bounds__(64)
void stn_kernel(const float* __restrict__ pooled,
                const float* __restrict__ w1, const float* __restrict__ b1,
                const float* __restrict__ w2, const float* __restrict__ b2,
                float* __restrict__ theta) {
    __shared__ float pl[1024];
    __shared__ float hl[50];
    int b = blockIdx.x, tid = threadIdx.x;
    for (int i = tid; i < 1024; i += 64) pl[i] = pooled[b*1024 + i];
    __syncthreads();
    if (tid < 50) {
        float acc = b1[tid];
        for (int k = 0; k < 1024; ++k) acc += pl[k] * w1[k*50 + tid];
        hl[tid] = tanhf(acc);
    }
    __syncthreads();
    if (tid < 6) {
        float acc = b2[tid];
        for (int k = 0; k < 50; ++k) acc += hl[k] * w2[k*6 + tid];
        theta[b*6 + tid] = acc;
    }
}

// ---------------------------------------------------------------------------
// fused affine_grid + grid_sample; also emits bf16 copy of transformed img
// ---------------------------------------------------------------------------
__global__ __launch_bounds__(256)
void gridsample_kernel(const float* __restrict__ x, const float* __restrict__ seg,
                       const float* __restrict__ theta,
                       float* __restrict__ timg, float* __restrict__ tmask,
                       bf16_t* __restrict__ timgb) {
    size_t idx = (size_t)blockIdx.x * 256 + threadIdx.x;
    int xx = (int)(idx & 511);
    int yy = (int)((idx >> 9) & 511);
    int b  = (int)(idx >> 18);
    __shared__ float th[6];
    if (threadIdx.x < 6) th[threadIdx.x] = theta[b*6 + threadIdx.x];
    __syncthreads();
    float gx = (2.0f*xx + 1.0f) * (1.0f/512.0f) - 1.0f;
    float gy = (2.0f*yy + 1.0f) * (1.0f/512.0f) - 1.0f;
    float g0 = gx*th[0] + gy*th[1] + th[2];
    float g1 = gx*th[3] + gy*th[4] + th[5];
    float fx = ((g0 + 1.0f)*512.0f - 1.0f)*0.5f;
    float fy = ((g1 + 1.0f)*512.0f - 1.0f)*0.5f;
    float x0f = floorf(fx), y0f = floorf(fy);
    float wx1 = fx - x0f,  wy1 = fy - y0f;
    int ix0 = (int)x0f, iy0 = (int)y0f;
    int ix1 = ix0 + 1,  iy1 = iy0 + 1;
    float fy0ok = (iy0 >= 0 && iy0 < HH) ? 1.0f : 0.0f;
    float fy1ok = (iy1 >= 0 && iy1 < HH) ? 1.0f : 0.0f;
    float fx0ok = (ix0 >= 0 && ix0 < WW) ? 1.0f : 0.0f;
    float fx1ok = (ix1 >= 0 && ix1 < WW) ? 1.0f : 0.0f;
    float w00 = (1.0f-wy1)*(1.0f-wx1) * fy0ok * fx0ok;
    float w01 = (1.0f-wy1)*wx1        * fy0ok * fx1ok;
    float w10 = wy1*(1.0f-wx1)        * fy1ok * fx0ok;
    float w11 = wy1*wx1               * fy1ok * fx1ok;
    int cx0 = min(max(ix0,0),511), cx1 = min(max(ix1,0),511);
    int cy0 = min(max(iy0,0),511), cy1 = min(max(iy1,0),511);
    int i00 = cy0*WW + cx0, i01 = cy0*WW + cx1, i10 = cy1*WW + cx0, i11 = cy1*WW + cx1;
    size_t pix = (size_t)yy*WW + xx;
    #pragma unroll
    for (int c = 0; c < 3; ++c) {
        const float* pl = x + ((size_t)(b*3 + c)) * (HH*WW);
        float v = w00*pl[i00] + w01*pl[i01] + w10*pl[i10] + w11*pl[i11];
        timg [((size_t)(b*3 + c))*(HH*WW) + pix] = v;
        timgb[((size_t)(b*3 + c))*(HH*WW) + pix] = (bf16_t)v;
    }
    const float* sp = seg + (size_t)b * (HH*WW);
    float mv = w00*sp[i00] + w01*sp[i01] + w10*sp[i10] + w11*sp[i11];
    tmask[(size_t)b*(HH*WW) + pix] = mv;
}

// ---------------------------------------------------------------------------
// conversions
// ---------------------------------------------------------------------------
__global__ __launch_bounds__(256)
void convert_bf16_kernel(const float* __restrict__ in, bf16_t* __restrict__ out) {
    int idx = (blockIdx.x * 256 + threadIdx.x) * 8;
    float4 v0 = *reinterpret_cast<const float4*>(in + idx);
    float4 v1 = *reinterpret_cast<const float4*>(in + idx + 4);
    bf16x8 o;
    o[0]=(bf16_t)v0.x; o[1]=(bf16_t)v0.y; o[2]=(bf16_t)v0.z; o[3]=(bf16_t)v0.w;
    o[4]=(bf16_t)v1.x; o[5]=(bf16_t)v1.y; o[6]=(bf16_t)v1.z; o[7]=(bf16_t)v1.w;
    *reinterpret_cast<bf16x8*>(out + idx) = o;
}

__global__ __launch_bounds__(256)
void transpose_bf16_kernel(const float* __restrict__ in, bf16_t* __restrict__ out,
                           int K, int N) {   // in[K][N] -> out[N][K]
    __shared__ float tile[32][33];
    int bk = blockIdx.y * 32, bn = blockIdx.x * 32;
    int r = threadIdx.x >> 5, c = threadIdx.x & 31;
    #pragma unroll
    for (int i = 0; i < 4; ++i)
        tile[r + 8*i][c] = in[(size_t)(bk + r + 8*i) * N + bn + c];
    __syncthreads();
    #pragma unroll
    for (int i = 0; i < 4; ++i)
        out[(size_t)(bn + r + 8*i) * K + bk + c] = (bf16_t)tile[c][r + 8*i];
}

// ---------------------------------------------------------------------------
// bf16 MFMA GEMM (m97 structure): C = A(MxK) * Bt(NxK)^T, fp32 accum.
// 128x128 tile, BK=32, 256 thr = 4 waves (wave: 64x64 = 4x4 16x16 frags).
// Staging via global_load_lds width=16 into LINEAR LDS (lane-order fill).
// ---------------------------------------------------------------------------
enum { EPI_CONV=0, EPI_PE=1, EPI_QKV=2, EPI_PROJ=3, EPI_GELU=4, EPI_MLP2=5 };

template<int EPI>
__device__ __forceinline__ void gemm_epilogue(
        f32x4 (&acc)[4][4], const float* bias, const float* extra,
        float* Cf, bf16_t* Cb, int bm, int bn, int wm, int wn,
        int rr, int g, int N) {
    #pragma unroll
    for (int i = 0; i < 4; ++i) {
        #pragma unroll
        for (int j = 0; j < 4; ++j) {
            #pragma unroll
            for (int r = 0; r < 4; ++r) {
                int m = bm + wm + i*16 + g*4 + r;
                int n = bn + wn + j*16 + rr;
                size_t o = (size_t)m * N + n;
                float v = acc[i][j][r] + bias[n];
                if (EPI == EPI_CONV) {
                    Cb[o] = (bf16_t)fmaxf(v, 0.0f);
                } else if (EPI == EPI_PE) {
                    Cf[o] = v + extra[(size_t)(m & 255)*N + n];
                } else if (EPI == EPI_QKV) {
                    Cb[o] = (bf16_t)v;
                } else if (EPI == EPI_PROJ || EPI == EPI_MLP2) {
                    Cf[o] = v + Cf[o];
                } else if (EPI == EPI_GELU) {
                    float u = v;
                    float gl = 0.5f*u*(1.0f + tanh_fast(0.7978845608028654f*(u + 0.044715f*u*u*u)));
                    Cb[o] = (bf16_t)gl;
                }
            }
        }
    }
}

template<int EPI>
__global__ __launch_bounds__(256)
void gemm_bf16_kernel(const bf16_t* __restrict__ A, const bf16_t* __restrict__ Bt,
                      const float* __restrict__ bias, const float* __restrict__ extra,
                      float* __restrict__ Cf, bf16_t* __restrict__ Cb,
                      int M, int N, int K) {
    __shared__ __align__(16) bf16_t As[128*32];
    __shared__ __align__(16) bf16_t Bs[128*32];
    const int tid = threadIdx.x;
    const int bm = blockIdx.y * 128, bn = blockIdx.x * 128;
    const int lane = tid & 63, w = tid >> 6;
    const int rr = lane & 15, g = lane >> 4;
    const int wm = (w & 1) * 64, wn = (w >> 1) * 64;
    const int srow = w*16 + (lane >> 2);
    const int scol = (lane & 3) * 8;
    const bf16_t* gA0 = A  + (size_t)(bm + srow)      * K + scol;
    const bf16_t* gA1 = A  + (size_t)(bm + 64 + srow) * K + scol;
    const bf16_t* gB0 = Bt + (size_t)(bn + srow)      * K + scol;
    const bf16_t* gB1 = Bt + (size_t)(bn + 64 + srow) * K + scol;
    bf16_t* lA0 = As + (w*16)*32;
    bf16_t* lA1 = As + (64 + w*16)*32;
    bf16_t* lB0 = Bs + (w*16)*32;
    bf16_t* lB1 = Bs + (64 + w*16)*32;
    f32x4 acc[4][4] = {};
    for (int k0 = 0; k0 < K; k0 += 32) {
        gload16(gA0 + k0, lA0);
        gload16(gA1 + k0, lA1);
        gload16(gB0 + k0, lB0);
        gload16(gB1 + k0, lB1);
        __syncthreads();
        bf16x8 af[4], bfr[4];
        #pragma unroll
        for (int i = 0; i < 4; ++i) {
            af[i]  = *reinterpret_cast<const bf16x8*>(As + (wm + i*16 + rr)*32 + g*8);
            bfr[i] = *reinterpret_cast<const bf16x8*>(Bs + (wn + i*16 + rr)*32 + g*8);
        }
        #pragma unroll
        for (int i = 0; i < 4; ++i)
            #pragma unroll
            for (int j = 0; j < 4; ++j)
                acc[i][j] = __builtin_amdgcn_mfma_f32_16x16x32_bf16(af[i], bfr[j], acc[i][j], 0, 0, 0);
        __syncthreads();
    }
    gemm_epilogue<EPI>(acc, bias, extra, Cf, Cb, bm, bn, wm, wn, rr, g, N);
}

// conv GEMM: implicit im2col from bf16 image. M=4096,N=1024,K=3072.
// k = c*1024 + ky*32 + kx  ->  timgb[b][c][py*32+ky][px*32+kx], 64B-contig rows.
__global__ __launch_bounds__(256)
void gemm_conv_kernel(const bf16_t* __restrict__ timgb, const bf16_t* __restrict__ Bt,
                      const float* __restrict__ bias, bf16_t* __restrict__ Cb) {
    const int N = NF_, K = KCONV;
    __shared__ __align__(16) bf16_t As[128*32];
    __shared__ __align__(16) bf16_t Bs[128*32];
    const int tid = threadIdx.x;
    const int bm = blockIdx.y * 128, bn = blockIdx.x * 128;
    const int lane = tid & 63, w = tid >> 6;
    const int rr = lane & 15, g = lane >> 4;
    const int wm = (w & 1) * 64, wn = (w >> 1) * 64;
    const int srow = w*16 + (lane >> 2);
    const int scol = (lane & 3) * 8;
    // per-lane invariant image offsets for rows bm+srow and bm+64+srow
    int row0 = bm + srow, row1 = bm + 64 + srow;
    int b0 = row0 >> 8, py0 = (row0 >> 4) & 15, px0 = row0 & 15;
    int b1 = row1 >> 8, py1 = (row1 >> 4) & 15, px1 = row1 & 15;
    size_t base0 = (size_t)b0*786432 + py0*16384 + px0*32 + scol;
    size_t base1 = (size_t)b1*786432 + py1*16384 + px1*32 + scol;
    const bf16_t* gB0 = Bt + (size_t)(bn + srow)      * K + scol;
    const bf16_t* gB1 = Bt + (size_t)(bn + 64 + srow) * K + scol;
    bf16_t* lA0 = As + (w*16)*32;
    bf16_t* lA1 = As + (64 + w*16)*32;
    bf16_t* lB0 = Bs + (w*16)*32;
    bf16_t* lB1 = Bs + (64 + w*16)*32;
    f32x4 acc[4][4] = {};
    for (int k0 = 0; k0 < K; k0 += 32) {
        int c  = k0 >> 10;
        int ky = (k0 >> 5) & 31;
        size_t koff = (size_t)c*262144 + ky*512;
        gload16(timgb + base0 + koff, lA0);
        gload16(timgb + base1 + koff, lA1);
        gload16(gB0 + k0, lB0);
        gload16(gB1 + k0, lB1);
        __syncthreads();
        bf16x8 af[4], bfr[4];
        #pragma unroll
        for (int i = 0; i < 4; ++i) {
            af[i]  = *reinterpret_cast<const bf16x8*>(As + (wm + i*16 + rr)*32 + g*8);
            bfr[i] = *reinterpret_cast<const bf16x8*>(Bs + (wn + i*16 + rr)*32 + g*8);
        }
        #pragma unroll
        for (int i = 0; i < 4; ++i)
            #pragma unroll
            for (int j = 0; j < 4; ++j)
                acc[i][j] = __builtin_amdgcn_mfma_f32_16x16x32_bf16(af[i], bfr[j], acc[i][j], 0, 0, 0);
        __syncthreads();
    }
    f32x4 (&accr)[4][4] = acc;
    gemm_epilogue<EPI_CONV>(accr, bias, nullptr, nullptr, Cb, bm, bn, wm, wn, rr, g, N);
}

// ---------------------------------------------------------------------------
// layernorm rows of 768, fp32 in -> bf16 out
// ---------------------------------------------------------------------------
__global__ __launch_bounds__(256)
void ln_kernel(const float* __restrict__ x, const float* __restrict__ g,
               const float* __restrict__ be, bf16_t* __restrict__ out) {
    int r = blockIdx.x, tid = threadIdx.x;
    const float* xr = x + (size_t)r * EMB_;
    float v0 = xr[tid], v1 = xr[tid+256], v2 = xr[tid+512];
    float s = v0+v1+v2, s2 = v0*v0 + v1*v1 + v2*v2;
    __shared__ float red[8];
    #pragma unroll
    for (int off = 32; off; off >>= 1) { s += __shfl_xor(s, off); s2 += __shfl_xor(s2, off); }
    if ((tid & 63) == 0) { red[tid>>6] = s; red[4 + (tid>>6)] = s2; }
    __syncthreads();
    s  = red[0]+red[1]+red[2]+red[3];
    s2 = red[4]+red[5]+red[6]+red[7];
    float mean = s * (1.0f/768.0f);
    float var  = s2 * (1.0f/768.0f) - mean*mean;
    float rstd = rsqrtf(var + 1e-5f);
    bf16_t* orow = out + (size_t)r * EMB_;
    orow[tid]     = (bf16_t)((v0-mean)*rstd*g[tid]     + be[tid]);
    orow[tid+256] = (bf16_t)((v1-mean)*rstd*g[tid+256] + be[tid+256]);
    orow[tid+512] = (bf16_t)((v2-mean)*rstd*g[tid+512] + be[tid+512]);
}

// ---------------------------------------------------------------------------
// attention round 3: grid = (qc,h,b) = 768 blocks, 4 waves.
// wave kc handles keys kc*64..+63 for 64 q rows (lane = q).
// K/V rows are wave-uniform broadcast loads from global (L2-hot).
// softmax without max-subtraction (|s/8| small for this data), partials
// combined across waves via LDS.
// ---------------------------------------------------------------------------
__global__ __launch_bounds__(256)
void attn_kernel3(const bf16_t* __restrict__ qkv, bf16_t* __restrict__ o) {
    __shared__ __align__(16) bf16_t Op[4][64][72];
    __shared__ float Ls[4][64];
    int tid = threadIdx.x;
    int lane = tid & 63;
    int kc   = tid >> 6;
    int qc = blockIdx.x & 3;
    int h  = (blockIdx.x >> 2) % HEADS_;
    int b  = blockIdx.x / (4*HEADS_);
    const bf16_t* base = qkv + (size_t)(b*256)*2304;

    float q[64];
    {
        const bf16_t* qr = base + (size_t)(qc*64 + lane)*2304 + h*64;
        #pragma unroll
        for (int c = 0; c < 8; ++c) {
            bf16x8 v = *reinterpret_cast<const bf16x8*>(qr + c*8);
            #pragma unroll
            for (int j = 0; j < 8; ++j) q[c*8+j] = (float)v[j];
        }
    }
    float O[64];
    #pragma unroll
    for (int d = 0; d < 64; ++d) O[d] = 0.0f;
    float l = 0.0f;

    const bf16_t* kbase = base + (size_t)(kc*64)*2304 + 768 + h*64;
    #pragma unroll 1
    for (int j = 0; j < 64; ++j) {
        const bf16_t* kr = kbase + (size_t)j*2304;       // wave-uniform
        float s = 0.0f;
        #pragma unroll
        for (int c = 0; c < 8; ++c) {
            bf16x8 kv = *reinterpret_cast<const bf16x8*>(kr + c*8);
            #pragma unroll
            for (int e = 0; e < 8; ++e) s = fmaf(q[c*8+e], (float)kv[e], s);
        }
        float p = __expf(s * 0.125f);
        l += p;
        const bf16_t* vr = kr + 768;                      // V row, uniform
        #pragma unroll
        for (int c = 0; c < 8; ++c) {
            bf16x8 vv = *reinterpret_cast<const bf16x8*>(vr + c*8);
            #pragma unroll
            for (int e = 0; e < 8; ++e) O[c*8+e] = fmaf(p, (float)vv[e], O[c*8+e]);
        }
    }

    Ls[kc][lane] = l;
    #pragma unroll
    for (int c = 0; c < 8; ++c) {
        bf16x8 ov;
        #pragma unroll
        for (int e = 0; e < 8; ++e) ov[e] = (bf16_t)O[c*8+e];
        *reinterpret_cast<bf16x8*>(&Op[kc][lane][c*8]) = ov;
    }
    __syncthreads();

    int q_ = tid & 63, dg = tid >> 6;
    float L = Ls[0][q_] + Ls[1][q_] + Ls[2][q_] + Ls[3][q_];
    float inv = 1.0f / L;
    bf16_t* orow = o + (size_t)(b*256 + qc*64 + q_)*EMB_ + h*64 + dg*16;
    #pragma unroll
    for (int c = 0; c < 2; ++c) {
        bf16x8 r;
        #pragma unroll
        for (int e = 0; e < 8; ++e) {
            int d = dg*16 + c*8 + e;
            float acc = (float)Op[0][q_][d] + (float)Op[1][q_][d]
                      + (float)Op[2][q_][d] + (float)Op[3][q_][d];
            r[e] = (bf16_t)(acc * inv);
        }
        *reinterpret_cast<bf16x8*>(orow + c*8) = r;
    }
}

// ---------------------------------------------------------------------------
// head (verified)
// ---------------------------------------------------------------------------
__global__ __launch_bounds__(256)
void head_kernel(const float* __restrict__ tok, const float* __restrict__ fcw,
                 const float* __restrict__ fcb, float* __restrict__ scores) {
    const int bx[6][4] = {{0,6,0,8},{4,11,0,8},{9,16,0,8},{0,6,8,16},{4,11,8,16},{9,16,8,16}};
    int box = blockIdx.x % 6, b = blockIdx.x / 6;
    int r0 = bx[box][0], r1 = bx[box][1], c0 = bx[box][2], c1 = bx[box][3];
    int rh = r1 - r0, rw = c1 - c0;
    __shared__ float wl[256];
    __shared__ float feats[768];
    __shared__ float red[4];
    int tid = threadIdx.x;
    int py = tid >> 4, px = tid & 15;
    float w = 0.0f;
    if (py >= r0 && py < r1 && px >= c0 && px < c1) {
        int ly = py - r0, lx = px - c0;
        float cy = 0.0f, cx = 0.0f;
        for (int o = 0; o < 16; ++o) {
            float sy = (o + 0.5f) * (float)rh * (1.0f/16.0f) - 0.5f;
            sy = fminf(fmaxf(sy, 0.0f), (float)(rh - 1));
            int i0 = (int)floorf(sy); float t = sy - (float)i0;
            if (ly == i0)     cy += 1.0f - t;
            if (ly == i0 + 1) cy += t;
            float sx = (o + 0.5f) * (float)rw * (1.0f/16.0f) - 0.5f;
            sx = fminf(fmaxf(sx, 0.0f), (float)(rw - 1));
            int j0 = (int)floorf(sx); float u = sx - (float)j0;
            if (lx == j0)     cx += 1.0f - u;
            if (lx == j0 + 1) cx += u;
        }
        w = (cy * (1.0f/16.0f)) * (cx * (1.0f/16.0f));
    }
    wl[tid] = w;
    __syncthreads();
    for (int e = tid; e < EMB_; e += 256) {
        float f = 0.0f;
        for (int iy = r0; iy < r1; ++iy)
            for (int ix = c0; ix < c1; ++ix) {
                int p = iy*16 + ix;
                f += wl[p] * tok[((size_t)(b*256 + p))*EMB_ + e];
            }
        feats[e] = f;
    }
    __syncthreads();
    float lg[4];
    #pragma unroll
    for (int cc = 0; cc < 4; ++cc) {
        float part = 0.0f;
        for (int e = tid; e < EMB_; e += 256) part += feats[e]*fcw[e*4 + cc];
        #pragma unroll
        for (int off = 32; off; off >>= 1) part += __shfl_xor(part, off);
        __syncthreads();
        if ((tid & 63) == 0) red[tid>>6] = part;
        __syncthreads();
        lg[cc] = red[0]+red[1]+red[2]+red[3] + fcb[cc];
    }
    if (tid == 0) {
        float mx = fmaxf(fmaxf(lg[0],lg[1]), fmaxf(lg[2],lg[3]));
        float e0 = expf(lg[0]-mx), e1 = expf(lg[1]-mx), e2 = expf(lg[2]-mx), e3 = expf(lg[3]-mx);
        float inv = 1.0f/(e0+e1+e2+e3);
        float* out = scores + (size_t)(b*6 + box)*4;
        out[0] = e0*inv; out[1] = e1*inv; out[2] = e2*inv; out[3] = e3*inv;
    }
}

// ===========================================================================
extern "C" void kernel_launch(void* const* d_in, const int* in_sizes, int n_in,
                              void* d_out, int out_size, void* d_ws, size_t ws_size,
                              hipStream_t stream) {
    (void)in_sizes; (void)n_in; (void)out_size; (void)ws_size;
    const float* x       = (const float*)d_in[0];
    const float* lm      = (const float*)d_in[1];
    const float* stn_w1  = (const float*)d_in[2];
    const float* stn_b1  = (const float*)d_in[3];
    const float* stn_w2  = (const float*)d_in[4];
    const float* stn_b2  = (const float*)d_in[5];
    const float* conv_w  = (const float*)d_in[6];
    const float* conv_b  = (const float*)d_in[7];
    const float* pe_w    = (const float*)d_in[8];
    const float* pe_b    = (const float*)d_in[9];
    const float* pos     = (const float*)d_in[10];
    const float* ln1_g   = (const float*)d_in[11];
    const float* ln1_b   = (const float*)d_in[12];
    const float* qkv_w   = (const float*)d_in[13];
    const float* qkv_b   = (const float*)d_in[14];
    const float* proj_w  = (const float*)d_in[15];
    const float* proj_b  = (const float*)d_in[16];
    const float* ln2_g   = (const float*)d_in[17];
    const float* ln2_b   = (const float*)d_in[18];
    const float* mlp_w1  = (const float*)d_in[19];
    const float* mlp_b1  = (const float*)d_in[20];
    const float* mlp_w2  = (const float*)d_in[21];
    const float* mlp_b2  = (const float*)d_in[22];
    const float* fc_w    = (const float*)d_in[23];
    const float* fc_b    = (const float*)d_in[24];

    float* out    = (float*)d_out;
    float* scores = out;
    float* timg   = out + 384;
    float* tmask  = out + 384 + (size_t)B_*3*HH*WW;

    char* ws = (char*)d_ws;
    size_t off = 0;
    auto alloc = [&](size_t bytes) {
        off = (off + 255) & ~(size_t)255;
        void* p = ws + off; off += bytes; return p;
    };
    // slotBig: seg(fp32,16MB) -> hidden(bf16,24MB)
    char*   slotBig = (char*)alloc(25165824);
    // slotT: timg_bf(25.2MB) -> qkvb(18.9MB)
    char*   slotT   = (char*)alloc((size_t)B_*3*HH*WW*2);
    // slotC: featC(8.4MB) -> obuf(6.3MB)
    char*   slotC   = (char*)alloc((size_t)M_*NF_*2);
    float*  tok     = (float*)alloc((size_t)M_*EMB_*4);
    bf16_t* tbuf    = (bf16_t*)alloc((size_t)M_*EMB_*2);
    bf16_t* conv_wb = (bf16_t*)alloc((size_t)NF_*KCONV*2);
    bf16_t* pe_wb   = (bf16_t*)alloc((size_t)EMB_*NF_*2);
    bf16_t* qkv_wb  = (bf16_t*)alloc((size_t)3*EMB_*EMB_*2);
    bf16_t* proj_wb = (bf16_t*)alloc((size_t)EMB_*EMB_*2);
    bf16_t* mlp1_wb = (bf16_t*)alloc((size_t)4*EMB_*EMB_*2);
    bf16_t* mlp2_wb = (bf16_t*)alloc((size_t)EMB_*4*EMB_*2);
    float*  pooled  = (float*)alloc(16384*4);
    float*  theta   = (float*)alloc(96*4);

    float*  seg    = (float*)slotBig;
    bf16_t* hidden = (bf16_t*)slotBig;
    bf16_t* timgb  = (bf16_t*)slotT;
    bf16_t* qkvb   = (bf16_t*)slotT;
    bf16_t* featC  = (bf16_t*)slotC;
    bf16_t* obuf   = (bf16_t*)slotC;

    // weight conversions (independent of data path)
    convert_bf16_kernel<<<(NF_*KCONV)/8/256, 256, 0, stream>>>(conv_w, conv_wb);
    transpose_bf16_kernel<<<dim3(EMB_/32, NF_/32),    256, 0, stream>>>(pe_w,   pe_wb,   NF_,  EMB_);
    transpose_bf16_kernel<<<dim3(3*EMB_/32, EMB_/32), 256, 0, stream>>>(qkv_w,  qkv_wb,  EMB_, 3*EMB_);
    transpose_bf16_kernel<<<dim3(EMB_/32, EMB_/32),   256, 0, stream>>>(proj_w, proj_wb, EMB_, EMB_);
    transpose_bf16_kernel<<<dim3(4*EMB_/32, EMB_/32), 256, 0, stream>>>(mlp_w1, mlp1_wb, EMB_, 4*EMB_);
    transpose_bf16_kernel<<<dim3(EMB_/32, 4*EMB_/32), 256, 0, stream>>>(mlp_w2, mlp2_wb, 4*EMB_, EMB_);

    // mask path
    hipMemsetAsync(seg, 0, (size_t)B_*HH*WW*sizeof(float), stream);
    raster_kernel<<<B_, 128, 0, stream>>>(lm, seg);
    pool_kernel<<<64, 256, 0, stream>>>(seg, pooled);
    stn_kernel<<<B_, 64, 0, stream>>>(pooled, stn_w1, stn_b1, stn_w2, stn_b2, theta);
    gridsample_kernel<<<(B_*HH*WW)/256, 256, 0, stream>>>(x, seg, theta, timg, tmask, timgb);

    // conv as implicit-im2col GEMM
    gemm_conv_kernel<<<dim3(NF_/128, M_/128), 256, 0, stream>>>(
        timgb, conv_wb, conv_b, featC);

    // patch embed + pos -> tok (fp32 residual stream)
    gemm_bf16_kernel<EPI_PE><<<dim3(EMB_/128, M_/128), 256, 0, stream>>>(
        featC, pe_wb, pe_b, pos, tok, nullptr, M_, EMB_, NF_);

    // LN1 -> qkv
    ln_kernel<<<M_, 256, 0, stream>>>(tok, ln1_g, ln1_b, tbuf);
    gemm_bf16_kernel<EPI_QKV><<<dim3(3*EMB_/128, M_/128), 256, 0, stream>>>(
        tbuf, qkv_wb, qkv_b, nullptr, nullptr, qkvb, M_, 3*EMB_, EMB_);

    // attention
    attn_kernel3<<<B_*HEADS_*4, 256, 0, stream>>>(qkvb, obuf);

    // proj + residual
    gemm_bf16_kernel<EPI_PROJ><<<dim3(EMB_/128, M_/128), 256, 0, stream>>>(
        obuf, proj_wb, proj_b, nullptr, tok, nullptr, M_, EMB_, EMB_);

    // LN2 -> mlp
    ln_kernel<<<M_, 256, 0, stream>>>(tok, ln2_g, ln2_b, tbuf);
    gemm_bf16_kernel<EPI_GELU><<<dim3(4*EMB_/128, M_/128), 256, 0, stream>>>(
        tbuf, mlp1_wb, mlp_b1, nullptr, nullptr, hidden, M_, 4*EMB_, EMB_);
    gemm_bf16_kernel<EPI_MLP2><<<dim3(EMB_/128, M_/128), 256, 0, stream>>>(
        hidden, mlp2_wb, mlp_b2, nullptr, tok, nullptr, M_, EMB_, 4*EMB_);

    // head
    head_kernel<<<B_*6, 256, 0, stream>>>(tok, fc_w, fc_b, scores);
}

// Round 4
// 599.707 us; speedup vs baseline: 1.1460x; 1.1460x over previous
//
#include <hip/hip_runtime.h>
#include <hip/hip_bf16.h>
#include <cstdint>

// ============================================================================
// Hybrid e2e STN pipeline, round 4:
//  - attention state in named ext_vector registers (fixes scratch spill of
//    float[64] arrays seen in r2/r3: VGPR_Count 72 proved alloca->scratch)
//  - GEMMs unchanged (m97 global_load_lds structure)
// ============================================================================

#define B_    16
#define HH    512
#define WW    512
#define NF_   1024
#define EMB_  768
#define HEADS_ 12
#define NTOK  256
#define M_    (B_*NTOK)      // 4096
#define KCONV 3072

typedef __bf16 bf16_t;
typedef __bf16 bf16x8 __attribute__((ext_vector_type(8)));
typedef float  f32x4  __attribute__((ext_vector_type(4)));
typedef float  f32x16 __attribute__((ext_vector_type(16)));

typedef __attribute__((address_space(1))) const void* gas_t;
typedef __attribute__((address_space(3))) void* las_t;

__device__ __forceinline__ void gload16(const bf16_t* g, bf16_t* l) {
    __builtin_amdgcn_global_load_lds((gas_t)g, (las_t)l, 16, 0, 0);
}

__device__ __forceinline__ float tanh_fast(float x) {
    return 1.0f - 2.0f / (__expf(2.0f * x) + 1.0f);
}

// bf16 pair -> f32 via bit ops (low halfword = element 2i, high = 2i+1)
__device__ __forceinline__ float bl_(unsigned u) {
    union { unsigned u; float f; } c; c.u = u << 16; return c.f;
}
__device__ __forceinline__ float bh_(unsigned u) {
    union { unsigned u; float f; } c; c.u = u & 0xffff0000u; return c.f;
}

// ---------------------------------------------------------------------------
// rasterize (verified)
// ---------------------------------------------------------------------------
__global__ __launch_bounds__(128)
void raster_kernel(const float* __restrict__ lm, float* __restrict__ seg) {
    int b = blockIdx.x;
    int s = threadIdx.x;
    if (s >= 117) return;
    int seg0 = (s < 43) ? s : ((s < 92) ? s + 1 : s + 2);
    const float* p = lm + (size_t)b * 240;
    int p1x = min(max((int)(p[seg0*2 + 0] * 512.0f), 0), 511);
    int p1y = min(max((int)(p[seg0*2 + 1] * 512.0f), 0), 511);
    int p2x = min(max((int)(p[(seg0+1)*2 + 0] * 512.0f), 0), 511);
    int p2y = min(max((int)(p[(seg0+1)*2 + 1] * 512.0f), 0), 511);
    int dy = p2y - p1y, dx = p2x - p1x;
    int kmax = min(dy, dx);
    float* sb = seg + (size_t)b * (HH*WW);
    for (int k = 0; k < kmax; ++k) {
        int yi = min(p1y + k, 511);
        int xi = min(p1x + k, 511);
        sb[yi*WW + xi] = 1.0f;
    }
}

// ---------------------------------------------------------------------------
// pool + stn (verified)
// ---------------------------------------------------------------------------
__global__ __launch_bounds__(256)
void pool_kernel(const float* __restrict__ seg, float* __restrict__ pooled) {
    int idx = blockIdx.x * 256 + threadIdx.x;
    int ox = idx & 31, oy = (idx >> 5) & 31, b = idx >> 10;
    const float* sb = seg + (size_t)b * (HH*WW) + (oy*16)*WW + ox*16;
    float s = 0.0f;
    for (int dy = 0; dy < 16; ++dy) {
        #pragma unroll
        for (int dx = 0; dx < 16; ++dx) s += sb[dy*WW + dx];
    }
    pooled[idx] = s * (1.0f/256.0f);
}

__global__ __launch_bounds__(64)
void stn_kernel(const float* __restrict__ pooled,
                const float* __restrict__ w1, const float* __restrict__ b1,
                const float* __restrict__ w2, const float* __restrict__ b2,
                float* __restrict__ theta) {
    __shared__ float pl[1024];
    __shared__ float hl[50];
    int b = blockIdx.x, tid = threadIdx.x;
    for (int i = tid; i < 1024; i += 64) pl[i] = pooled[b*1024 + i];
    __syncthreads();
    if (tid < 50) {
        float acc = b1[tid];
        for (int k = 0; k < 1024; ++k) acc += pl[k] * w1[k*50 + tid];
        hl[tid] = tanhf(acc);
    }
    __syncthreads();
    if (tid < 6) {
        float acc = b2[tid];
        for (int k = 0; k < 50; ++k) acc += hl[k] * w2[k*6 + tid];
        theta[b*6 + tid] = acc;
    }
}

// ---------------------------------------------------------------------------
// fused affine_grid + grid_sample; also emits bf16 copy of transformed img
// ---------------------------------------------------------------------------
__global__ __launch_bounds__(256)
void gridsample_kernel(const float* __restrict__ x, const float* __restrict__ seg,
                       const float* __restrict__ theta,
                       float* __restrict__ timg, float* __restrict__ tmask,
                       bf16_t* __restrict__ timgb) {
    size_t idx = (size_t)blockIdx.x * 256 + threadIdx.x;
    int xx = (int)(idx & 511);
    int yy = (int)((idx >> 9) & 511);
    int b  = (int)(idx >> 18);
    __shared__ float th[6];
    if (threadIdx.x < 6) th[threadIdx.x] = theta[b*6 + threadIdx.x];
    __syncthreads();
    float gx = (2.0f*xx + 1.0f) * (1.0f/512.0f) - 1.0f;
    float gy = (2.0f*yy + 1.0f) * (1.0f/512.0f) - 1.0f;
    float g0 = gx*th[0] + gy*th[1] + th[2];
    float g1 = gx*th[3] + gy*th[4] + th[5];
    float fx = ((g0 + 1.0f)*512.0f - 1.0f)*0.5f;
    float fy = ((g1 + 1.0f)*512.0f - 1.0f)*0.5f;
    float x0f = floorf(fx), y0f = floorf(fy);
    float wx1 = fx - x0f,  wy1 = fy - y0f;
    int ix0 = (int)x0f, iy0 = (int)y0f;
    int ix1 = ix0 + 1,  iy1 = iy0 + 1;
    float fy0ok = (iy0 >= 0 && iy0 < HH) ? 1.0f : 0.0f;
    float fy1ok = (iy1 >= 0 && iy1 < HH) ? 1.0f : 0.0f;
    float fx0ok = (ix0 >= 0 && ix0 < WW) ? 1.0f : 0.0f;
    float fx1ok = (ix1 >= 0 && ix1 < WW) ? 1.0f : 0.0f;
    float w00 = (1.0f-wy1)*(1.0f-wx1) * fy0ok * fx0ok;
    float w01 = (1.0f-wy1)*wx1        * fy0ok * fx1ok;
    float w10 = wy1*(1.0f-wx1)        * fy1ok * fx0ok;
    float w11 = wy1*wx1               * fy1ok * fx1ok;
    int cx0 = min(max(ix0,0),511), cx1 = min(max(ix1,0),511);
    int cy0 = min(max(iy0,0),511), cy1 = min(max(iy1,0),511);
    int i00 = cy0*WW + cx0, i01 = cy0*WW + cx1, i10 = cy1*WW + cx0, i11 = cy1*WW + cx1;
    size_t pix = (size_t)yy*WW + xx;
    #pragma unroll
    for (int c = 0; c < 3; ++c) {
        const float* pl = x + ((size_t)(b*3 + c)) * (HH*WW);
        float v = w00*pl[i00] + w01*pl[i01] + w10*pl[i10] + w11*pl[i11];
        timg [((size_t)(b*3 + c))*(HH*WW) + pix] = v;
        timgb[((size_t)(b*3 + c))*(HH*WW) + pix] = (bf16_t)v;
    }
    const float* sp = seg + (size_t)b * (HH*WW);
    float mv = w00*sp[i00] + w01*sp[i01] + w10*sp[i10] + w11*sp[i11];
    tmask[(size_t)b*(HH*WW) + pix] = mv;
}

// ---------------------------------------------------------------------------
// conversions
// ---------------------------------------------------------------------------
__global__ __launch_bounds__(256)
void convert_bf16_kernel(const float* __restrict__ in, bf16_t* __restrict__ out) {
    int idx = (blockIdx.x * 256 + threadIdx.x) * 8;
    float4 v0 = *reinterpret_cast<const float4*>(in + idx);
    float4 v1 = *reinterpret_cast<const float4*>(in + idx + 4);
    bf16x8 o;
    o[0]=(bf16_t)v0.x; o[1]=(bf16_t)v0.y; o[2]=(bf16_t)v0.z; o[3]=(bf16_t)v0.w;
    o[4]=(bf16_t)v1.x; o[5]=(bf16_t)v1.y; o[6]=(bf16_t)v1.z; o[7]=(bf16_t)v1.w;
    *reinterpret_cast<bf16x8*>(out + idx) = o;
}

__global__ __launch_bounds__(256)
void transpose_bf16_kernel(const float* __restrict__ in, bf16_t* __restrict__ out,
                           int K, int N) {   // in[K][N] -> out[N][K]
    __shared__ float tile[32][33];
    int bk = blockIdx.y * 32, bn = blockIdx.x * 32;
    int r = threadIdx.x >> 5, c = threadIdx.x & 31;
    #pragma unroll
    for (int i = 0; i < 4; ++i)
        tile[r + 8*i][c] = in[(size_t)(bk + r + 8*i) * N + bn + c];
    __syncthreads();
    #pragma unroll
    for (int i = 0; i < 4; ++i)
        out[(size_t)(bn + r + 8*i) * K + bk + c] = (bf16_t)tile[c][r + 8*i];
}

// ---------------------------------------------------------------------------
// bf16 MFMA GEMM (m97 structure)
// ---------------------------------------------------------------------------
enum { EPI_CONV=0, EPI_PE=1, EPI_QKV=2, EPI_PROJ=3, EPI_GELU=4, EPI_MLP2=5 };

template<int EPI>
__device__ __forceinline__ void gemm_epilogue(
        f32x4 (&acc)[4][4], const float* bias, const float* extra,
        float* Cf, bf16_t* Cb, int bm, int bn, int wm, int wn,
        int rr, int g, int N) {
    #pragma unroll
    for (int i = 0; i < 4; ++i) {
        #pragma unroll
        for (int j = 0; j < 4; ++j) {
            #pragma unroll
            for (int r = 0; r < 4; ++r) {
                int m = bm + wm + i*16 + g*4 + r;
                int n = bn + wn + j*16 + rr;
                size_t o = (size_t)m * N + n;
                float v = acc[i][j][r] + bias[n];
                if (EPI == EPI_CONV) {
                    Cb[o] = (bf16_t)fmaxf(v, 0.0f);
                } else if (EPI == EPI_PE) {
                    Cf[o] = v + extra[(size_t)(m & 255)*N + n];
                } else if (EPI == EPI_QKV) {
                    Cb[o] = (bf16_t)v;
                } else if (EPI == EPI_PROJ || EPI == EPI_MLP2) {
                    Cf[o] = v + Cf[o];
                } else if (EPI == EPI_GELU) {
                    float u = v;
                    float gl = 0.5f*u*(1.0f + tanh_fast(0.7978845608028654f*(u + 0.044715f*u*u*u)));
                    Cb[o] = (bf16_t)gl;
                }
            }
        }
    }
}

template<int EPI>
__global__ __launch_bounds__(256)
void gemm_bf16_kernel(const bf16_t* __restrict__ A, const bf16_t* __restrict__ Bt,
                      const float* __restrict__ bias, const float* __restrict__ extra,
                      float* __restrict__ Cf, bf16_t* __restrict__ Cb,
                      int M, int N, int K) {
    __shared__ __align__(16) bf16_t As[128*32];
    __shared__ __align__(16) bf16_t Bs[128*32];
    const int tid = threadIdx.x;
    const int bm = blockIdx.y * 128, bn = blockIdx.x * 128;
    const int lane = tid & 63, w = tid >> 6;
    const int rr = lane & 15, g = lane >> 4;
    const int wm = (w & 1) * 64, wn = (w >> 1) * 64;
    const int srow = w*16 + (lane >> 2);
    const int scol = (lane & 3) * 8;
    const bf16_t* gA0 = A  + (size_t)(bm + srow)      * K + scol;
    const bf16_t* gA1 = A  + (size_t)(bm + 64 + srow) * K + scol;
    const bf16_t* gB0 = Bt + (size_t)(bn + srow)      * K + scol;
    const bf16_t* gB1 = Bt + (size_t)(bn + 64 + srow) * K + scol;
    bf16_t* lA0 = As + (w*16)*32;
    bf16_t* lA1 = As + (64 + w*16)*32;
    bf16_t* lB0 = Bs + (w*16)*32;
    bf16_t* lB1 = Bs + (64 + w*16)*32;
    f32x4 acc[4][4] = {};
    for (int k0 = 0; k0 < K; k0 += 32) {
        gload16(gA0 + k0, lA0);
        gload16(gA1 + k0, lA1);
        gload16(gB0 + k0, lB0);
        gload16(gB1 + k0, lB1);
        __syncthreads();
        bf16x8 af[4], bfr[4];
        #pragma unroll
        for (int i = 0; i < 4; ++i) {
            af[i]  = *reinterpret_cast<const bf16x8*>(As + (wm + i*16 + rr)*32 + g*8);
            bfr[i] = *reinterpret_cast<const bf16x8*>(Bs + (wn + i*16 + rr)*32 + g*8);
        }
        #pragma unroll
        for (int i = 0; i < 4; ++i)
            #pragma unroll
            for (int j = 0; j < 4; ++j)
                acc[i][j] = __builtin_amdgcn_mfma_f32_16x16x32_bf16(af[i], bfr[j], acc[i][j], 0, 0, 0);
        __syncthreads();
    }
    gemm_epilogue<EPI>(acc, bias, extra, Cf, Cb, bm, bn, wm, wn, rr, g, N);
}

// conv GEMM: implicit im2col from bf16 image. M=4096,N=1024,K=3072.
__global__ __launch_bounds__(256)
void gemm_conv_kernel(const bf16_t* __restrict__ timgb, const bf16_t* __restrict__ Bt,
                      const float* __restrict__ bias, bf16_t* __restrict__ Cb) {
    const int N = NF_, K = KCONV;
    __shared__ __align__(16) bf16_t As[128*32];
    __shared__ __align__(16) bf16_t Bs[128*32];
    const int tid = threadIdx.x;
    const int bm = blockIdx.y * 128, bn = blockIdx.x * 128;
    const int lane = tid & 63, w = tid >> 6;
    const int rr = lane & 15, g = lane >> 4;
    const int wm = (w & 1) * 64, wn = (w >> 1) * 64;
    const int srow = w*16 + (lane >> 2);
    const int scol = (lane & 3) * 8;
    int row0 = bm + srow, row1 = bm + 64 + srow;
    int b0 = row0 >> 8, py0 = (row0 >> 4) & 15, px0 = row0 & 15;
    int b1 = row1 >> 8, py1 = (row1 >> 4) & 15, px1 = row1 & 15;
    size_t base0 = (size_t)b0*786432 + py0*16384 + px0*32 + scol;
    size_t base1 = (size_t)b1*786432 + py1*16384 + px1*32 + scol;
    const bf16_t* gB0 = Bt + (size_t)(bn + srow)      * K + scol;
    const bf16_t* gB1 = Bt + (size_t)(bn + 64 + srow) * K + scol;
    bf16_t* lA0 = As + (w*16)*32;
    bf16_t* lA1 = As + (64 + w*16)*32;
    bf16_t* lB0 = Bs + (w*16)*32;
    bf16_t* lB1 = Bs + (64 + w*16)*32;
    f32x4 acc[4][4] = {};
    for (int k0 = 0; k0 < K; k0 += 32) {
        int c  = k0 >> 10;
        int ky = (k0 >> 5) & 31;
        size_t koff = (size_t)c*262144 + ky*512;
        gload16(timgb + base0 + koff, lA0);
        gload16(timgb + base1 + koff, lA1);
        gload16(gB0 + k0, lB0);
        gload16(gB1 + k0, lB1);
        __syncthreads();
        bf16x8 af[4], bfr[4];
        #pragma unroll
        for (int i = 0; i < 4; ++i) {
            af[i]  = *reinterpret_cast<const bf16x8*>(As + (wm + i*16 + rr)*32 + g*8);
            bfr[i] = *reinterpret_cast<const bf16x8*>(Bs + (wn + i*16 + rr)*32 + g*8);
        }
        #pragma unroll
        for (int i = 0; i < 4; ++i)
            #pragma unroll
            for (int j = 0; j < 4; ++j)
                acc[i][j] = __builtin_amdgcn_mfma_f32_16x16x32_bf16(af[i], bfr[j], acc[i][j], 0, 0, 0);
        __syncthreads();
    }
    f32x4 (&accr)[4][4] = acc;
    gemm_epilogue<EPI_CONV>(accr, bias, nullptr, nullptr, Cb, bm, bn, wm, wn, rr, g, N);
}

// ---------------------------------------------------------------------------
// layernorm rows of 768, fp32 in -> bf16 out
// ---------------------------------------------------------------------------
__global__ __launch_bounds__(256)
void ln_kernel(const float* __restrict__ x, const float* __restrict__ g,
               const float* __restrict__ be, bf16_t* __restrict__ out) {
    int r = blockIdx.x, tid = threadIdx.x;
    const float* xr = x + (size_t)r * EMB_;
    float v0 = xr[tid], v1 = xr[tid+256], v2 = xr[tid+512];
    float s = v0+v1+v2, s2 = v0*v0 + v1*v1 + v2*v2;
    __shared__ float red[8];
    #pragma unroll
    for (int off = 32; off; off >>= 1) { s += __shfl_xor(s, off); s2 += __shfl_xor(s2, off); }
    if ((tid & 63) == 0) { red[tid>>6] = s; red[4 + (tid>>6)] = s2; }
    __syncthreads();
    s  = red[0]+red[1]+red[2]+red[3];
    s2 = red[4]+red[5]+red[6]+red[7];
    float mean = s * (1.0f/768.0f);
    float var  = s2 * (1.0f/768.0f) - mean*mean;
    float rstd = rsqrtf(var + 1e-5f);
    bf16_t* orow = out + (size_t)r * EMB_;
    orow[tid]     = (bf16_t)((v0-mean)*rstd*g[tid]     + be[tid]);
    orow[tid+256] = (bf16_t)((v1-mean)*rstd*g[tid+256] + be[tid+256]);
    orow[tid+512] = (bf16_t)((v2-mean)*rstd*g[tid+512] + be[tid+512]);
}

// ---------------------------------------------------------------------------
// attention round 4: same decomposition as r3 (768 blocks, wave=k-chunk,
// lane=q-row) but ALL per-thread state in named ext_vector registers.
// K/V rows are wave-uniform (readfirstlane'd chunk) -> scalar loads + SALU
// bf16->f32, VALU does only the FMAs.
// ---------------------------------------------------------------------------
#define LOADQ16(QV, P) do {                                             \
    uint4 ua_ = *reinterpret_cast<const uint4*>(P);                     \
    uint4 ub_ = *reinterpret_cast<const uint4*>((P) + 8);               \
    QV[0]=bl_(ua_.x); QV[1]=bh_(ua_.x); QV[2]=bl_(ua_.y); QV[3]=bh_(ua_.y); \
    QV[4]=bl_(ua_.z); QV[5]=bh_(ua_.z); QV[6]=bl_(ua_.w); QV[7]=bh_(ua_.w); \
    QV[8]=bl_(ub_.x); QV[9]=bh_(ub_.x); QV[10]=bl_(ub_.y); QV[11]=bh_(ub_.y); \
    QV[12]=bl_(ub_.z); QV[13]=bh_(ub_.z); QV[14]=bl_(ub_.w); QV[15]=bh_(ub_.w); \
} while (0)

#define DOT16(QV, P, S) do {                                            \
    uint4 ua_ = *reinterpret_cast<const uint4*>(P);                     \
    uint4 ub_ = *reinterpret_cast<const uint4*>((P) + 8);               \
    S = fmaf(QV[0],  bl_(ua_.x), S); S = fmaf(QV[1],  bh_(ua_.x), S);   \
    S = fmaf(QV[2],  bl_(ua_.y), S); S = fmaf(QV[3],  bh_(ua_.y), S);   \
    S = fmaf(QV[4],  bl_(ua_.z), S); S = fmaf(QV[5],  bh_(ua_.z), S);   \
    S = fmaf(QV[6],  bl_(ua_.w), S); S = fmaf(QV[7],  bh_(ua_.w), S);   \
    S = fmaf(QV[8],  bl_(ub_.x), S); S = fmaf(QV[9],  bh_(ub_.x), S);   \
    S = fmaf(QV[10], bl_(ub_.y), S); S = fmaf(QV[11], bh_(ub_.y), S);   \
    S = fmaf(QV[12], bl_(ub_.z), S); S = fmaf(QV[13], bh_(ub_.z), S);   \
    S = fmaf(QV[14], bl_(ub_.w), S); S = fmaf(QV[15], bh_(ub_.w), S);   \
} while (0)

#define PVACC16(OV, P, PP) do {                                         \
    uint4 ua_ = *reinterpret_cast<const uint4*>(P);                     \
    uint4 ub_ = *reinterpret_cast<const uint4*>((P) + 8);               \
    OV[0]  = fmaf(PP, bl_(ua_.x), OV[0]);  OV[1]  = fmaf(PP, bh_(ua_.x), OV[1]);  \
    OV[2]  = fmaf(PP, bl_(ua_.y), OV[2]);  OV[3]  = fmaf(PP, bh_(ua_.y), OV[3]);  \
    OV[4]  = fmaf(PP, bl_(ua_.z), OV[4]);  OV[5]  = fmaf(PP, bh_(ua_.z), OV[5]);  \
    OV[6]  = fmaf(PP, bl_(ua_.w), OV[6]);  OV[7]  = fmaf(PP, bh_(ua_.w), OV[7]);  \
    OV[8]  = fmaf(PP, bl_(ub_.x), OV[8]);  OV[9]  = fmaf(PP, bh_(ub_.x), OV[9]);  \
    OV[10] = fmaf(PP, bl_(ub_.y), OV[10]); OV[11] = fmaf(PP, bh_(ub_.y), OV[11]); \
    OV[12] = fmaf(PP, bl_(ub_.z), OV[12]); OV[13] = fmaf(PP, bh_(ub_.z), OV[13]); \
} while (0)

#define PVACC16T(OV, P, PP) do {                                        \
    uint4 ua_ = *reinterpret_cast<const uint4*>(P);                     \
    uint4 ub_ = *reinterpret_cast<const uint4*>((P) + 8);               \
    OV[0]  = fmaf(PP, bl_(ua_.x), OV[0]);  OV[1]  = fmaf(PP, bh_(ua_.x), OV[1]);  \
    OV[2]  = fmaf(PP, bl_(ua_.y), OV[2]);  OV[3]  = fmaf(PP, bh_(ua_.y), OV[3]);  \
    OV[4]  = fmaf(PP, bl_(ua_.z), OV[4]);  OV[5]  = fmaf(PP, bh_(ua_.z), OV[5]);  \
    OV[6]  = fmaf(PP, bl_(ua_.w), OV[6]);  OV[7]  = fmaf(PP, bh_(ua_.w), OV[7]);  \
    OV[8]  = fmaf(PP, bl_(ub_.x), OV[8]);  OV[9]  = fmaf(PP, bh_(ub_.x), OV[9]);  \
    OV[10] = fmaf(PP, bl_(ub_.y), OV[10]); OV[11] = fmaf(PP, bh_(ub_.y), OV[11]); \
    OV[12] = fmaf(PP, bl_(ub_.z), OV[12]); OV[13] = fmaf(PP, bh_(ub_.z), OV[13]); \
    OV[14] = fmaf(PP, bl_(ub_.w), OV[14]); OV[15] = fmaf(PP, bh_(ub_.w), OV[15]); \
} while (0)

#define STORE8B(OV, I0, DST) do {                                       \
    bf16x8 t_;                                                          \
    t_[0]=(bf16_t)OV[I0+0]; t_[1]=(bf16_t)OV[I0+1];                     \
    t_[2]=(bf16_t)OV[I0+2]; t_[3]=(bf16_t)OV[I0+3];                     \
    t_[4]=(bf16_t)OV[I0+4]; t_[5]=(bf16_t)OV[I0+5];                     \
    t_[6]=(bf16_t)OV[I0+6]; t_[7]=(bf16_t)OV[I0+7];                     \
    *reinterpret_cast<bf16x8*>(DST) = t_;                               \
} while (0)

__global__ __launch_bounds__(256)
void attn_kernel4(const bf16_t* __restrict__ qkv, bf16_t* __restrict__ o) {
    __shared__ __align__(16) bf16_t Op[4][64][72];
    __shared__ float Ls[4][64];
    int tid  = threadIdx.x;
    int lane = tid & 63;
    int kc   = __builtin_amdgcn_readfirstlane(tid >> 6);   // wave-uniform
    int qc = blockIdx.x & 3;
    int h  = (blockIdx.x >> 2) % HEADS_;
    int b  = blockIdx.x / (4*HEADS_);
    const bf16_t* base = qkv + (size_t)(b*256)*2304;

    // Q row (per-lane) into named vector registers
    f32x16 q0, q1, q2, q3;
    {
        const bf16_t* qr = base + (size_t)(qc*64 + lane)*2304 + h*64;
        LOADQ16(q0, qr);
        LOADQ16(q1, qr + 16);
        LOADQ16(q2, qr + 32);
        LOADQ16(q3, qr + 48);
    }
    f32x16 o0 = {}, o1 = {}, o2 = {}, o3 = {};
    float l = 0.0f;

    const bf16_t* kbase = base + (size_t)(kc*64)*2304 + 768 + h*64;
    #pragma unroll 2
    for (int j = 0; j < 64; ++j) {
        const bf16_t* kr = kbase + (size_t)j*2304;   // wave-uniform address
        float s = 0.0f;
        DOT16(q0, kr,      s);
        DOT16(q1, kr + 16, s);
        DOT16(q2, kr + 32, s);
        DOT16(q3, kr + 48, s);
        float p = __expf(s * 0.125f);
        l += p;
        const bf16_t* vr = kr + 768;                 // V row, wave-uniform
        PVACC16T(o0, vr,      p);
        PVACC16T(o1, vr + 16, p);
        PVACC16T(o2, vr + 32, p);
        PVACC16T(o3, vr + 48, p);
    }

    Ls[kc][lane] = l;
    STORE8B(o0, 0, &Op[kc][lane][0]);
    STORE8B(o0, 8, &Op[kc][lane][8]);
    STORE8B(o1, 0, &Op[kc][lane][16]);
    STORE8B(o1, 8, &Op[kc][lane][24]);
    STORE8B(o2, 0, &Op[kc][lane][32]);
    STORE8B(o2, 8, &Op[kc][lane][40]);
    STORE8B(o3, 0, &Op[kc][lane][48]);
    STORE8B(o3, 8, &Op[kc][lane][56]);
    __syncthreads();

    int q_ = tid & 63, dg = tid >> 6;
    float L = Ls[0][q_] + Ls[1][q_] + Ls[2][q_] + Ls[3][q_];
    float inv = 1.0f / L;
    bf16_t* orow = o + (size_t)(b*256 + qc*64 + q_)*EMB_ + h*64 + dg*16;
    #pragma unroll
    for (int c = 0; c < 2; ++c) {
        bf16x8 r;
        #pragma unroll
        for (int e = 0; e < 8; ++e) {
            int d = dg*16 + c*8 + e;
            float acc = (float)Op[0][q_][d] + (float)Op[1][q_][d]
                      + (float)Op[2][q_][d] + (float)Op[3][q_][d];
            r[e] = (bf16_t)(acc * inv);
        }
        *reinterpret_cast<bf16x8*>(orow + c*8) = r;
    }
}

// ---------------------------------------------------------------------------
// head (verified)
// ---------------------------------------------------------------------------
__global__ __launch_bounds__(256)
void head_kernel(const float* __restrict__ tok, const float* __restrict__ fcw,
                 const float* __restrict__ fcb, float* __restrict__ scores) {
    const int bx[6][4] = {{0,6,0,8},{4,11,0,8},{9,16,0,8},{0,6,8,16},{4,11,8,16},{9,16,8,16}};
    int box = blockIdx.x % 6, b = blockIdx.x / 6;
    int r0 = bx[box][0], r1 = bx[box][1], c0 = bx[box][2], c1 = bx[box][3];
    int rh = r1 - r0, rw = c1 - c0;
    __shared__ float wl[256];
    __shared__ float feats[768];
    __shared__ float red[4];
    int tid = threadIdx.x;
    int py = tid >> 4, px = tid & 15;
    float w = 0.0f;
    if (py >= r0 && py < r1 && px >= c0 && px < c1) {
        int ly = py - r0, lx = px - c0;
        float cy = 0.0f, cx = 0.0f;
        for (int o = 0; o < 16; ++o) {
            float sy = (o + 0.5f) * (float)rh * (1.0f/16.0f) - 0.5f;
            sy = fminf(fmaxf(sy, 0.0f), (float)(rh - 1));
            int i0 = (int)floorf(sy); float t = sy - (float)i0;
            if (ly == i0)     cy += 1.0f - t;
            if (ly == i0 + 1) cy += t;
            float sx = (o + 0.5f) * (float)rw * (1.0f/16.0f) - 0.5f;
            sx = fminf(fmaxf(sx, 0.0f), (float)(rw - 1));
            int j0 = (int)floorf(sx); float u = sx - (float)j0;
            if (lx == j0)     cx += 1.0f - u;
            if (lx == j0 + 1) cx += u;
        }
        w = (cy * (1.0f/16.0f)) * (cx * (1.0f/16.0f));
    }
    wl[tid] = w;
    __syncthreads();
    for (int e = tid; e < EMB_; e += 256) {
        float f = 0.0f;
        for (int iy = r0; iy < r1; ++iy)
            for (int ix = c0; ix < c1; ++ix) {
                int p = iy*16 + ix;
                f += wl[p] * tok[((size_t)(b*256 + p))*EMB_ + e];
            }
        feats[e] = f;
    }
    __syncthreads();
    float lg[4];
    #pragma unroll
    for (int cc = 0; cc < 4; ++cc) {
        float part = 0.0f;
        for (int e = tid; e < EMB_; e += 256) part += feats[e]*fcw[e*4 + cc];
        #pragma unroll
        for (int off = 32; off; off >>= 1) part += __shfl_xor(part, off);
        __syncthreads();
        if ((tid & 63) == 0) red[tid>>6] = part;
        __syncthreads();
        lg[cc] = red[0]+red[1]+red[2]+red[3] + fcb[cc];
    }
    if (tid == 0) {
        float mx = fmaxf(fmaxf(lg[0],lg[1]), fmaxf(lg[2],lg[3]));
        float e0 = expf(lg[0]-mx), e1 = expf(lg[1]-mx), e2 = expf(lg[2]-mx), e3 = expf(lg[3]-mx);
        float inv = 1.0f/(e0+e1+e2+e3);
        float* out = scores + (size_t)(b*6 + box)*4;
        out[0] = e0*inv; out[1] = e1*inv; out[2] = e2*inv; out[3] = e3*inv;
    }
}

// ===========================================================================
extern "C" void kernel_launch(void* const* d_in, const int* in_sizes, int n_in,
                              void* d_out, int out_size, void* d_ws, size_t ws_size,
                              hipStream_t stream) {
    (void)in_sizes; (void)n_in; (void)out_size; (void)ws_size;
    const float* x       = (const float*)d_in[0];
    const float* lm      = (const float*)d_in[1];
    const float* stn_w1  = (const float*)d_in[2];
    const float* stn_b1  = (const float*)d_in[3];
    const float* stn_w2  = (const float*)d_in[4];
    const float* stn_b2  = (const float*)d_in[5];
    const float* conv_w  = (const float*)d_in[6];
    const float* conv_b  = (const float*)d_in[7];
    const float* pe_w    = (const float*)d_in[8];
    const float* pe_b    = (const float*)d_in[9];
    const float* pos     = (const float*)d_in[10];
    const float* ln1_g   = (const float*)d_in[11];
    const float* ln1_b   = (const float*)d_in[12];
    const float* qkv_w   = (const float*)d_in[13];
    const float* qkv_b   = (const float*)d_in[14];
    const float* proj_w  = (const float*)d_in[15];
    const float* proj_b  = (const float*)d_in[16];
    const float* ln2_g   = (const float*)d_in[17];
    const float* ln2_b   = (const float*)d_in[18];
    const float* mlp_w1  = (const float*)d_in[19];
    const float* mlp_b1  = (const float*)d_in[20];
    const float* mlp_w2  = (const float*)d_in[21];
    const float* mlp_b2  = (const float*)d_in[22];
    const float* fc_w    = (const float*)d_in[23];
    const float* fc_b    = (const float*)d_in[24];

    float* out    = (float*)d_out;
    float* scores = out;
    float* timg   = out + 384;
    float* tmask  = out + 384 + (size_t)B_*3*HH*WW;

    char* ws = (char*)d_ws;
    size_t off = 0;
    auto alloc = [&](size_t bytes) {
        off = (off + 255) & ~(size_t)255;
        void* p = ws + off; off += bytes; return p;
    };
    // slotBig: seg(fp32,16MB) -> hidden(bf16,24MB)
    char*   slotBig = (char*)alloc(25165824);
    // slotT: timg_bf(25.2MB) -> qkvb(18.9MB)
    char*   slotT   = (char*)alloc((size_t)B_*3*HH*WW*2);
    // slotC: featC(8.4MB) -> obuf(6.3MB)
    char*   slotC   = (char*)alloc((size_t)M_*NF_*2);
    float*  tok     = (float*)alloc((size_t)M_*EMB_*4);
    bf16_t* tbuf    = (bf16_t*)alloc((size_t)M_*EMB_*2);
    bf16_t* conv_wb = (bf16_t*)alloc((size_t)NF_*KCONV*2);
    bf16_t* pe_wb   = (bf16_t*)alloc((size_t)EMB_*NF_*2);
    bf16_t* qkv_wb  = (bf16_t*)alloc((size_t)3*EMB_*EMB_*2);
    bf16_t* proj_wb = (bf16_t*)alloc((size_t)EMB_*EMB_*2);
    bf16_t* mlp1_wb = (bf16_t*)alloc((size_t)4*EMB_*EMB_*2);
    bf16_t* mlp2_wb = (bf16_t*)alloc((size_t)EMB_*4*EMB_*2);
    float*  pooled  = (float*)alloc(16384*4);
    float*  theta   = (float*)alloc(96*4);

    float*  seg    = (float*)slotBig;
    bf16_t* hidden = (bf16_t*)slotBig;
    bf16_t* timgb  = (bf16_t*)slotT;
    bf16_t* qkvb   = (bf16_t*)slotT;
    bf16_t* featC  = (bf16_t*)slotC;
    bf16_t* obuf   = (bf16_t*)slotC;

    // weight conversions (independent of data path)
    convert_bf16_kernel<<<(NF_*KCONV)/8/256, 256, 0, stream>>>(conv_w, conv_wb);
    transpose_bf16_kernel<<<dim3(EMB_/32, NF_/32),    256, 0, stream>>>(pe_w,   pe_wb,   NF_,  EMB_);
    transpose_bf16_kernel<<<dim3(3*EMB_/32, EMB_/32), 256, 0, stream>>>(qkv_w,  qkv_wb,  EMB_, 3*EMB_);
    transpose_bf16_kernel<<<dim3(EMB_/32, EMB_/32),   256, 0, stream>>>(proj_w, proj_wb, EMB_, EMB_);
    transpose_bf16_kernel<<<dim3(4*EMB_/32, EMB_/32), 256, 0, stream>>>(mlp_w1, mlp1_wb, EMB_, 4*EMB_);
    transpose_bf16_kernel<<<dim3(EMB_/32, 4*EMB_/32), 256, 0, stream>>>(mlp_w2, mlp2_wb, 4*EMB_, EMB_);

    // mask path
    hipMemsetAsync(seg, 0, (size_t)B_*HH*WW*sizeof(float), stream);
    raster_kernel<<<B_, 128, 0, stream>>>(lm, seg);
    pool_kernel<<<64, 256, 0, stream>>>(seg, pooled);
    stn_kernel<<<B_, 64, 0, stream>>>(pooled, stn_w1, stn_b1, stn_w2, stn_b2, theta);
    gridsample_kernel<<<(B_*HH*WW)/256, 256, 0, stream>>>(x, seg, theta, timg, tmask, timgb);

    // conv as implicit-im2col GEMM
    gemm_conv_kernel<<<dim3(NF_/128, M_/128), 256, 0, stream>>>(
        timgb, conv_wb, conv_b, featC);

    // patch embed + pos -> tok (fp32 residual stream)
    gemm_bf16_kernel<EPI_PE><<<dim3(EMB_/128, M_/128), 256, 0, stream>>>(
        featC, pe_wb, pe_b, pos, tok, nullptr, M_, EMB_, NF_);

    // LN1 -> qkv
    ln_kernel<<<M_, 256, 0, stream>>>(tok, ln1_g, ln1_b, tbuf);
    gemm_bf16_kernel<EPI_QKV><<<dim3(3*EMB_/128, M_/128), 256, 0, stream>>>(
        tbuf, qkv_wb, qkv_b, nullptr, nullptr, qkvb, M_, 3*EMB_, EMB_);

    // attention
    attn_kernel4<<<B_*HEADS_*4, 256, 0, stream>>>(qkvb, obuf);

    // proj + residual
    gemm_bf16_kernel<EPI_PROJ><<<dim3(EMB_/128, M_/128), 256, 0, stream>>>(
        obuf, proj_wb, proj_b, nullptr, tok, nullptr, M_, EMB_, EMB_);

    // LN2 -> mlp
    ln_kernel<<<M_, 256, 0, stream>>>(tok, ln2_g, ln2_b, tbuf);
    gemm_bf16_kernel<EPI_GELU><<<dim3(4*EMB_/128, M_/128), 256, 0, stream>>>(
        tbuf, mlp1_wb, mlp_b1, nullptr, nullptr, hidden, M_, 4*EMB_, EMB_);
    gemm_bf16_kernel<EPI_MLP2><<<dim3(EMB_/128, M_/128), 256, 0, stream>>>(
        hidden, mlp2_wb, mlp_b2, nullptr, tok, nullptr, M_, EMB_, 4*EMB_);

    // head
    head_kernel<<<B_*6, 256, 0, stream>>>(tok, fc_w, fc_b, scores);
}

// Round 5
// 465.183 us; speedup vs baseline: 1.4774x; 1.2892x over previous
//
#include <hip/hip_runtime.h>
#include <hip/hip_bf16.h>
#include <cstdint>

// ============================================================================
// Hybrid e2e STN pipeline, round 5:
//  - attention rebuilt on MFMA (QK^T and PV), flash-chunked, no-max softmax
//  - GEMMs unchanged (m97 global_load_lds structure, verified r2-r4)
// ============================================================================

#define B_    16
#define HH    512
#define WW    512
#define NF_   1024
#define EMB_  768
#define HEADS_ 12
#define NTOK  256
#define M_    (B_*NTOK)      // 4096
#define KCONV 3072

typedef __bf16 bf16_t;
typedef __bf16 bf16x8 __attribute__((ext_vector_type(8)));
typedef float  f32x4  __attribute__((ext_vector_type(4)));

typedef __attribute__((address_space(1))) const void* gas_t;
typedef __attribute__((address_space(3))) void* las_t;

__device__ __forceinline__ void gload16(const bf16_t* g, bf16_t* l) {
    __builtin_amdgcn_global_load_lds((gas_t)g, (las_t)l, 16, 0, 0);
}

__device__ __forceinline__ float tanh_fast(float x) {
    return 1.0f - 2.0f / (__expf(2.0f * x) + 1.0f);
}

// ---------------------------------------------------------------------------
// rasterize (verified)
// ---------------------------------------------------------------------------
__global__ __launch_bounds__(128)
void raster_kernel(const float* __restrict__ lm, float* __restrict__ seg) {
    int b = blockIdx.x;
    int s = threadIdx.x;
    if (s >= 117) return;
    int seg0 = (s < 43) ? s : ((s < 92) ? s + 1 : s + 2);
    const float* p = lm + (size_t)b * 240;
    int p1x = min(max((int)(p[seg0*2 + 0] * 512.0f), 0), 511);
    int p1y = min(max((int)(p[seg0*2 + 1] * 512.0f), 0), 511);
    int p2x = min(max((int)(p[(seg0+1)*2 + 0] * 512.0f), 0), 511);
    int p2y = min(max((int)(p[(seg0+1)*2 + 1] * 512.0f), 0), 511);
    int dy = p2y - p1y, dx = p2x - p1x;
    int kmax = min(dy, dx);
    float* sb = seg + (size_t)b * (HH*WW);
    for (int k = 0; k < kmax; ++k) {
        int yi = min(p1y + k, 511);
        int xi = min(p1x + k, 511);
        sb[yi*WW + xi] = 1.0f;
    }
}

// ---------------------------------------------------------------------------
// pool + stn (verified)
// ---------------------------------------------------------------------------
__global__ __launch_bounds__(256)
void pool_kernel(const float* __restrict__ seg, float* __restrict__ pooled) {
    int idx = blockIdx.x * 256 + threadIdx.x;
    int ox = idx & 31, oy = (idx >> 5) & 31, b = idx >> 10;
    const float* sb = seg + (size_t)b * (HH*WW) + (oy*16)*WW + ox*16;
    float s = 0.0f;
    for (int dy = 0; dy < 16; ++dy) {
        #pragma unroll
        for (int dx = 0; dx < 16; ++dx) s += sb[dy*WW + dx];
    }
    pooled[idx] = s * (1.0f/256.0f);
}

__global__ __launch_bounds__(64)
void stn_kernel(const float* __restrict__ pooled,
                const float* __restrict__ w1, const float* __restrict__ b1,
                const float* __restrict__ w2, const float* __restrict__ b2,
                float* __restrict__ theta) {
    __shared__ float pl[1024];
    __shared__ float hl[50];
    int b = blockIdx.x, tid = threadIdx.x;
    for (int i = tid; i < 1024; i += 64) pl[i] = pooled[b*1024 + i];
    __syncthreads();
    if (tid < 50) {
        float acc = b1[tid];
        for (int k = 0; k < 1024; ++k) acc += pl[k] * w1[k*50 + tid];
        hl[tid] = tanhf(acc);
    }
    __syncthreads();
    if (tid < 6) {
        float acc = b2[tid];
        for (int k = 0; k < 50; ++k) acc += hl[k] * w2[k*6 + tid];
        theta[b*6 + tid] = acc;
    }
}

// ---------------------------------------------------------------------------
// fused affine_grid + grid_sample; also emits bf16 copy of transformed img
// ---------------------------------------------------------------------------
__global__ __launch_bounds__(256)
void gridsample_kernel(const float* __restrict__ x, const float* __restrict__ seg,
                       const float* __restrict__ theta,
                       float* __restrict__ timg, float* __restrict__ tmask,
                       bf16_t* __restrict__ timgb) {
    size_t idx = (size_t)blockIdx.x * 256 + threadIdx.x;
    int xx = (int)(idx & 511);
    int yy = (int)((idx >> 9) & 511);
    int b  = (int)(idx >> 18);
    __shared__ float th[6];
    if (threadIdx.x < 6) th[threadIdx.x] = theta[b*6 + threadIdx.x];
    __syncthreads();
    float gx = (2.0f*xx + 1.0f) * (1.0f/512.0f) - 1.0f;
    float gy = (2.0f*yy + 1.0f) * (1.0f/512.0f) - 1.0f;
    float g0 = gx*th[0] + gy*th[1] + th[2];
    float g1 = gx*th[3] + gy*th[4] + th[5];
    float fx = ((g0 + 1.0f)*512.0f - 1.0f)*0.5f;
    float fy = ((g1 + 1.0f)*512.0f - 1.0f)*0.5f;
    float x0f = floorf(fx), y0f = floorf(fy);
    float wx1 = fx - x0f,  wy1 = fy - y0f;
    int ix0 = (int)x0f, iy0 = (int)y0f;
    int ix1 = ix0 + 1,  iy1 = iy0 + 1;
    float fy0ok = (iy0 >= 0 && iy0 < HH) ? 1.0f : 0.0f;
    float fy1ok = (iy1 >= 0 && iy1 < HH) ? 1.0f : 0.0f;
    float fx0ok = (ix0 >= 0 && ix0 < WW) ? 1.0f : 0.0f;
    float fx1ok = (ix1 >= 0 && ix1 < WW) ? 1.0f : 0.0f;
    float w00 = (1.0f-wy1)*(1.0f-wx1) * fy0ok * fx0ok;
    float w01 = (1.0f-wy1)*wx1        * fy0ok * fx1ok;
    float w10 = wy1*(1.0f-wx1)        * fy1ok * fx0ok;
    float w11 = wy1*wx1               * fy1ok * fx1ok;
    int cx0 = min(max(ix0,0),511), cx1 = min(max(ix1,0),511);
    int cy0 = min(max(iy0,0),511), cy1 = min(max(iy1,0),511);
    int i00 = cy0*WW + cx0, i01 = cy0*WW + cx1, i10 = cy1*WW + cx0, i11 = cy1*WW + cx1;
    size_t pix = (size_t)yy*WW + xx;
    #pragma unroll
    for (int c = 0; c < 3; ++c) {
        const float* pl = x + ((size_t)(b*3 + c)) * (HH*WW);
        float v = w00*pl[i00] + w01*pl[i01] + w10*pl[i10] + w11*pl[i11];
        timg [((size_t)(b*3 + c))*(HH*WW) + pix] = v;
        timgb[((size_t)(b*3 + c))*(HH*WW) + pix] = (bf16_t)v;
    }
    const float* sp = seg + (size_t)b * (HH*WW);
    float mv = w00*sp[i00] + w01*sp[i01] + w10*sp[i10] + w11*sp[i11];
    tmask[(size_t)b*(HH*WW) + pix] = mv;
}

// ---------------------------------------------------------------------------
// conversions
// ---------------------------------------------------------------------------
__global__ __launch_bounds__(256)
void convert_bf16_kernel(const float* __restrict__ in, bf16_t* __restrict__ out) {
    int idx = (blockIdx.x * 256 + threadIdx.x) * 8;
    float4 v0 = *reinterpret_cast<const float4*>(in + idx);
    float4 v1 = *reinterpret_cast<const float4*>(in + idx + 4);
    bf16x8 o;
    o[0]=(bf16_t)v0.x; o[1]=(bf16_t)v0.y; o[2]=(bf16_t)v0.z; o[3]=(bf16_t)v0.w;
    o[4]=(bf16_t)v1.x; o[5]=(bf16_t)v1.y; o[6]=(bf16_t)v1.z; o[7]=(bf16_t)v1.w;
    *reinterpret_cast<bf16x8*>(out + idx) = o;
}

__global__ __launch_bounds__(256)
void transpose_bf16_kernel(const float* __restrict__ in, bf16_t* __restrict__ out,
                           int K, int N) {   // in[K][N] -> out[N][K]
    __shared__ float tile[32][33];
    int bk = blockIdx.y * 32, bn = blockIdx.x * 32;
    int r = threadIdx.x >> 5, c = threadIdx.x & 31;
    #pragma unroll
    for (int i = 0; i < 4; ++i)
        tile[r + 8*i][c] = in[(size_t)(bk + r + 8*i) * N + bn + c];
    __syncthreads();
    #pragma unroll
    for (int i = 0; i < 4; ++i)
        out[(size_t)(bn + r + 8*i) * K + bk + c] = (bf16_t)tile[c][r + 8*i];
}

// ---------------------------------------------------------------------------
// bf16 MFMA GEMM (m97 structure)
// ---------------------------------------------------------------------------
enum { EPI_CONV=0, EPI_PE=1, EPI_QKV=2, EPI_PROJ=3, EPI_GELU=4, EPI_MLP2=5 };

template<int EPI>
__device__ __forceinline__ void gemm_epilogue(
        f32x4 (&acc)[4][4], const float* bias, const float* extra,
        float* Cf, bf16_t* Cb, int bm, int bn, int wm, int wn,
        int rr, int g, int N) {
    #pragma unroll
    for (int i = 0; i < 4; ++i) {
        #pragma unroll
        for (int j = 0; j < 4; ++j) {
            #pragma unroll
            for (int r = 0; r < 4; ++r) {
                int m = bm + wm + i*16 + g*4 + r;
                int n = bn + wn + j*16 + rr;
                size_t o = (size_t)m * N + n;
                float v = acc[i][j][r] + bias[n];
                if (EPI == EPI_CONV) {
                    Cb[o] = (bf16_t)fmaxf(v, 0.0f);
                } else if (EPI == EPI_PE) {
                    Cf[o] = v + extra[(size_t)(m & 255)*N + n];
                } else if (EPI == EPI_QKV) {
                    Cb[o] = (bf16_t)v;
                } else if (EPI == EPI_PROJ || EPI == EPI_MLP2) {
                    Cf[o] = v + Cf[o];
                } else if (EPI == EPI_GELU) {
                    float u = v;
                    float gl = 0.5f*u*(1.0f + tanh_fast(0.7978845608028654f*(u + 0.044715f*u*u*u)));
                    Cb[o] = (bf16_t)gl;
                }
            }
        }
    }
}

template<int EPI>
__global__ __launch_bounds__(256)
void gemm_bf16_kernel(const bf16_t* __restrict__ A, const bf16_t* __restrict__ Bt,
                      const float* __restrict__ bias, const float* __restrict__ extra,
                      float* __restrict__ Cf, bf16_t* __restrict__ Cb,
                      int M, int N, int K) {
    __shared__ __align__(16) bf16_t As[128*32];
    __shared__ __align__(16) bf16_t Bs[128*32];
    const int tid = threadIdx.x;
    const int bm = blockIdx.y * 128, bn = blockIdx.x * 128;
    const int lane = tid & 63, w = tid >> 6;
    const int rr = lane & 15, g = lane >> 4;
    const int wm = (w & 1) * 64, wn = (w >> 1) * 64;
    const int srow = w*16 + (lane >> 2);
    const int scol = (lane & 3) * 8;
    const bf16_t* gA0 = A  + (size_t)(bm + srow)      * K + scol;
    const bf16_t* gA1 = A  + (size_t)(bm + 64 + srow) * K + scol;
    const bf16_t* gB0 = Bt + (size_t)(bn + srow)      * K + scol;
    const bf16_t* gB1 = Bt + (size_t)(bn + 64 + srow) * K + scol;
    bf16_t* lA0 = As + (w*16)*32;
    bf16_t* lA1 = As + (64 + w*16)*32;
    bf16_t* lB0 = Bs + (w*16)*32;
    bf16_t* lB1 = Bs + (64 + w*16)*32;
    f32x4 acc[4][4] = {};
    for (int k0 = 0; k0 < K; k0 += 32) {
        gload16(gA0 + k0, lA0);
        gload16(gA1 + k0, lA1);
        gload16(gB0 + k0, lB0);
        gload16(gB1 + k0, lB1);
        __syncthreads();
        bf16x8 af[4], bfr[4];
        #pragma unroll
        for (int i = 0; i < 4; ++i) {
            af[i]  = *reinterpret_cast<const bf16x8*>(As + (wm + i*16 + rr)*32 + g*8);
            bfr[i] = *reinterpret_cast<const bf16x8*>(Bs + (wn + i*16 + rr)*32 + g*8);
        }
        #pragma unroll
        for (int i = 0; i < 4; ++i)
            #pragma unroll
            for (int j = 0; j < 4; ++j)
                acc[i][j] = __builtin_amdgcn_mfma_f32_16x16x32_bf16(af[i], bfr[j], acc[i][j], 0, 0, 0);
        __syncthreads();
    }
    gemm_epilogue<EPI>(acc, bias, extra, Cf, Cb, bm, bn, wm, wn, rr, g, N);
}

// conv GEMM: implicit im2col from bf16 image. M=4096,N=1024,K=3072.
__global__ __launch_bounds__(256)
void gemm_conv_kernel(const bf16_t* __restrict__ timgb, const bf16_t* __restrict__ Bt,
                      const float* __restrict__ bias, bf16_t* __restrict__ Cb) {
    const int N = NF_, K = KCONV;
    __shared__ __align__(16) bf16_t As[128*32];
    __shared__ __align__(16) bf16_t Bs[128*32];
    const int tid = threadIdx.x;
    const int bm = blockIdx.y * 128, bn = blockIdx.x * 128;
    const int lane = tid & 63, w = tid >> 6;
    const int rr = lane & 15, g = lane >> 4;
    const int wm = (w & 1) * 64, wn = (w >> 1) * 64;
    const int srow = w*16 + (lane >> 2);
    const int scol = (lane & 3) * 8;
    int row0 = bm + srow, row1 = bm + 64 + srow;
    int b0 = row0 >> 8, py0 = (row0 >> 4) & 15, px0 = row0 & 15;
    int b1 = row1 >> 8, py1 = (row1 >> 4) & 15, px1 = row1 & 15;
    size_t base0 = (size_t)b0*786432 + py0*16384 + px0*32 + scol;
    size_t base1 = (size_t)b1*786432 + py1*16384 + px1*32 + scol;
    const bf16_t* gB0 = Bt + (size_t)(bn + srow)      * K + scol;
    const bf16_t* gB1 = Bt + (size_t)(bn + 64 + srow) * K + scol;
    bf16_t* lA0 = As + (w*16)*32;
    bf16_t* lA1 = As + (64 + w*16)*32;
    bf16_t* lB0 = Bs + (w*16)*32;
    bf16_t* lB1 = Bs + (64 + w*16)*32;
    f32x4 acc[4][4] = {};
    for (int k0 = 0; k0 < K; k0 += 32) {
        int c  = k0 >> 10;
        int ky = (k0 >> 5) & 31;
        size_t koff = (size_t)c*262144 + ky*512;
        gload16(timgb + base0 + koff, lA0);
        gload16(timgb + base1 + koff, lA1);
        gload16(gB0 + k0, lB0);
        gload16(gB1 + k0, lB1);
        __syncthreads();
        bf16x8 af[4], bfr[4];
        #pragma unroll
        for (int i = 0; i < 4; ++i) {
            af[i]  = *reinterpret_cast<const bf16x8*>(As + (wm + i*16 + rr)*32 + g*8);
            bfr[i] = *reinterpret_cast<const bf16x8*>(Bs + (wn + i*16 + rr)*32 + g*8);
        }
        #pragma unroll
        for (int i = 0; i < 4; ++i)
            #pragma unroll
            for (int j = 0; j < 4; ++j)
                acc[i][j] = __builtin_amdgcn_mfma_f32_16x16x32_bf16(af[i], bfr[j], acc[i][j], 0, 0, 0);
        __syncthreads();
    }
    f32x4 (&accr)[4][4] = acc;
    gemm_epilogue<EPI_CONV>(accr, bias, nullptr, nullptr, Cb, bm, bn, wm, wn, rr, g, N);
}

// ---------------------------------------------------------------------------
// layernorm rows of 768, fp32 in -> bf16 out
// ---------------------------------------------------------------------------
__global__ __launch_bounds__(256)
void ln_kernel(const float* __restrict__ x, const float* __restrict__ g,
               const float* __restrict__ be, bf16_t* __restrict__ out) {
    int r = blockIdx.x, tid = threadIdx.x;
    const float* xr = x + (size_t)r * EMB_;
    float v0 = xr[tid], v1 = xr[tid+256], v2 = xr[tid+512];
    float s = v0+v1+v2, s2 = v0*v0 + v1*v1 + v2*v2;
    __shared__ float red[8];
    #pragma unroll
    for (int off = 32; off; off >>= 1) { s += __shfl_xor(s, off); s2 += __shfl_xor(s2, off); }
    if ((tid & 63) == 0) { red[tid>>6] = s; red[4 + (tid>>6)] = s2; }
    __syncthreads();
    s  = red[0]+red[1]+red[2]+red[3];
    s2 = red[4]+red[5]+red[6]+red[7];
    float mean = s * (1.0f/768.0f);
    float var  = s2 * (1.0f/768.0f) - mean*mean;
    float rstd = rsqrtf(var + 1e-5f);
    bf16_t* orow = out + (size_t)r * EMB_;
    orow[tid]     = (bf16_t)((v0-mean)*rstd*g[tid]     + be[tid]);
    orow[tid+256] = (bf16_t)((v1-mean)*rstd*g[tid+256] + be[tid+256]);
    orow[tid+512] = (bf16_t)((v2-mean)*rstd*g[tid+512] + be[tid+512]);
}

// ---------------------------------------------------------------------------
// attention round 5: MFMA flash-chunked. One block per (b,h) = 192 blocks,
// 4 waves; wave w owns q-rows [w*64, w*64+64). K in LDS [256][72] (padded),
// V transposed in LDS [64][264], P per-wave private [64][72].
// No-max softmax (verified r3/r4). Fragment layouts identical to the GEMM
// (hardware-verified rounds 2-4).
// ---------------------------------------------------------------------------
__global__ __launch_bounds__(256)
void attn_kernel5(const bf16_t* __restrict__ qkv, bf16_t* __restrict__ o) {
    __shared__ __align__(16) bf16_t Ks[256*72];     // 36 KB  K[key][d]
    __shared__ __align__(16) bf16_t Vt[64*264];     // 33 KB  V^T[d][key]
    __shared__ __align__(16) bf16_t Ps[4][64*72];   // 36 KB  per-wave P[q][key]
    const int tid  = threadIdx.x;
    const int lane = tid & 63, w = tid >> 6;
    const int rr   = lane & 15, g = lane >> 4;
    const int h = blockIdx.x % HEADS_;
    const int b = blockIdx.x / HEADS_;
    const bf16_t* base = qkv + (size_t)(b*256)*2304;

    // stage K row tid and V row tid (V transposed)
    {
        const bf16_t* kr = base + (size_t)tid*2304 + 768  + h*64;
        const bf16_t* vr = base + (size_t)tid*2304 + 1536 + h*64;
        bf16_t* kd = Ks + tid*72;
        #pragma unroll
        for (int c2 = 0; c2 < 8; ++c2) {
            *reinterpret_cast<bf16x8*>(kd + c2*8) =
                *reinterpret_cast<const bf16x8*>(kr + c2*8);
            bf16x8 v = *reinterpret_cast<const bf16x8*>(vr + c2*8);
            #pragma unroll
            for (int e = 0; e < 8; ++e)
                Vt[(c2*8 + e)*264 + tid] = v[e];
        }
    }

    // Q A-fragments direct from global (read once)
    bf16x8 qf[4][2];
    #pragma unroll
    for (int i = 0; i < 4; ++i)
        #pragma unroll
        for (int ks = 0; ks < 2; ++ks)
            qf[i][ks] = *reinterpret_cast<const bf16x8*>(
                base + (size_t)(w*64 + i*16 + rr)*2304 + h*64 + ks*32 + g*8);

    f32x4 oacc[4][4] = {};
    float lacc[4][4] = {};
    __syncthreads();

    bf16_t* Pw = Ps[w];
    for (int kc = 0; kc < 4; ++kc) {
        // S = Q K^T for this 64-key chunk
        f32x4 sacc[4][4] = {};
        #pragma unroll
        for (int ks = 0; ks < 2; ++ks) {
            bf16x8 kf[4];
            #pragma unroll
            for (int j = 0; j < 4; ++j)
                kf[j] = *reinterpret_cast<const bf16x8*>(
                    Ks + (size_t)(kc*64 + j*16 + rr)*72 + ks*32 + g*8);
            #pragma unroll
            for (int i = 0; i < 4; ++i)
                #pragma unroll
                for (int j = 0; j < 4; ++j)
                    sacc[i][j] = __builtin_amdgcn_mfma_f32_16x16x32_bf16(
                        qf[i][ks], kf[j], sacc[i][j], 0, 0, 0);
        }
        // softmax (no max), write P bf16, accumulate in-lane l partials
        #pragma unroll
        for (int i = 0; i < 4; ++i) {
            #pragma unroll
            for (int r = 0; r < 4; ++r) {
                int prow = i*16 + g*4 + r;
                float ps = 0.0f;
                #pragma unroll
                for (int j = 0; j < 4; ++j) {
                    float p = __expf(sacc[i][j][r] * 0.125f);
                    ps += p;
                    Pw[prow*72 + j*16 + rr] = (bf16_t)p;
                }
                lacc[i][r] += ps;
            }
        }
        // O += P V  (P wave-private; compiler orders the LDS dep)
        #pragma unroll
        for (int ks = 0; ks < 2; ++ks) {
            bf16x8 pa[4], vb[4];
            #pragma unroll
            for (int i = 0; i < 4; ++i)
                pa[i] = *reinterpret_cast<const bf16x8*>(
                    Pw + (size_t)(i*16 + rr)*72 + ks*32 + g*8);
            #pragma unroll
            for (int n = 0; n < 4; ++n)
                vb[n] = *reinterpret_cast<const bf16x8*>(
                    Vt + (size_t)(n*16 + rr)*264 + kc*64 + ks*32 + g*8);
            #pragma unroll
            for (int i = 0; i < 4; ++i)
                #pragma unroll
                for (int n = 0; n < 4; ++n)
                    oacc[i][n] = __builtin_amdgcn_mfma_f32_16x16x32_bf16(
                        pa[i], vb[n], oacc[i][n], 0, 0, 0);
        }
    }

    // finish l: reduce partials across the 16 rr-lanes (xor bits 0..3)
    #pragma unroll
    for (int i = 0; i < 4; ++i) {
        #pragma unroll
        for (int r = 0; r < 4; ++r) {
            float v = lacc[i][r];
            v += __shfl_xor(v, 1);
            v += __shfl_xor(v, 2);
            v += __shfl_xor(v, 4);
            v += __shfl_xor(v, 8);
            lacc[i][r] = 1.0f / v;
        }
    }
    // write O
    #pragma unroll
    for (int i = 0; i < 4; ++i) {
        #pragma unroll
        for (int r = 0; r < 4; ++r) {
            int qrow = w*64 + i*16 + g*4 + r;
            bf16_t* orow = o + (size_t)(b*256 + qrow)*EMB_ + h*64;
            float inv = lacc[i][r];
            #pragma unroll
            for (int n = 0; n < 4; ++n)
                orow[n*16 + rr] = (bf16_t)(oacc[i][n][r] * inv);
        }
    }
}

// ---------------------------------------------------------------------------
// head (verified)
// ---------------------------------------------------------------------------
__global__ __launch_bounds__(256)
void head_kernel(const float* __restrict__ tok, const float* __restrict__ fcw,
                 const float* __restrict__ fcb, float* __restrict__ scores) {
    const int bx[6][4] = {{0,6,0,8},{4,11,0,8},{9,16,0,8},{0,6,8,16},{4,11,8,16},{9,16,8,16}};
    int box = blockIdx.x % 6, b = blockIdx.x / 6;
    int r0 = bx[box][0], r1 = bx[box][1], c0 = bx[box][2], c1 = bx[box][3];
    int rh = r1 - r0, rw = c1 - c0;
    __shared__ float wl[256];
    __shared__ float feats[768];
    __shared__ float red[4];
    int tid = threadIdx.x;
    int py = tid >> 4, px = tid & 15;
    float w = 0.0f;
    if (py >= r0 && py < r1 && px >= c0 && px < c1) {
        int ly = py - r0, lx = px - c0;
        float cy = 0.0f, cx = 0.0f;
        for (int o = 0; o < 16; ++o) {
            float sy = (o + 0.5f) * (float)rh * (1.0f/16.0f) - 0.5f;
            sy = fminf(fmaxf(sy, 0.0f), (float)(rh - 1));
            int i0 = (int)floorf(sy); float t = sy - (float)i0;
            if (ly == i0)     cy += 1.0f - t;
            if (ly == i0 + 1) cy += t;
            float sx = (o + 0.5f) * (float)rw * (1.0f/16.0f) - 0.5f;
            sx = fminf(fmaxf(sx, 0.0f), (float)(rw - 1));
            int j0 = (int)floorf(sx); float u = sx - (float)j0;
            if (lx == j0)     cx += 1.0f - u;
            if (lx == j0 + 1) cx += u;
        }
        w = (cy * (1.0f/16.0f)) * (cx * (1.0f/16.0f));
    }
    wl[tid] = w;
    __syncthreads();
    for (int e = tid; e < EMB_; e += 256) {
        float f = 0.0f;
        for (int iy = r0; iy < r1; ++iy)
            for (int ix = c0; ix < c1; ++ix) {
                int p = iy*16 + ix;
                f += wl[p] * tok[((size_t)(b*256 + p))*EMB_ + e];
            }
        feats[e] = f;
    }
    __syncthreads();
    float lg[4];
    #pragma unroll
    for (int cc = 0; cc < 4; ++cc) {
        float part = 0.0f;
        for (int e = tid; e < EMB_; e += 256) part += feats[e]*fcw[e*4 + cc];
        #pragma unroll
        for (int off = 32; off; off >>= 1) part += __shfl_xor(part, off);
        __syncthreads();
        if ((tid & 63) == 0) red[tid>>6] = part;
        __syncthreads();
        lg[cc] = red[0]+red[1]+red[2]+red[3] + fcb[cc];
    }
    if (tid == 0) {
        float mx = fmaxf(fmaxf(lg[0],lg[1]), fmaxf(lg[2],lg[3]));
        float e0 = expf(lg[0]-mx), e1 = expf(lg[1]-mx), e2 = expf(lg[2]-mx), e3 = expf(lg[3]-mx);
        float inv = 1.0f/(e0+e1+e2+e3);
        float* out = scores + (size_t)(b*6 + box)*4;
        out[0] = e0*inv; out[1] = e1*inv; out[2] = e2*inv; out[3] = e3*inv;
    }
}

// ===========================================================================
extern "C" void kernel_launch(void* const* d_in, const int* in_sizes, int n_in,
                              void* d_out, int out_size, void* d_ws, size_t ws_size,
                              hipStream_t stream) {
    (void)in_sizes; (void)n_in; (void)out_size; (void)ws_size;
    const float* x       = (const float*)d_in[0];
    const float* lm      = (const float*)d_in[1];
    const float* stn_w1  = (const float*)d_in[2];
    const float* stn_b1  = (const float*)d_in[3];
    const float* stn_w2  = (const float*)d_in[4];
    const float* stn_b2  = (const float*)d_in[5];
    const float* conv_w  = (const float*)d_in[6];
    const float* conv_b  = (const float*)d_in[7];
    const float* pe_w    = (const float*)d_in[8];
    const float* pe_b    = (const float*)d_in[9];
    const float* pos     = (const float*)d_in[10];
    const float* ln1_g   = (const float*)d_in[11];
    const float* ln1_b   = (const float*)d_in[12];
    const float* qkv_w   = (const float*)d_in[13];
    const float* qkv_b   = (const float*)d_in[14];
    const float* proj_w  = (const float*)d_in[15];
    const float* proj_b  = (const float*)d_in[16];
    const float* ln2_g   = (const float*)d_in[17];
    const float* ln2_b   = (const float*)d_in[18];
    const float* mlp_w1  = (const float*)d_in[19];
    const float* mlp_b1  = (const float*)d_in[20];
    const float* mlp_w2  = (const float*)d_in[21];
    const float* mlp_b2  = (const float*)d_in[22];
    const float* fc_w    = (const float*)d_in[23];
    const float* fc_b    = (const float*)d_in[24];

    float* out    = (float*)d_out;
    float* scores = out;
    float* timg   = out + 384;
    float* tmask  = out + 384 + (size_t)B_*3*HH*WW;

    char* ws = (char*)d_ws;
    size_t off = 0;
    auto alloc = [&](size_t bytes) {
        off = (off + 255) & ~(size_t)255;
        void* p = ws + off; off += bytes; return p;
    };
    // slotBig: seg(fp32,16MB) -> hidden(bf16,24MB)
    char*   slotBig = (char*)alloc(25165824);
    // slotT: timg_bf(25.2MB) -> qkvb(18.9MB)
    char*   slotT   = (char*)alloc((size_t)B_*3*HH*WW*2);
    // slotC: featC(8.4MB) -> obuf(6.3MB)
    char*   slotC   = (char*)alloc((size_t)M_*NF_*2);
    float*  tok     = (float*)alloc((size_t)M_*EMB_*4);
    bf16_t* tbuf    = (bf16_t*)alloc((size_t)M_*EMB_*2);
    bf16_t* conv_wb = (bf16_t*)alloc((size_t)NF_*KCONV*2);
    bf16_t* pe_wb   = (bf16_t*)alloc((size_t)EMB_*NF_*2);
    bf16_t* qkv_wb  = (bf16_t*)alloc((size_t)3*EMB_*EMB_*2);
    bf16_t* proj_wb = (bf16_t*)alloc((size_t)EMB_*EMB_*2);
    bf16_t* mlp1_wb = (bf16_t*)alloc((size_t)4*EMB_*EMB_*2);
    bf16_t* mlp2_wb = (bf16_t*)alloc((size_t)EMB_*4*EMB_*2);
    float*  pooled  = (float*)alloc(16384*4);
    float*  theta   = (float*)alloc(96*4);

    float*  seg    = (float*)slotBig;
    bf16_t* hidden = (bf16_t*)slotBig;
    bf16_t* timgb  = (bf16_t*)slotT;
    bf16_t* qkvb   = (bf16_t*)slotT;
    bf16_t* featC  = (bf16_t*)slotC;
    bf16_t* obuf   = (bf16_t*)slotC;

    // weight conversions (independent of data path)
    convert_bf16_kernel<<<(NF_*KCONV)/8/256, 256, 0, stream>>>(conv_w, conv_wb);
    transpose_bf16_kernel<<<dim3(EMB_/32, NF_/32),    256, 0, stream>>>(pe_w,   pe_wb,   NF_,  EMB_);
    transpose_bf16_kernel<<<dim3(3*EMB_/32, EMB_/32), 256, 0, stream>>>(qkv_w,  qkv_wb,  EMB_, 3*EMB_);
    transpose_bf16_kernel<<<dim3(EMB_/32, EMB_/32),   256, 0, stream>>>(proj_w, proj_wb, EMB_, EMB_);
    transpose_bf16_kernel<<<dim3(4*EMB_/32, EMB_/32), 256, 0, stream>>>(mlp_w1, mlp1_wb, EMB_, 4*EMB_);
    transpose_bf16_kernel<<<dim3(EMB_/32, 4*EMB_/32), 256, 0, stream>>>(mlp_w2, mlp2_wb, 4*EMB_, EMB_);

    // mask path
    hipMemsetAsync(seg, 0, (size_t)B_*HH*WW*sizeof(float), stream);
    raster_kernel<<<B_, 128, 0, stream>>>(lm, seg);
    pool_kernel<<<64, 256, 0, stream>>>(seg, pooled);
    stn_kernel<<<B_, 64, 0, stream>>>(pooled, stn_w1, stn_b1, stn_w2, stn_b2, theta);
    gridsample_kernel<<<(B_*HH*WW)/256, 256, 0, stream>>>(x, seg, theta, timg, tmask, timgb);

    // conv as implicit-im2col GEMM
    gemm_conv_kernel<<<dim3(NF_/128, M_/128), 256, 0, stream>>>(
        timgb, conv_wb, conv_b, featC);

    // patch embed + pos -> tok (fp32 residual stream)
    gemm_bf16_kernel<EPI_PE><<<dim3(EMB_/128, M_/128), 256, 0, stream>>>(
        featC, pe_wb, pe_b, pos, tok, nullptr, M_, EMB_, NF_);

    // LN1 -> qkv
    ln_kernel<<<M_, 256, 0, stream>>>(tok, ln1_g, ln1_b, tbuf);
    gemm_bf16_kernel<EPI_QKV><<<dim3(3*EMB_/128, M_/128), 256, 0, stream>>>(
        tbuf, qkv_wb, qkv_b, nullptr, nullptr, qkvb, M_, 3*EMB_, EMB_);

    // attention (MFMA)
    attn_kernel5<<<B_*HEADS_, 256, 0, stream>>>(qkvb, obuf);

    // proj + residual
    gemm_bf16_kernel<EPI_PROJ><<<dim3(EMB_/128, M_/128), 256, 0, stream>>>(
        obuf, proj_wb, proj_b, nullptr, tok, nullptr, M_, EMB_, EMB_);

    // LN2 -> mlp
    ln_kernel<<<M_, 256, 0, stream>>>(tok, ln2_g, ln2_b, tbuf);
    gemm_bf16_kernel<EPI_GELU><<<dim3(4*EMB_/128, M_/128), 256, 0, stream>>>(
        tbuf, mlp1_wb, mlp_b1, nullptr, nullptr, hidden, M_, 4*EMB_, EMB_);
    gemm_bf16_kernel<EPI_MLP2><<<dim3(EMB_/128, M_/128), 256, 0, stream>>>(
        hidden, mlp2_wb, mlp_b2, nullptr, tok, nullptr, M_, EMB_, 4*EMB_);

    // head
    head_kernel<<<B_*6, 256, 0, stream>>>(tok, fc_w, fc_b, scores);
}

// Round 6
// 413.559 us; speedup vs baseline: 1.6618x; 1.1248x over previous
//
#include <hip/hip_runtime.h>
#include <hip/hip_bf16.h>
#include <cstdint>

// ============================================================================
// Hybrid e2e STN pipeline, round 6:
//  - GEMMs: double-buffered LDS (prefetch-before-compute), XOR bank swizzle
//    via pre-swizzled global source, BN=64 tiles for narrow-N GEMMs
//  - attention: MFMA flash (unchanged from r5, verified)
// ============================================================================

#define B_    16
#define HH    512
#define WW    512
#define NF_   1024
#define EMB_  768
#define HEADS_ 12
#define NTOK  256
#define M_    (B_*NTOK)      // 4096
#define KCONV 3072

typedef __bf16 bf16_t;
typedef __bf16 bf16x8 __attribute__((ext_vector_type(8)));
typedef float  f32x4  __attribute__((ext_vector_type(4)));

typedef __attribute__((address_space(1))) const void* gas_t;
typedef __attribute__((address_space(3))) void* las_t;

__device__ __forceinline__ void gload16(const bf16_t* g, bf16_t* l) {
    __builtin_amdgcn_global_load_lds((gas_t)g, (las_t)l, 16, 0, 0);
}

__device__ __forceinline__ float tanh_fast(float x) {
    return 1.0f - 2.0f / (__expf(2.0f * x) + 1.0f);
}

// ---------------------------------------------------------------------------
// rasterize (verified)
// ---------------------------------------------------------------------------
__global__ __launch_bounds__(128)
void raster_kernel(const float* __restrict__ lm, float* __restrict__ seg) {
    int b = blockIdx.x;
    int s = threadIdx.x;
    if (s >= 117) return;
    int seg0 = (s < 43) ? s : ((s < 92) ? s + 1 : s + 2);
    const float* p = lm + (size_t)b * 240;
    int p1x = min(max((int)(p[seg0*2 + 0] * 512.0f), 0), 511);
    int p1y = min(max((int)(p[seg0*2 + 1] * 512.0f), 0), 511);
    int p2x = min(max((int)(p[(seg0+1)*2 + 0] * 512.0f), 0), 511);
    int p2y = min(max((int)(p[(seg0+1)*2 + 1] * 512.0f), 0), 511);
    int dy = p2y - p1y, dx = p2x - p1x;
    int kmax = min(dy, dx);
    float* sb = seg + (size_t)b * (HH*WW);
    for (int k = 0; k < kmax; ++k) {
        int yi = min(p1y + k, 511);
        int xi = min(p1x + k, 511);
        sb[yi*WW + xi] = 1.0f;
    }
}

// ---------------------------------------------------------------------------
// pool + stn (verified)
// ---------------------------------------------------------------------------
__global__ __launch_bounds__(256)
void pool_kernel(const float* __restrict__ seg, float* __restrict__ pooled) {
    int idx = blockIdx.x * 256 + threadIdx.x;
    int ox = idx & 31, oy = (idx >> 5) & 31, b = idx >> 10;
    const float* sb = seg + (size_t)b * (HH*WW) + (oy*16)*WW + ox*16;
    float s = 0.0f;
    for (int dy = 0; dy < 16; ++dy) {
        #pragma unroll
        for (int dx = 0; dx < 16; ++dx) s += sb[dy*WW + dx];
    }
    pooled[idx] = s * (1.0f/256.0f);
}

__global__ __launch_bounds__(64)
void stn_kernel(const float* __restrict__ pooled,
                const float* __restrict__ w1, const float* __restrict__ b1,
                const float* __restrict__ w2, const float* __restrict__ b2,
                float* __restrict__ theta) {
    __shared__ float pl[1024];
    __shared__ float hl[50];
    int b = blockIdx.x, tid = threadIdx.x;
    for (int i = tid; i < 1024; i += 64) pl[i] = pooled[b*1024 + i];
    __syncthreads();
    if (tid < 50) {
        float acc = b1[tid];
        for (int k = 0; k < 1024; ++k) acc += pl[k] * w1[k*50 + tid];
        hl[tid] = tanhf(acc);
    }
    __syncthreads();
    if (tid < 6) {
        float acc = b2[tid];
        for (int k = 0; k < 50; ++k) acc += hl[k] * w2[k*6 + tid];
        theta[b*6 + tid] = acc;
    }
}

// ---------------------------------------------------------------------------
// fused affine_grid + grid_sample; also emits bf16 copy of transformed img
// ---------------------------------------------------------------------------
__global__ __launch_bounds__(256)
void gridsample_kernel(const float* __restrict__ x, const float* __restrict__ seg,
                       const float* __restrict__ theta,
                       float* __restrict__ timg, float* __restrict__ tmask,
                       bf16_t* __restrict__ timgb) {
    size_t idx = (size_t)blockIdx.x * 256 + threadIdx.x;
    int xx = (int)(idx & 511);
    int yy = (int)((idx >> 9) & 511);
    int b  = (int)(idx >> 18);
    __shared__ float th[6];
    if (threadIdx.x < 6) th[threadIdx.x] = theta[b*6 + threadIdx.x];
    __syncthreads();
    float gx = (2.0f*xx + 1.0f) * (1.0f/512.0f) - 1.0f;
    float gy = (2.0f*yy + 1.0f) * (1.0f/512.0f) - 1.0f;
    float g0 = gx*th[0] + gy*th[1] + th[2];
    float g1 = gx*th[3] + gy*th[4] + th[5];
    float fx = ((g0 + 1.0f)*512.0f - 1.0f)*0.5f;
    float fy = ((g1 + 1.0f)*512.0f - 1.0f)*0.5f;
    float x0f = floorf(fx), y0f = floorf(fy);
    float wx1 = fx - x0f,  wy1 = fy - y0f;
    int ix0 = (int)x0f, iy0 = (int)y0f;
    int ix1 = ix0 + 1,  iy1 = iy0 + 1;
    float fy0ok = (iy0 >= 0 && iy0 < HH) ? 1.0f : 0.0f;
    float fy1ok = (iy1 >= 0 && iy1 < HH) ? 1.0f : 0.0f;
    float fx0ok = (ix0 >= 0 && ix0 < WW) ? 1.0f : 0.0f;
    float fx1ok = (ix1 >= 0 && ix1 < WW) ? 1.0f : 0.0f;
    float w00 = (1.0f-wy1)*(1.0f-wx1) * fy0ok * fx0ok;
    float w01 = (1.0f-wy1)*wx1        * fy0ok * fx1ok;
    float w10 = wy1*(1.0f-wx1)        * fy1ok * fx0ok;
    float w11 = wy1*wx1               * fy1ok * fx1ok;
    int cx0 = min(max(ix0,0),511), cx1 = min(max(ix1,0),511);
    int cy0 = min(max(iy0,0),511), cy1 = min(max(iy1,0),511);
    int i00 = cy0*WW + cx0, i01 = cy0*WW + cx1, i10 = cy1*WW + cx0, i11 = cy1*WW + cx1;
    size_t pix = (size_t)yy*WW + xx;
    #pragma unroll
    for (int c = 0; c < 3; ++c) {
        const float* pl = x + ((size_t)(b*3 + c)) * (HH*WW);
        float v = w00*pl[i00] + w01*pl[i01] + w10*pl[i10] + w11*pl[i11];
        timg [((size_t)(b*3 + c))*(HH*WW) + pix] = v;
        timgb[((size_t)(b*3 + c))*(HH*WW) + pix] = (bf16_t)v;
    }
    const float* sp = seg + (size_t)b * (HH*WW);
    float mv = w00*sp[i00] + w01*sp[i01] + w10*sp[i10] + w11*sp[i11];
    tmask[(size_t)b*(HH*WW) + pix] = mv;
}

// ---------------------------------------------------------------------------
// conversions
// ---------------------------------------------------------------------------
__global__ __launch_bounds__(256)
void convert_bf16_kernel(const float* __restrict__ in, bf16_t* __restrict__ out) {
    int idx = (blockIdx.x * 256 + threadIdx.x) * 8;
    float4 v0 = *reinterpret_cast<const float4*>(in + idx);
    float4 v1 = *reinterpret_cast<const float4*>(in + idx + 4);
    bf16x8 o;
    o[0]=(bf16_t)v0.x; o[1]=(bf16_t)v0.y; o[2]=(bf16_t)v0.z; o[3]=(bf16_t)v0.w;
    o[4]=(bf16_t)v1.x; o[5]=(bf16_t)v1.y; o[6]=(bf16_t)v1.z; o[7]=(bf16_t)v1.w;
    *reinterpret_cast<bf16x8*>(out + idx) = o;
}

__global__ __launch_bounds__(256)
void transpose_bf16_kernel(const float* __restrict__ in, bf16_t* __restrict__ out,
                           int K, int N) {   // in[K][N] -> out[N][K]
    __shared__ float tile[32][33];
    int bk = blockIdx.y * 32, bn = blockIdx.x * 32;
    int r = threadIdx.x >> 5, c = threadIdx.x & 31;
    #pragma unroll
    for (int i = 0; i < 4; ++i)
        tile[r + 8*i][c] = in[(size_t)(bk + r + 8*i) * N + bn + c];
    __syncthreads();
    #pragma unroll
    for (int i = 0; i < 4; ++i)
        out[(size_t)(bn + r + 8*i) * K + bk + c] = (bf16_t)tile[c][r + 8*i];
}

// ---------------------------------------------------------------------------
// bf16 MFMA GEMM, round-6 structure:
//  - tile 128 x BN (BN = 64 or 128), BK=32, 256 thr = 4 waves
//  - double-buffered LDS, STAGE(next) issued BEFORE compute(cur)   [T3 2-ph]
//  - XOR swizzle: stage global col (slot^((srow>>1)&3)), read (g^((rr>>1)&3))
//    -> 2-way LDS conflicts (free)                                  [T2/m201]
// ---------------------------------------------------------------------------
enum { EPI_CONV=0, EPI_PE=1, EPI_QKV=2, EPI_PROJ=3, EPI_GELU=4, EPI_MLP2=5 };

template<int EPI, int FJ>
__device__ __forceinline__ void gemm_epilogue(
        f32x4 (&acc)[4][FJ], const float* bias, const float* extra,
        float* Cf, bf16_t* Cb, int bm, int bn, int wm, int wn,
        int rr, int g, int N) {
    #pragma unroll
    for (int i = 0; i < 4; ++i) {
        #pragma unroll
        for (int j = 0; j < FJ; ++j) {
            #pragma unroll
            for (int r = 0; r < 4; ++r) {
                int m = bm + wm + i*16 + g*4 + r;
                int n = bn + wn + j*16 + rr;
                size_t o = (size_t)m * N + n;
                float v = acc[i][j][r] + bias[n];
                if (EPI == EPI_CONV) {
                    Cb[o] = (bf16_t)fmaxf(v, 0.0f);
                } else if (EPI == EPI_PE) {
                    Cf[o] = v + extra[(size_t)(m & 255)*N + n];
                } else if (EPI == EPI_QKV) {
                    Cb[o] = (bf16_t)v;
                } else if (EPI == EPI_PROJ || EPI == EPI_MLP2) {
                    Cf[o] = v + Cf[o];
                } else if (EPI == EPI_GELU) {
                    float u = v;
                    float gl = 0.5f*u*(1.0f + tanh_fast(0.7978845608028654f*(u + 0.044715f*u*u*u)));
                    Cb[o] = (bf16_t)gl;
                }
            }
        }
    }
}

template<int EPI, int BN>
__global__ __launch_bounds__(256)
void gemm_bf16_kernel(const bf16_t* __restrict__ A, const bf16_t* __restrict__ Bt,
                      const float* __restrict__ bias, const float* __restrict__ extra,
                      float* __restrict__ Cf, bf16_t* __restrict__ Cb,
                      int M, int N, int K) {
    constexpr int WN = BN / 2;          // wave n-extent
    constexpr int FJ = WN / 16;         // n-frags per wave (2 or 4)
    __shared__ __align__(16) bf16_t As[2][128*32];
    __shared__ __align__(16) bf16_t Bs[2][BN*32];
    const int tid = threadIdx.x;
    const int bm = blockIdx.y * 128, bn = blockIdx.x * BN;
    const int lane = tid & 63, w = tid >> 6;
    const int rr = lane & 15, g = lane >> 4;
    const int wm = (w & 1) * 64, wn = (w >> 1) * WN;
    const int srow = tid >> 2;                     // 0..63
    const int gc   = (((tid & 3) ^ ((srow >> 1) & 3)) * 8);  // swizzled g-col
    const int rc   = (g ^ ((rr >> 1) & 3)) * 8;              // swizzled r-col

    const bf16_t* gA0 = A  + (size_t)(bm + srow)      * K + gc;
    const bf16_t* gA1 = A  + (size_t)(bm + 64 + srow) * K + gc;
    const bf16_t* gB0 = Bt + (size_t)(bn + srow)      * K + gc;
    const bf16_t* gB1 = Bt + (size_t)(bn + 64 + srow) * K + gc;  // BN=128 only

    auto STAGE = [&](int buf, int k0) {
        gload16(gA0 + k0, As[buf] + (w*16)*32);
        gload16(gA1 + k0, As[buf] + (64 + w*16)*32);
        gload16(gB0 + k0, Bs[buf] + (w*16)*32);
        if (BN == 128)
            gload16(gB1 + k0, Bs[buf] + (64 + w*16)*32);
    };

    f32x4 acc[4][FJ] = {};
    STAGE(0, 0);
    __syncthreads();
    int cur = 0;
    for (int k0 = 0; k0 < K; k0 += 32) {
        if (k0 + 32 < K) STAGE(cur ^ 1, k0 + 32);   // prefetch before compute
        bf16x8 af[4], bfr[FJ];
        #pragma unroll
        for (int i = 0; i < 4; ++i)
            af[i] = *reinterpret_cast<const bf16x8*>(As[cur] + (wm + i*16 + rr)*32 + rc);
        #pragma unroll
        for (int j = 0; j < FJ; ++j)
            bfr[j] = *reinterpret_cast<const bf16x8*>(Bs[cur] + (wn + j*16 + rr)*32 + rc);
        #pragma unroll
        for (int i = 0; i < 4; ++i)
            #pragma unroll
            for (int j = 0; j < FJ; ++j)
                acc[i][j] = __builtin_amdgcn_mfma_f32_16x16x32_bf16(af[i], bfr[j], acc[i][j], 0, 0, 0);
        __syncthreads();                             // drains prefetch too
        cur ^= 1;
    }
    gemm_epilogue<EPI, FJ>(acc, bias, extra, Cf, Cb, bm, bn, wm, wn, rr, g, N);
}

// conv GEMM: implicit im2col from bf16 image. M=4096, N=1024, K=3072, BN=64.
__global__ __launch_bounds__(256)
void gemm_conv_kernel(const bf16_t* __restrict__ timgb, const bf16_t* __restrict__ Bt,
                      const float* __restrict__ bias, bf16_t* __restrict__ Cb) {
    constexpr int BN = 64, WN = 32, FJ = 2;
    const int N = NF_, K = KCONV;
    __shared__ __align__(16) bf16_t As[2][128*32];
    __shared__ __align__(16) bf16_t Bs[2][BN*32];
    const int tid = threadIdx.x;
    const int bm = blockIdx.y * 128, bn = blockIdx.x * BN;
    const int lane = tid & 63, w = tid >> 6;
    const int rr = lane & 15, g = lane >> 4;
    const int wm = (w & 1) * 64, wn = (w >> 1) * WN;
    const int srow = tid >> 2;
    const int gc   = (((tid & 3) ^ ((srow >> 1) & 3)) * 8);
    const int rc   = (g ^ ((rr >> 1) & 3)) * 8;

    int row0 = bm + srow, row1 = bm + 64 + srow;
    int b0 = row0 >> 8, py0 = (row0 >> 4) & 15, px0 = row0 & 15;
    int b1 = row1 >> 8, py1 = (row1 >> 4) & 15, px1 = row1 & 15;
    size_t base0 = (size_t)b0*786432 + py0*16384 + px0*32 + gc;
    size_t base1 = (size_t)b1*786432 + py1*16384 + px1*32 + gc;
    const bf16_t* gB0 = Bt + (size_t)(bn + srow) * K + gc;

    auto STAGE = [&](int buf, int k0) {
        int c  = k0 >> 10;
        int ky = (k0 >> 5) & 31;
        size_t koff = (size_t)c*262144 + ky*512;
        gload16(timgb + base0 + koff, As[buf] + (w*16)*32);
        gload16(timgb + base1 + koff, As[buf] + (64 + w*16)*32);
        gload16(gB0 + k0, Bs[buf] + (w*16)*32);
    };

    f32x4 acc[4][FJ] = {};
    STAGE(0, 0);
    __syncthreads();
    int cur = 0;
    for (int k0 = 0; k0 < K; k0 += 32) {
        if (k0 + 32 < K) STAGE(cur ^ 1, k0 + 32);
        bf16x8 af[4], bfr[FJ];
        #pragma unroll
        for (int i = 0; i < 4; ++i)
            af[i] = *reinterpret_cast<const bf16x8*>(As[cur] + (wm + i*16 + rr)*32 + rc);
        #pragma unroll
        for (int j = 0; j < FJ; ++j)
            bfr[j] = *reinterpret_cast<const bf16x8*>(Bs[cur] + (wn + j*16 + rr)*32 + rc);
        #pragma unroll
        for (int i = 0; i < 4; ++i)
            #pragma unroll
            for (int j = 0; j < FJ; ++j)
                acc[i][j] = __builtin_amdgcn_mfma_f32_16x16x32_bf16(af[i], bfr[j], acc[i][j], 0, 0, 0);
        __syncthreads();
        cur ^= 1;
    }
    gemm_epilogue<EPI_CONV, FJ>(acc, bias, nullptr, nullptr, Cb, bm, bn, wm, wn, rr, g, N);
}

// ---------------------------------------------------------------------------
// layernorm rows of 768, fp32 in -> bf16 out
// ---------------------------------------------------------------------------
__global__ __launch_bounds__(256)
void ln_kernel(const float* __restrict__ x, const float* __restrict__ g,
               const float* __restrict__ be, bf16_t* __restrict__ out) {
    int r = blockIdx.x, tid = threadIdx.x;
    const float* xr = x + (size_t)r * EMB_;
    float v0 = xr[tid], v1 = xr[tid+256], v2 = xr[tid+512];
    float s = v0+v1+v2, s2 = v0*v0 + v1*v1 + v2*v2;
    __shared__ float red[8];
    #pragma unroll
    for (int off = 32; off; off >>= 1) { s += __shfl_xor(s, off); s2 += __shfl_xor(s2, off); }
    if ((tid & 63) == 0) { red[tid>>6] = s; red[4 + (tid>>6)] = s2; }
    __syncthreads();
    s  = red[0]+red[1]+red[2]+red[3];
    s2 = red[4]+red[5]+red[6]+red[7];
    float mean = s * (1.0f/768.0f);
    float var  = s2 * (1.0f/768.0f) - mean*mean;
    float rstd = rsqrtf(var + 1e-5f);
    bf16_t* orow = out + (size_t)r * EMB_;
    orow[tid]     = (bf16_t)((v0-mean)*rstd*g[tid]     + be[tid]);
    orow[tid+256] = (bf16_t)((v1-mean)*rstd*g[tid+256] + be[tid+256]);
    orow[tid+512] = (bf16_t)((v2-mean)*rstd*g[tid+512] + be[tid+512]);
}

// ---------------------------------------------------------------------------
// attention: MFMA flash-chunked (verified r5)
// ---------------------------------------------------------------------------
__global__ __launch_bounds__(256)
void attn_kernel5(const bf16_t* __restrict__ qkv, bf16_t* __restrict__ o) {
    __shared__ __align__(16) bf16_t Ks[256*72];
    __shared__ __align__(16) bf16_t Vt[64*264];
    __shared__ __align__(16) bf16_t Ps[4][64*72];
    const int tid  = threadIdx.x;
    const int lane = tid & 63, w = tid >> 6;
    const int rr   = lane & 15, g = lane >> 4;
    const int h = blockIdx.x % HEADS_;
    const int b = blockIdx.x / HEADS_;
    const bf16_t* base = qkv + (size_t)(b*256)*2304;

    {
        const bf16_t* kr = base + (size_t)tid*2304 + 768  + h*64;
        const bf16_t* vr = base + (size_t)tid*2304 + 1536 + h*64;
        bf16_t* kd = Ks + tid*72;
        #pragma unroll
        for (int c2 = 0; c2 < 8; ++c2) {
            *reinterpret_cast<bf16x8*>(kd + c2*8) =
                *reinterpret_cast<const bf16x8*>(kr + c2*8);
            bf16x8 v = *reinterpret_cast<const bf16x8*>(vr + c2*8);
            #pragma unroll
            for (int e = 0; e < 8; ++e)
                Vt[(c2*8 + e)*264 + tid] = v[e];
        }
    }

    bf16x8 qf[4][2];
    #pragma unroll
    for (int i = 0; i < 4; ++i)
        #pragma unroll
        for (int ks = 0; ks < 2; ++ks)
            qf[i][ks] = *reinterpret_cast<const bf16x8*>(
                base + (size_t)(w*64 + i*16 + rr)*2304 + h*64 + ks*32 + g*8);

    f32x4 oacc[4][4] = {};
    float lacc[4][4] = {};
    __syncthreads();

    bf16_t* Pw = Ps[w];
    for (int kc = 0; kc < 4; ++kc) {
        f32x4 sacc[4][4] = {};
        #pragma unroll
        for (int ks = 0; ks < 2; ++ks) {
            bf16x8 kf[4];
            #pragma unroll
            for (int j = 0; j < 4; ++j)
                kf[j] = *reinterpret_cast<const bf16x8*>(
                    Ks + (size_t)(kc*64 + j*16 + rr)*72 + ks*32 + g*8);
            #pragma unroll
            for (int i = 0; i < 4; ++i)
                #pragma unroll
                for (int j = 0; j < 4; ++j)
                    sacc[i][j] = __builtin_amdgcn_mfma_f32_16x16x32_bf16(
                        qf[i][ks], kf[j], sacc[i][j], 0, 0, 0);
        }
        #pragma unroll
        for (int i = 0; i < 4; ++i) {
            #pragma unroll
            for (int r = 0; r < 4; ++r) {
                int prow = i*16 + g*4 + r;
                float ps = 0.0f;
                #pragma unroll
                for (int j = 0; j < 4; ++j) {
                    float p = __expf(sacc[i][j][r] * 0.125f);
                    ps += p;
                    Pw[prow*72 + j*16 + rr] = (bf16_t)p;
                }
                lacc[i][r] += ps;
            }
        }
        #pragma unroll
        for (int ks = 0; ks < 2; ++ks) {
            bf16x8 pa[4], vb[4];
            #pragma unroll
            for (int i = 0; i < 4; ++i)
                pa[i] = *reinterpret_cast<const bf16x8*>(
                    Pw + (size_t)(i*16 + rr)*72 + ks*32 + g*8);
            #pragma unroll
            for (int n = 0; n < 4; ++n)
                vb[n] = *reinterpret_cast<const bf16x8*>(
                    Vt + (size_t)(n*16 + rr)*264 + kc*64 + ks*32 + g*8);
            #pragma unroll
            for (int i = 0; i < 4; ++i)
                #pragma unroll
                for (int n = 0; n < 4; ++n)
                    oacc[i][n] = __builtin_amdgcn_mfma_f32_16x16x32_bf16(
                        pa[i], vb[n], oacc[i][n], 0, 0, 0);
        }
    }

    #pragma unroll
    for (int i = 0; i < 4; ++i) {
        #pragma unroll
        for (int r = 0; r < 4; ++r) {
            float v = lacc[i][r];
            v += __shfl_xor(v, 1);
            v += __shfl_xor(v, 2);
            v += __shfl_xor(v, 4);
            v += __shfl_xor(v, 8);
            lacc[i][r] = 1.0f / v;
        }
    }
    #pragma unroll
    for (int i = 0; i < 4; ++i) {
        #pragma unroll
        for (int r = 0; r < 4; ++r) {
            int qrow = w*64 + i*16 + g*4 + r;
            bf16_t* orow = o + (size_t)(b*256 + qrow)*EMB_ + h*64;
            float inv = lacc[i][r];
            #pragma unroll
            for (int n = 0; n < 4; ++n)
                orow[n*16 + rr] = (bf16_t)(oacc[i][n][r] * inv);
        }
    }
}

// ---------------------------------------------------------------------------
// head (verified)
// ---------------------------------------------------------------------------
__global__ __launch_bounds__(256)
void head_kernel(const float* __restrict__ tok, const float* __restrict__ fcw,
                 const float* __restrict__ fcb, float* __restrict__ scores) {
    const int bx[6][4] = {{0,6,0,8},{4,11,0,8},{9,16,0,8},{0,6,8,16},{4,11,8,16},{9,16,8,16}};
    int box = blockIdx.x % 6, b = blockIdx.x / 6;
    int r0 = bx[box][0], r1 = bx[box][1], c0 = bx[box][2], c1 = bx[box][3];
    int rh = r1 - r0, rw = c1 - c0;
    __shared__ float wl[256];
    __shared__ float feats[768];
    __shared__ float red[4];
    int tid = threadIdx.x;
    int py = tid >> 4, px = tid & 15;
    float w = 0.0f;
    if (py >= r0 && py < r1 && px >= c0 && px < c1) {
        int ly = py - r0, lx = px - c0;
        float cy = 0.0f, cx = 0.0f;
        for (int o = 0; o < 16; ++o) {
            float sy = (o + 0.5f) * (float)rh * (1.0f/16.0f) - 0.5f;
            sy = fminf(fmaxf(sy, 0.0f), (float)(rh - 1));
            int i0 = (int)floorf(sy); float t = sy - (float)i0;
            if (ly == i0)     cy += 1.0f - t;
            if (ly == i0 + 1) cy += t;
            float sx = (o + 0.5f) * (float)rw * (1.0f/16.0f) - 0.5f;
            sx = fminf(fmaxf(sx, 0.0f), (float)(rw - 1));
            int j0 = (int)floorf(sx); float u = sx - (float)j0;
            if (lx == j0)     cx += 1.0f - u;
            if (lx == j0 + 1) cx += u;
        }
        w = (cy * (1.0f/16.0f)) * (cx * (1.0f/16.0f));
    }
    wl[tid] = w;
    __syncthreads();
    for (int e = tid; e < EMB_; e += 256) {
        float f = 0.0f;
        for (int iy = r0; iy < r1; ++iy)
            for (int ix = c0; ix < c1; ++ix) {
                int p = iy*16 + ix;
                f += wl[p] * tok[((size_t)(b*256 + p))*EMB_ + e];
            }
        feats[e] = f;
    }
    __syncthreads();
    float lg[4];
    #pragma unroll
    for (int cc = 0; cc < 4; ++cc) {
        float part = 0.0f;
        for (int e = tid; e < EMB_; e += 256) part += feats[e]*fcw[e*4 + cc];
        #pragma unroll
        for (int off = 32; off; off >>= 1) part += __shfl_xor(part, off);
        __syncthreads();
        if ((tid & 63) == 0) red[tid>>6] = part;
        __syncthreads();
        lg[cc] = red[0]+red[1]+red[2]+red[3] + fcb[cc];
    }
    if (tid == 0) {
        float mx = fmaxf(fmaxf(lg[0],lg[1]), fmaxf(lg[2],lg[3]));
        float e0 = expf(lg[0]-mx), e1 = expf(lg[1]-mx), e2 = expf(lg[2]-mx), e3 = expf(lg[3]-mx);
        float inv = 1.0f/(e0+e1+e2+e3);
        float* out = scores + (size_t)(b*6 + box)*4;
        out[0] = e0*inv; out[1] = e1*inv; out[2] = e2*inv; out[3] = e3*inv;
    }
}

// ===========================================================================
extern "C" void kernel_launch(void* const* d_in, const int* in_sizes, int n_in,
                              void* d_out, int out_size, void* d_ws, size_t ws_size,
                              hipStream_t stream) {
    (void)in_sizes; (void)n_in; (void)out_size; (void)ws_size;
    const float* x       = (const float*)d_in[0];
    const float* lm      = (const float*)d_in[1];
    const float* stn_w1  = (const float*)d_in[2];
    const float* stn_b1  = (const float*)d_in[3];
    const float* stn_w2  = (const float*)d_in[4];
    const float* stn_b2  = (const float*)d_in[5];
    const float* conv_w  = (const float*)d_in[6];
    const float* conv_b  = (const float*)d_in[7];
    const float* pe_w    = (const float*)d_in[8];
    const float* pe_b    = (const float*)d_in[9];
    const float* pos     = (const float*)d_in[10];
    const float* ln1_g   = (const float*)d_in[11];
    const float* ln1_b   = (const float*)d_in[12];
    const float* qkv_w   = (const float*)d_in[13];
    const float* qkv_b   = (const float*)d_in[14];
    const float* proj_w  = (const float*)d_in[15];
    const float* proj_b  = (const float*)d_in[16];
    const float* ln2_g   = (const float*)d_in[17];
    const float* ln2_b   = (const float*)d_in[18];
    const float* mlp_w1  = (const float*)d_in[19];
    const float* mlp_b1  = (const float*)d_in[20];
    const float* mlp_w2  = (const float*)d_in[21];
    const float* mlp_b2  = (const float*)d_in[22];
    const float* fc_w    = (const float*)d_in[23];
    const float* fc_b    = (const float*)d_in[24];

    float* out    = (float*)d_out;
    float* scores = out;
    float* timg   = out + 384;
    float* tmask  = out + 384 + (size_t)B_*3*HH*WW;

    char* ws = (char*)d_ws;
    size_t off = 0;
    auto alloc = [&](size_t bytes) {
        off = (off + 255) & ~(size_t)255;
        void* p = ws + off; off += bytes; return p;
    };
    // slotBig: seg(fp32,16MB) -> hidden(bf16,24MB)
    char*   slotBig = (char*)alloc(25165824);
    // slotT: timg_bf(25.2MB) -> qkvb(18.9MB)
    char*   slotT   = (char*)alloc((size_t)B_*3*HH*WW*2);
    // slotC: featC(8.4MB) -> obuf(6.3MB)
    char*   slotC   = (char*)alloc((size_t)M_*NF_*2);
    float*  tok     = (float*)alloc((size_t)M_*EMB_*4);
    bf16_t* tbuf    = (bf16_t*)alloc((size_t)M_*EMB_*2);
    bf16_t* conv_wb = (bf16_t*)alloc((size_t)NF_*KCONV*2);
    bf16_t* pe_wb   = (bf16_t*)alloc((size_t)EMB_*NF_*2);
    bf16_t* qkv_wb  = (bf16_t*)alloc((size_t)3*EMB_*EMB_*2);
    bf16_t* proj_wb = (bf16_t*)alloc((size_t)EMB_*EMB_*2);
    bf16_t* mlp1_wb = (bf16_t*)alloc((size_t)4*EMB_*EMB_*2);
    bf16_t* mlp2_wb = (bf16_t*)alloc((size_t)EMB_*4*EMB_*2);
    float*  pooled  = (float*)alloc(16384*4);
    float*  theta   = (float*)alloc(96*4);

    float*  seg    = (float*)slotBig;
    bf16_t* hidden = (bf16_t*)slotBig;
    bf16_t* timgb  = (bf16_t*)slotT;
    bf16_t* qkvb   = (bf16_t*)slotT;
    bf16_t* featC  = (bf16_t*)slotC;
    bf16_t* obuf   = (bf16_t*)slotC;

    // weight conversions (independent of data path)
    convert_bf16_kernel<<<(NF_*KCONV)/8/256, 256, 0, stream>>>(conv_w, conv_wb);
    transpose_bf16_kernel<<<dim3(EMB_/32, NF_/32),    256, 0, stream>>>(pe_w,   pe_wb,   NF_,  EMB_);
    transpose_bf16_kernel<<<dim3(3*EMB_/32, EMB_/32), 256, 0, stream>>>(qkv_w,  qkv_wb,  EMB_, 3*EMB_);
    transpose_bf16_kernel<<<dim3(EMB_/32, EMB_/32),   256, 0, stream>>>(proj_w, proj_wb, EMB_, EMB_);
    transpose_bf16_kernel<<<dim3(4*EMB_/32, EMB_/32), 256, 0, stream>>>(mlp_w1, mlp1_wb, EMB_, 4*EMB_);
    transpose_bf16_kernel<<<dim3(EMB_/32, 4*EMB_/32), 256, 0, stream>>>(mlp_w2, mlp2_wb, 4*EMB_, EMB_);

    // mask path
    hipMemsetAsync(seg, 0, (size_t)B_*HH*WW*sizeof(float), stream);
    raster_kernel<<<B_, 128, 0, stream>>>(lm, seg);
    pool_kernel<<<64, 256, 0, stream>>>(seg, pooled);
    stn_kernel<<<B_, 64, 0, stream>>>(pooled, stn_w1, stn_b1, stn_w2, stn_b2, theta);
    gridsample_kernel<<<(B_*HH*WW)/256, 256, 0, stream>>>(x, seg, theta, timg, tmask, timgb);

    // conv as implicit-im2col GEMM (BN=64 -> 512 blocks)
    gemm_conv_kernel<<<dim3(NF_/64, M_/128), 256, 0, stream>>>(
        timgb, conv_wb, conv_b, featC);

    // patch embed + pos -> tok (fp32 residual stream)  [N=768 -> BN=64, 384 blk]
    gemm_bf16_kernel<EPI_PE, 64><<<dim3(EMB_/64, M_/128), 256, 0, stream>>>(
        featC, pe_wb, pe_b, pos, tok, nullptr, M_, EMB_, NF_);

    // LN1 -> qkv  [N=2304 -> BN=128, 576 blk]
    ln_kernel<<<M_, 256, 0, stream>>>(tok, ln1_g, ln1_b, tbuf);
    gemm_bf16_kernel<EPI_QKV, 128><<<dim3(3*EMB_/128, M_/128), 256, 0, stream>>>(
        tbuf, qkv_wb, qkv_b, nullptr, nullptr, qkvb, M_, 3*EMB_, EMB_);

    // attention (MFMA)
    attn_kernel5<<<B_*HEADS_, 256, 0, stream>>>(qkvb, obuf);

    // proj + residual  [BN=64]
    gemm_bf16_kernel<EPI_PROJ, 64><<<dim3(EMB_/64, M_/128), 256, 0, stream>>>(
        obuf, proj_wb, proj_b, nullptr, tok, nullptr, M_, EMB_, EMB_);

    // LN2 -> mlp  [mlp1 N=3072 -> BN=128, 768 blk; mlp2 BN=64, 384 blk]
    ln_kernel<<<M_, 256, 0, stream>>>(tok, ln2_g, ln2_b, tbuf);
    gemm_bf16_kernel<EPI_GELU, 128><<<dim3(4*EMB_/128, M_/128), 256, 0, stream>>>(
        tbuf, mlp1_wb, mlp_b1, nullptr, nullptr, hidden, M_, 4*EMB_, EMB_);
    gemm_bf16_kernel<EPI_MLP2, 64><<<dim3(EMB_/64, M_/128), 256, 0, stream>>>(
        hidden, mlp2_wb, mlp_b2, nullptr, tok, nullptr, M_, EMB_, 4*EMB_);

    // head
    head_kernel<<<B_*6, 256, 0, stream>>>(tok, fc_w, fc_b, scores);
}

// Round 7
// 366.387 us; speedup vs baseline: 1.8758x; 1.1288x over previous
//
#include <hip/hip_runtime.h>
#include <hip/hip_bf16.h>
#include <cstdint>

// ============================================================================
// Hybrid e2e STN pipeline, round 7:
//  - GEMMs: 64x64 tiles (4 waves of 32x32), BK=64, double-buffered
//    global_load_lds staging, row&7 XOR swizzle (2-way, free),
//    bijective XCD-chunked block swizzle (A-panel L2 reuse)
//  - attention: MFMA flash (verified r5/r6)
// ============================================================================

#define B_    16
#define HH    512
#define WW    512
#define NF_   1024
#define EMB_  768
#define HEADS_ 12
#define NTOK  256
#define M_    (B_*NTOK)      // 4096
#define KCONV 3072

typedef __bf16 bf16_t;
typedef __bf16 bf16x8 __attribute__((ext_vector_type(8)));
typedef float  f32x4  __attribute__((ext_vector_type(4)));

typedef __attribute__((address_space(1))) const void* gas_t;
typedef __attribute__((address_space(3))) void* las_t;

__device__ __forceinline__ void gload16(const bf16_t* g, bf16_t* l) {
    __builtin_amdgcn_global_load_lds((gas_t)g, (las_t)l, 16, 0, 0);
}

__device__ __forceinline__ float tanh_fast(float x) {
    return 1.0f - 2.0f / (__expf(2.0f * x) + 1.0f);
}

// ---------------------------------------------------------------------------
// rasterize (verified)
// ---------------------------------------------------------------------------
__global__ __launch_bounds__(128)
void raster_kernel(const float* __restrict__ lm, float* __restrict__ seg) {
    int b = blockIdx.x;
    int s = threadIdx.x;
    if (s >= 117) return;
    int seg0 = (s < 43) ? s : ((s < 92) ? s + 1 : s + 2);
    const float* p = lm + (size_t)b * 240;
    int p1x = min(max((int)(p[seg0*2 + 0] * 512.0f), 0), 511);
    int p1y = min(max((int)(p[seg0*2 + 1] * 512.0f), 0), 511);
    int p2x = min(max((int)(p[(seg0+1)*2 + 0] * 512.0f), 0), 511);
    int p2y = min(max((int)(p[(seg0+1)*2 + 1] * 512.0f), 0), 511);
    int dy = p2y - p1y, dx = p2x - p1x;
    int kmax = min(dy, dx);
    float* sb = seg + (size_t)b * (HH*WW);
    for (int k = 0; k < kmax; ++k) {
        int yi = min(p1y + k, 511);
        int xi = min(p1x + k, 511);
        sb[yi*WW + xi] = 1.0f;
    }
}

// ---------------------------------------------------------------------------
// pool + stn (verified)
// ---------------------------------------------------------------------------
__global__ __launch_bounds__(256)
void pool_kernel(const float* __restrict__ seg, float* __restrict__ pooled) {
    int idx = blockIdx.x * 256 + threadIdx.x;
    int ox = idx & 31, oy = (idx >> 5) & 31, b = idx >> 10;
    const float* sb = seg + (size_t)b * (HH*WW) + (oy*16)*WW + ox*16;
    float s = 0.0f;
    for (int dy = 0; dy < 16; ++dy) {
        #pragma unroll
        for (int dx = 0; dx < 16; ++dx) s += sb[dy*WW + dx];
    }
    pooled[idx] = s * (1.0f/256.0f);
}

__global__ __launch_bounds__(64)
void stn_kernel(const float* __restrict__ pooled,
                const float* __restrict__ w1, const float* __restrict__ b1,
                const float* __restrict__ w2, const float* __restrict__ b2,
                float* __restrict__ theta) {
    __shared__ float pl[1024];
    __shared__ float hl[50];
    int b = blockIdx.x, tid = threadIdx.x;
    for (int i = tid; i < 1024; i += 64) pl[i] = pooled[b*1024 + i];
    __syncthreads();
    if (tid < 50) {
        float acc = b1[tid];
        for (int k = 0; k < 1024; ++k) acc += pl[k] * w1[k*50 + tid];
        hl[tid] = tanhf(acc);
    }
    __syncthreads();
    if (tid < 6) {
        float acc = b2[tid];
        for (int k = 0; k < 50; ++k) acc += hl[k] * w2[k*6 + tid];
        theta[b*6 + tid] = acc;
    }
}

// ---------------------------------------------------------------------------
// fused affine_grid + grid_sample; also emits bf16 copy of transformed img
// ---------------------------------------------------------------------------
__global__ __launch_bounds__(256)
void gridsample_kernel(const float* __restrict__ x, const float* __restrict__ seg,
                       const float* __restrict__ theta,
                       float* __restrict__ timg, float* __restrict__ tmask,
                       bf16_t* __restrict__ timgb) {
    size_t idx = (size_t)blockIdx.x * 256 + threadIdx.x;
    int xx = (int)(idx & 511);
    int yy = (int)((idx >> 9) & 511);
    int b  = (int)(idx >> 18);
    __shared__ float th[6];
    if (threadIdx.x < 6) th[threadIdx.x] = theta[b*6 + threadIdx.x];
    __syncthreads();
    float gx = (2.0f*xx + 1.0f) * (1.0f/512.0f) - 1.0f;
    float gy = (2.0f*yy + 1.0f) * (1.0f/512.0f) - 1.0f;
    float g0 = gx*th[0] + gy*th[1] + th[2];
    float g1 = gx*th[3] + gy*th[4] + th[5];
    float fx = ((g0 + 1.0f)*512.0f - 1.0f)*0.5f;
    float fy = ((g1 + 1.0f)*512.0f - 1.0f)*0.5f;
    float x0f = floorf(fx), y0f = floorf(fy);
    float wx1 = fx - x0f,  wy1 = fy - y0f;
    int ix0 = (int)x0f, iy0 = (int)y0f;
    int ix1 = ix0 + 1,  iy1 = iy0 + 1;
    float fy0ok = (iy0 >= 0 && iy0 < HH) ? 1.0f : 0.0f;
    float fy1ok = (iy1 >= 0 && iy1 < HH) ? 1.0f : 0.0f;
    float fx0ok = (ix0 >= 0 && ix0 < WW) ? 1.0f : 0.0f;
    float fx1ok = (ix1 >= 0 && ix1 < WW) ? 1.0f : 0.0f;
    float w00 = (1.0f-wy1)*(1.0f-wx1) * fy0ok * fx0ok;
    float w01 = (1.0f-wy1)*wx1        * fy0ok * fx1ok;
    float w10 = wy1*(1.0f-wx1)        * fy1ok * fx0ok;
    float w11 = wy1*wx1               * fy1ok * fx1ok;
    int cx0 = min(max(ix0,0),511), cx1 = min(max(ix1,0),511);
    int cy0 = min(max(iy0,0),511), cy1 = min(max(iy1,0),511);
    int i00 = cy0*WW + cx0, i01 = cy0*WW + cx1, i10 = cy1*WW + cx0, i11 = cy1*WW + cx1;
    size_t pix = (size_t)yy*WW + xx;
    #pragma unroll
    for (int c = 0; c < 3; ++c) {
        const float* pl = x + ((size_t)(b*3 + c)) * (HH*WW);
        float v = w00*pl[i00] + w01*pl[i01] + w10*pl[i10] + w11*pl[i11];
        timg [((size_t)(b*3 + c))*(HH*WW) + pix] = v;
        timgb[((size_t)(b*3 + c))*(HH*WW) + pix] = (bf16_t)v;
    }
    const float* sp = seg + (size_t)b * (HH*WW);
    float mv = w00*sp[i00] + w01*sp[i01] + w10*sp[i10] + w11*sp[i11];
    tmask[(size_t)b*(HH*WW) + pix] = mv;
}

// ---------------------------------------------------------------------------
// conversions
// ---------------------------------------------------------------------------
__global__ __launch_bounds__(256)
void convert_bf16_kernel(const float* __restrict__ in, bf16_t* __restrict__ out) {
    int idx = (blockIdx.x * 256 + threadIdx.x) * 8;
    float4 v0 = *reinterpret_cast<const float4*>(in + idx);
    float4 v1 = *reinterpret_cast<const float4*>(in + idx + 4);
    bf16x8 o;
    o[0]=(bf16_t)v0.x; o[1]=(bf16_t)v0.y; o[2]=(bf16_t)v0.z; o[3]=(bf16_t)v0.w;
    o[4]=(bf16_t)v1.x; o[5]=(bf16_t)v1.y; o[6]=(bf16_t)v1.z; o[7]=(bf16_t)v1.w;
    *reinterpret_cast<bf16x8*>(out + idx) = o;
}

__global__ __launch_bounds__(256)
void transpose_bf16_kernel(const float* __restrict__ in, bf16_t* __restrict__ out,
                           int K, int N) {   // in[K][N] -> out[N][K]
    __shared__ float tile[32][33];
    int bk = blockIdx.y * 32, bn = blockIdx.x * 32;
    int r = threadIdx.x >> 5, c = threadIdx.x & 31;
    #pragma unroll
    for (int i = 0; i < 4; ++i)
        tile[r + 8*i][c] = in[(size_t)(bk + r + 8*i) * N + bn + c];
    __syncthreads();
    #pragma unroll
    for (int i = 0; i < 4; ++i)
        out[(size_t)(bn + r + 8*i) * K + bk + c] = (bf16_t)tile[c][r + 8*i];
}

// ---------------------------------------------------------------------------
// bf16 MFMA GEMM round 7: 64x64 tile, BK=64, 4 waves of 32x32.
// LDS rows = 128B (32 banks exactly) -> slot^(row&7) swizzle = 2-way free.
// Staging: 2 x gload16 per matrix per buffer; swizzle on SOURCE column.
// Block swizzle: bijective XCD chunking (grid % 8 == 0 for all shapes),
// n-index fastest within chunk -> same-A-panel blocks run on one XCD.
// ---------------------------------------------------------------------------
enum { EPI_CONV=0, EPI_PE=1, EPI_QKV=2, EPI_PROJ=3, EPI_GELU=4, EPI_MLP2=5 };

template<int EPI>
__device__ __forceinline__ void gemm_epilogue64(
        f32x4 (&acc)[2][2], const float* bias, const float* extra,
        float* Cf, bf16_t* Cb, int bm, int bn, int wm, int wn,
        int rr, int g, int N) {
    #pragma unroll
    for (int i = 0; i < 2; ++i) {
        #pragma unroll
        for (int j = 0; j < 2; ++j) {
            #pragma unroll
            for (int r = 0; r < 4; ++r) {
                int m = bm + wm + i*16 + g*4 + r;
                int n = bn + wn + j*16 + rr;
                size_t o = (size_t)m * N + n;
                float v = acc[i][j][r] + bias[n];
                if (EPI == EPI_CONV) {
                    Cb[o] = (bf16_t)fmaxf(v, 0.0f);
                } else if (EPI == EPI_PE) {
                    Cf[o] = v + extra[(size_t)(m & 255)*N + n];
                } else if (EPI == EPI_QKV) {
                    Cb[o] = (bf16_t)v;
                } else if (EPI == EPI_PROJ || EPI == EPI_MLP2) {
                    Cf[o] = v + Cf[o];
                } else if (EPI == EPI_GELU) {
                    float u = v;
                    float gl = 0.5f*u*(1.0f + tanh_fast(0.7978845608028654f*(u + 0.044715f*u*u*u)));
                    Cb[o] = (bf16_t)gl;
                }
            }
        }
    }
}

template<int EPI>
__global__ __launch_bounds__(256)
void gemm64_kernel(const bf16_t* __restrict__ A, const bf16_t* __restrict__ Bt,
                   const float* __restrict__ bias, const float* __restrict__ extra,
                   float* __restrict__ Cf, bf16_t* __restrict__ Cb,
                   int M, int N, int K) {
    __shared__ __align__(16) bf16_t As[2][64*64];
    __shared__ __align__(16) bf16_t Bs[2][64*64];
    const int tid = threadIdx.x;
    const int nN   = N >> 6;
    const int nblk = (M >> 6) * nN;
    const int q    = nblk >> 3;
    const int id   = (blockIdx.x & 7) * q + (blockIdx.x >> 3);   // XCD chunk
    const int bm = (id / nN) * 64, bn = (id % nN) * 64;
    const int lane = tid & 63, w = tid >> 6;
    const int rr = lane & 15, g = lane >> 4;
    const int wm = (w & 1) * 32, wn = (w >> 1) * 32;
    const int sr = tid >> 3;                         // staging row 0..31
    const int sc = ((tid & 7) ^ (sr & 7)) * 8;       // swizzled source col
    const bf16_t* gA0 = A  + (size_t)(bm + sr)      * K + sc;
    const bf16_t* gA1 = A  + (size_t)(bm + 32 + sr) * K + sc;
    const bf16_t* gB0 = Bt + (size_t)(bn + sr)      * K + sc;
    const bf16_t* gB1 = Bt + (size_t)(bn + 32 + sr) * K + sc;

    auto STAGE = [&](int buf, int k0) {
        gload16(gA0 + k0, As[buf] + w*512);
        gload16(gA1 + k0, As[buf] + 2048 + w*512);
        gload16(gB0 + k0, Bs[buf] + w*512);
        gload16(gB1 + k0, Bs[buf] + 2048 + w*512);
    };

    const int s0 = (0*4 + g) ^ (rr & 7);   // read slots (k-sub 0/1)
    const int s1 = (1*4 + g) ^ (rr & 7);

    f32x4 acc[2][2] = {};
    STAGE(0, 0);
    __syncthreads();
    int cur = 0;
    for (int k0 = 0; k0 < K; k0 += 64) {
        if (k0 + 64 < K) STAGE(cur ^ 1, k0 + 64);
        bf16x8 af[2][2], bfv[2][2];
        #pragma unroll
        for (int i = 0; i < 2; ++i) {
            int ra = (wm + i*16 + rr) * 64;
            af[i][0] = *reinterpret_cast<const bf16x8*>(As[cur] + ra + s0*8);
            af[i][1] = *reinterpret_cast<const bf16x8*>(As[cur] + ra + s1*8);
            int rb = (wn + i*16 + rr) * 64;
            bfv[i][0] = *reinterpret_cast<const bf16x8*>(Bs[cur] + rb + s0*8);
            bfv[i][1] = *reinterpret_cast<const bf16x8*>(Bs[cur] + rb + s1*8);
        }
        #pragma unroll
        for (int ks = 0; ks < 2; ++ks)
            #pragma unroll
            for (int i = 0; i < 2; ++i)
                #pragma unroll
                for (int j = 0; j < 2; ++j)
                    acc[i][j] = __builtin_amdgcn_mfma_f32_16x16x32_bf16(
                        af[i][ks], bfv[j][ks], acc[i][j], 0, 0, 0);
        __syncthreads();
        cur ^= 1;
    }
    gemm_epilogue64<EPI>(acc, bias, extra, Cf, Cb, bm, bn, wm, wn, rr, g, N);
}

// conv GEMM: implicit im2col from bf16 image. M=4096, N=1024, K=3072.
__global__ __launch_bounds__(256)
void gemm_conv64_kernel(const bf16_t* __restrict__ timgb, const bf16_t* __restrict__ Bt,
                        const float* __restrict__ bias, bf16_t* __restrict__ Cb) {
    const int N = NF_, K = KCONV;
    __shared__ __align__(16) bf16_t As[2][64*64];
    __shared__ __align__(16) bf16_t Bs[2][64*64];
    const int tid = threadIdx.x;
    const int nN   = N >> 6;                 // 16
    const int nblk = (M_ >> 6) * nN;         // 1024
    const int q    = nblk >> 3;
    const int id   = (blockIdx.x & 7) * q + (blockIdx.x >> 3);
    const int bm = (id / nN) * 64, bn = (id % nN) * 64;
    const int lane = tid & 63, w = tid >> 6;
    const int rr = lane & 15, g = lane >> 4;
    const int wm = (w & 1) * 32, wn = (w >> 1) * 32;
    const int sr = tid >> 3;
    const int s  = (tid & 7) ^ (sr & 7);     // swizzled source slot 0..7
    // image offsets: k = k0 + s*8 + j -> c=k>>10, ky=(k>>5)&31, kx=k&31
    int row0 = bm + sr, row1 = bm + 32 + sr;
    int b0 = row0 >> 8, py0 = (row0 >> 4) & 15, px0 = row0 & 15;
    int b1 = row1 >> 8, py1 = (row1 >> 4) & 15, px1 = row1 & 15;
    size_t off0 = (size_t)b0*786432 + py0*16384 + px0*32 + (s>>2)*512 + (s&3)*8;
    size_t off1 = (size_t)b1*786432 + py1*16384 + px1*32 + (s>>2)*512 + (s&3)*8;
    const bf16_t* gB0 = Bt + (size_t)(bn + sr)      * K + s*8;
    const bf16_t* gB1 = Bt + (size_t)(bn + 32 + sr) * K + s*8;

    auto STAGE = [&](int buf, int k0) {
        int c   = k0 >> 10;
        int ky0 = (k0 >> 5) & 31;
        size_t koff = (size_t)c*262144 + (size_t)ky0*512;
        gload16(timgb + off0 + koff, As[buf] + w*512);
        gload16(timgb + off1 + koff, As[buf] + 2048 + w*512);
        gload16(gB0 + k0, Bs[buf] + w*512);
        gload16(gB1 + k0, Bs[buf] + 2048 + w*512);
    };

    const int s0 = (0*4 + g) ^ (rr & 7);
    const int s1 = (1*4 + g) ^ (rr & 7);

    f32x4 acc[2][2] = {};
    STAGE(0, 0);
    __syncthreads();
    int cur = 0;
    for (int k0 = 0; k0 < K; k0 += 64) {
        if (k0 + 64 < K) STAGE(cur ^ 1, k0 + 64);
        bf16x8 af[2][2], bfv[2][2];
        #pragma unroll
        for (int i = 0; i < 2; ++i) {
            int ra = (wm + i*16 + rr) * 64;
            af[i][0] = *reinterpret_cast<const bf16x8*>(As[cur] + ra + s0*8);
            af[i][1] = *reinterpret_cast<const bf16x8*>(As[cur] + ra + s1*8);
            int rb = (wn + i*16 + rr) * 64;
            bfv[i][0] = *reinterpret_cast<const bf16x8*>(Bs[cur] + rb + s0*8);
            bfv[i][1] = *reinterpret_cast<const bf16x8*>(Bs[cur] + rb + s1*8);
        }
        #pragma unroll
        for (int ks = 0; ks < 2; ++ks)
            #pragma unroll
            for (int i = 0; i < 2; ++i)
                #pragma unroll
                for (int j = 0; j < 2; ++j)
                    acc[i][j] = __builtin_amdgcn_mfma_f32_16x16x32_bf16(
                        af[i][ks], bfv[j][ks], acc[i][j], 0, 0, 0);
        __syncthreads();
        cur ^= 1;
    }
    gemm_epilogue64<EPI_CONV>(acc, bias, nullptr, nullptr, Cb, bm, bn, wm, wn, rr, g, N);
}

// ---------------------------------------------------------------------------
// layernorm rows of 768, fp32 in -> bf16 out
// ---------------------------------------------------------------------------
__global__ __launch_bounds__(256)
void ln_kernel(const float* __restrict__ x, const float* __restrict__ g,
               const float* __restrict__ be, bf16_t* __restrict__ out) {
    int r = blockIdx.x, tid = threadIdx.x;
    const float* xr = x + (size_t)r * EMB_;
    float v0 = xr[tid], v1 = xr[tid+256], v2 = xr[tid+512];
    float s = v0+v1+v2, s2 = v0*v0 + v1*v1 + v2*v2;
    __shared__ float red[8];
    #pragma unroll
    for (int off = 32; off; off >>= 1) { s += __shfl_xor(s, off); s2 += __shfl_xor(s2, off); }
    if ((tid & 63) == 0) { red[tid>>6] = s; red[4 + (tid>>6)] = s2; }
    __syncthreads();
    s  = red[0]+red[1]+red[2]+red[3];
    s2 = red[4]+red[5]+red[6]+red[7];
    float mean = s * (1.0f/768.0f);
    float var  = s2 * (1.0f/768.0f) - mean*mean;
    float rstd = rsqrtf(var + 1e-5f);
    bf16_t* orow = out + (size_t)r * EMB_;
    orow[tid]     = (bf16_t)((v0-mean)*rstd*g[tid]     + be[tid]);
    orow[tid+256] = (bf16_t)((v1-mean)*rstd*g[tid+256] + be[tid+256]);
    orow[tid+512] = (bf16_t)((v2-mean)*rstd*g[tid+512] + be[tid+512]);
}

// ---------------------------------------------------------------------------
// attention: MFMA flash-chunked (verified r5/r6)
// ---------------------------------------------------------------------------
__global__ __launch_bounds__(256)
void attn_kernel5(const bf16_t* __restrict__ qkv, bf16_t* __restrict__ o) {
    __shared__ __align__(16) bf16_t Ks[256*72];
    __shared__ __align__(16) bf16_t Vt[64*264];
    __shared__ __align__(16) bf16_t Ps[4][64*72];
    const int tid  = threadIdx.x;
    const int lane = tid & 63, w = tid >> 6;
    const int rr   = lane & 15, g = lane >> 4;
    const int h = blockIdx.x % HEADS_;
    const int b = blockIdx.x / HEADS_;
    const bf16_t* base = qkv + (size_t)(b*256)*2304;

    {
        const bf16_t* kr = base + (size_t)tid*2304 + 768  + h*64;
        const bf16_t* vr = base + (size_t)tid*2304 + 1536 + h*64;
        bf16_t* kd = Ks + tid*72;
        #pragma unroll
        for (int c2 = 0; c2 < 8; ++c2) {
            *reinterpret_cast<bf16x8*>(kd + c2*8) =
                *reinterpret_cast<const bf16x8*>(kr + c2*8);
            bf16x8 v = *reinterpret_cast<const bf16x8*>(vr + c2*8);
            #pragma unroll
            for (int e = 0; e < 8; ++e)
                Vt[(c2*8 + e)*264 + tid] = v[e];
        }
    }

    bf16x8 qf[4][2];
    #pragma unroll
    for (int i = 0; i < 4; ++i)
        #pragma unroll
        for (int ks = 0; ks < 2; ++ks)
            qf[i][ks] = *reinterpret_cast<const bf16x8*>(
                base + (size_t)(w*64 + i*16 + rr)*2304 + h*64 + ks*32 + g*8);

    f32x4 oacc[4][4] = {};
    float lacc[4][4] = {};
    __syncthreads();

    bf16_t* Pw = Ps[w];
    for (int kc = 0; kc < 4; ++kc) {
        f32x4 sacc[4][4] = {};
        #pragma unroll
        for (int ks = 0; ks < 2; ++ks) {
            bf16x8 kf[4];
            #pragma unroll
            for (int j = 0; j < 4; ++j)
                kf[j] = *reinterpret_cast<const bf16x8*>(
                    Ks + (size_t)(kc*64 + j*16 + rr)*72 + ks*32 + g*8);
            #pragma unroll
            for (int i = 0; i < 4; ++i)
                #pragma unroll
                for (int j = 0; j < 4; ++j)
                    sacc[i][j] = __builtin_amdgcn_mfma_f32_16x16x32_bf16(
                        qf[i][ks], kf[j], sacc[i][j], 0, 0, 0);
        }
        #pragma unroll
        for (int i = 0; i < 4; ++i) {
            #pragma unroll
            for (int r = 0; r < 4; ++r) {
                int prow = i*16 + g*4 + r;
                float ps = 0.0f;
                #pragma unroll
                for (int j = 0; j < 4; ++j) {
                    float p = __expf(sacc[i][j][r] * 0.125f);
                    ps += p;
                    Pw[prow*72 + j*16 + rr] = (bf16_t)p;
                }
                lacc[i][r] += ps;
            }
        }
        #pragma unroll
        for (int ks = 0; ks < 2; ++ks) {
            bf16x8 pa[4], vb[4];
            #pragma unroll
            for (int i = 0; i < 4; ++i)
                pa[i] = *reinterpret_cast<const bf16x8*>(
                    Pw + (size_t)(i*16 + rr)*72 + ks*32 + g*8);
            #pragma unroll
            for (int n = 0; n < 4; ++n)
                vb[n] = *reinterpret_cast<const bf16x8*>(
                    Vt + (size_t)(n*16 + rr)*264 + kc*64 + ks*32 + g*8);
            #pragma unroll
            for (int i = 0; i < 4; ++i)
                #pragma unroll
                for (int n = 0; n < 4; ++n)
                    oacc[i][n] = __builtin_amdgcn_mfma_f32_16x16x32_bf16(
                        pa[i], vb[n], oacc[i][n], 0, 0, 0);
        }
    }

    #pragma unroll
    for (int i = 0; i < 4; ++i) {
        #pragma unroll
        for (int r = 0; r < 4; ++r) {
            float v = lacc[i][r];
            v += __shfl_xor(v, 1);
            v += __shfl_xor(v, 2);
            v += __shfl_xor(v, 4);
            v += __shfl_xor(v, 8);
            lacc[i][r] = 1.0f / v;
        }
    }
    #pragma unroll
    for (int i = 0; i < 4; ++i) {
        #pragma unroll
        for (int r = 0; r < 4; ++r) {
            int qrow = w*64 + i*16 + g*4 + r;
            bf16_t* orow = o + (size_t)(b*256 + qrow)*EMB_ + h*64;
            float inv = lacc[i][r];
            #pragma unroll
            for (int n = 0; n < 4; ++n)
                orow[n*16 + rr] = (bf16_t)(oacc[i][n][r] * inv);
        }
    }
}

// ---------------------------------------------------------------------------
// head (verified)
// ---------------------------------------------------------------------------
__global__ __launch_bounds__(256)
void head_kernel(const float* __restrict__ tok, const float* __restrict__ fcw,
                 const float* __restrict__ fcb, float* __restrict__ scores) {
    const int bx[6][4] = {{0,6,0,8},{4,11,0,8},{9,16,0,8},{0,6,8,16},{4,11,8,16},{9,16,8,16}};
    int box = blockIdx.x % 6, b = blockIdx.x / 6;
    int r0 = bx[box][0], r1 = bx[box][1], c0 = bx[box][2], c1 = bx[box][3];
    int rh = r1 - r0, rw = c1 - c0;
    __shared__ float wl[256];
    __shared__ float feats[768];
    __shared__ float red[4];
    int tid = threadIdx.x;
    int py = tid >> 4, px = tid & 15;
    float w = 0.0f;
    if (py >= r0 && py < r1 && px >= c0 && px < c1) {
        int ly = py - r0, lx = px - c0;
        float cy = 0.0f, cx = 0.0f;
        for (int o = 0; o < 16; ++o) {
            float sy = (o + 0.5f) * (float)rh * (1.0f/16.0f) - 0.5f;
            sy = fminf(fmaxf(sy, 0.0f), (float)(rh - 1));
            int i0 = (int)floorf(sy); float t = sy - (float)i0;
            if (ly == i0)     cy += 1.0f - t;
            if (ly == i0 + 1) cy += t;
            float sx = (o + 0.5f) * (float)rw * (1.0f/16.0f) - 0.5f;
            sx = fminf(fmaxf(sx, 0.0f), (float)(rw - 1));
            int j0 = (int)floorf(sx); float u = sx - (float)j0;
            if (lx == j0)     cx += 1.0f - u;
            if (lx == j0 + 1) cx += u;
        }
        w = (cy * (1.0f/16.0f)) * (cx * (1.0f/16.0f));
    }
    wl[tid] = w;
    __syncthreads();
    for (int e = tid; e < EMB_; e += 256) {
        float f = 0.0f;
        for (int iy = r0; iy < r1; ++iy)
            for (int ix = c0; ix < c1; ++ix) {
                int p = iy*16 + ix;
                f += wl[p] * tok[((size_t)(b*256 + p))*EMB_ + e];
            }
        feats[e] = f;
    }
    __syncthreads();
    float lg[4];
    #pragma unroll
    for (int cc = 0; cc < 4; ++cc) {
        float part = 0.0f;
        for (int e = tid; e < EMB_; e += 256) part += feats[e]*fcw[e*4 + cc];
        #pragma unroll
        for (int off = 32; off; off >>= 1) part += __shfl_xor(part, off);
        __syncthreads();
        if ((tid & 63) == 0) red[tid>>6] = part;
        __syncthreads();
        lg[cc] = red[0]+red[1]+red[2]+red[3] + fcb[cc];
    }
    if (tid == 0) {
        float mx = fmaxf(fmaxf(lg[0],lg[1]), fmaxf(lg[2],lg[3]));
        float e0 = expf(lg[0]-mx), e1 = expf(lg[1]-mx), e2 = expf(lg[2]-mx), e3 = expf(lg[3]-mx);
        float inv = 1.0f/(e0+e1+e2+e3);
        float* out = scores + (size_t)(b*6 + box)*4;
        out[0] = e0*inv; out[1] = e1*inv; out[2] = e2*inv; out[3] = e3*inv;
    }
}

// ===========================================================================
extern "C" void kernel_launch(void* const* d_in, const int* in_sizes, int n_in,
                              void* d_out, int out_size, void* d_ws, size_t ws_size,
                              hipStream_t stream) {
    (void)in_sizes; (void)n_in; (void)out_size; (void)ws_size;
    const float* x       = (const float*)d_in[0];
    const float* lm      = (const float*)d_in[1];
    const float* stn_w1  = (const float*)d_in[2];
    const float* stn_b1  = (const float*)d_in[3];
    const float* stn_w2  = (const float*)d_in[4];
    const float* stn_b2  = (const float*)d_in[5];
    const float* conv_w  = (const float*)d_in[6];
    const float* conv_b  = (const float*)d_in[7];
    const float* pe_w    = (const float*)d_in[8];
    const float* pe_b    = (const float*)d_in[9];
    const float* pos     = (const float*)d_in[10];
    const float* ln1_g   = (const float*)d_in[11];
    const float* ln1_b   = (const float*)d_in[12];
    const float* qkv_w   = (const float*)d_in[13];
    const float* qkv_b   = (const float*)d_in[14];
    const float* proj_w  = (const float*)d_in[15];
    const float* proj_b  = (const float*)d_in[16];
    const float* ln2_g   = (const float*)d_in[17];
    const float* ln2_b   = (const float*)d_in[18];
    const float* mlp_w1  = (const float*)d_in[19];
    const float* mlp_b1  = (const float*)d_in[20];
    const float* mlp_w2  = (const float*)d_in[21];
    const float* mlp_b2  = (const float*)d_in[22];
    const float* fc_w    = (const float*)d_in[23];
    const float* fc_b    = (const float*)d_in[24];

    float* out    = (float*)d_out;
    float* scores = out;
    float* timg   = out + 384;
    float* tmask  = out + 384 + (size_t)B_*3*HH*WW;

    char* ws = (char*)d_ws;
    size_t off = 0;
    auto alloc = [&](size_t bytes) {
        off = (off + 255) & ~(size_t)255;
        void* p = ws + off; off += bytes; return p;
    };
    // slotBig: seg(fp32,16MB) -> hidden(bf16,24MB)
    char*   slotBig = (char*)alloc(25165824);
    // slotT: timg_bf(25.2MB) -> qkvb(18.9MB)
    char*   slotT   = (char*)alloc((size_t)B_*3*HH*WW*2);
    // slotC: featC(8.4MB) -> obuf(6.3MB)
    char*   slotC   = (char*)alloc((size_t)M_*NF_*2);
    float*  tok     = (float*)alloc((size_t)M_*EMB_*4);
    bf16_t* tbuf    = (bf16_t*)alloc((size_t)M_*EMB_*2);
    bf16_t* conv_wb = (bf16_t*)alloc((size_t)NF_*KCONV*2);
    bf16_t* pe_wb   = (bf16_t*)alloc((size_t)EMB_*NF_*2);
    bf16_t* qkv_wb  = (bf16_t*)alloc((size_t)3*EMB_*EMB_*2);
    bf16_t* proj_wb = (bf16_t*)alloc((size_t)EMB_*EMB_*2);
    bf16_t* mlp1_wb = (bf16_t*)alloc((size_t)4*EMB_*EMB_*2);
    bf16_t* mlp2_wb = (bf16_t*)alloc((size_t)EMB_*4*EMB_*2);
    float*  pooled  = (float*)alloc(16384*4);
    float*  theta   = (float*)alloc(96*4);

    float*  seg    = (float*)slotBig;
    bf16_t* hidden = (bf16_t*)slotBig;
    bf16_t* timgb  = (bf16_t*)slotT;
    bf16_t* qkvb   = (bf16_t*)slotT;
    bf16_t* featC  = (bf16_t*)slotC;
    bf16_t* obuf   = (bf16_t*)slotC;

    // weight conversions (independent of data path)
    convert_bf16_kernel<<<(NF_*KCONV)/8/256, 256, 0, stream>>>(conv_w, conv_wb);
    transpose_bf16_kernel<<<dim3(EMB_/32, NF_/32),    256, 0, stream>>>(pe_w,   pe_wb,   NF_,  EMB_);
    transpose_bf16_kernel<<<dim3(3*EMB_/32, EMB_/32), 256, 0, stream>>>(qkv_w,  qkv_wb,  EMB_, 3*EMB_);
    transpose_bf16_kernel<<<dim3(EMB_/32, EMB_/32),   256, 0, stream>>>(proj_w, proj_wb, EMB_, EMB_);
    transpose_bf16_kernel<<<dim3(4*EMB_/32, EMB_/32), 256, 0, stream>>>(mlp_w1, mlp1_wb, EMB_, 4*EMB_);
    transpose_bf16_kernel<<<dim3(EMB_/32, 4*EMB_/32), 256, 0, stream>>>(mlp_w2, mlp2_wb, 4*EMB_, EMB_);

    // mask path
    hipMemsetAsync(seg, 0, (size_t)B_*HH*WW*sizeof(float), stream);
    raster_kernel<<<B_, 128, 0, stream>>>(lm, seg);
    pool_kernel<<<64, 256, 0, stream>>>(seg, pooled);
    stn_kernel<<<B_, 64, 0, stream>>>(pooled, stn_w1, stn_b1, stn_w2, stn_b2, theta);
    gridsample_kernel<<<(B_*HH*WW)/256, 256, 0, stream>>>(x, seg, theta, timg, tmask, timgb);

    // conv as implicit-im2col GEMM (64x64 tiles, 1024 blocks)
    gemm_conv64_kernel<<<(M_/64)*(NF_/64), 256, 0, stream>>>(
        timgb, conv_wb, conv_b, featC);

    // patch embed + pos -> tok (fp32 residual stream)   [768 blocks]
    gemm64_kernel<EPI_PE><<<(M_/64)*(EMB_/64), 256, 0, stream>>>(
        featC, pe_wb, pe_b, pos, tok, nullptr, M_, EMB_, NF_);

    // LN1 -> qkv   [2304 blocks]
    ln_kernel<<<M_, 256, 0, stream>>>(tok, ln1_g, ln1_b, tbuf);
    gemm64_kernel<EPI_QKV><<<(M_/64)*(3*EMB_/64), 256, 0, stream>>>(
        tbuf, qkv_wb, qkv_b, nullptr, nullptr, qkvb, M_, 3*EMB_, EMB_);

    // attention (MFMA)
    attn_kernel5<<<B_*HEADS_, 256, 0, stream>>>(qkvb, obuf);

    // proj + residual   [768 blocks]
    gemm64_kernel<EPI_PROJ><<<(M_/64)*(EMB_/64), 256, 0, stream>>>(
        obuf, proj_wb, proj_b, nullptr, tok, nullptr, M_, EMB_, EMB_);

    // LN2 -> mlp   [mlp1 3072 blocks; mlp2 768 blocks]
    ln_kernel<<<M_, 256, 0, stream>>>(tok, ln2_g, ln2_b, tbuf);
    gemm64_kernel<EPI_GELU><<<(M_/64)*(4*EMB_/64), 256, 0, stream>>>(
        tbuf, mlp1_wb, mlp_b1, nullptr, nullptr, hidden, M_, 4*EMB_, EMB_);
    gemm64_kernel<EPI_MLP2><<<(M_/64)*(EMB_/64), 256, 0, stream>>>(
        hidden, mlp2_wb, mlp_b2, nullptr, tok, nullptr, M_, EMB_, 4*EMB_);

    // head
    head_kernel<<<B_*6, 256, 0, stream>>>(tok, fc_w, fc_b, scores);
}

// Round 8
// 339.608 us; speedup vs baseline: 2.0237x; 1.0789x over previous
//
#include <hip/hip_runtime.h>
#include <hip/hip_bf16.h>
#include <cstdint>

// ============================================================================
// Hybrid e2e STN pipeline, round 8:
//  - stn MLP parallelized (was 61us latency-bound single-wave loop: r7 PMC
//    Occupancy 0.17%, VALUBusy 0.05%) -> w1 transposed + 16-wave reduction
//  - GEMMs / attention / rest identical to verified round 7
// ============================================================================

#define B_    16
#define HH    512
#define WW    512
#define NF_   1024
#define EMB_  768
#define HEADS_ 12
#define NTOK  256
#define M_    (B_*NTOK)      // 4096
#define KCONV 3072

typedef __bf16 bf16_t;
typedef __bf16 bf16x8 __attribute__((ext_vector_type(8)));
typedef float  f32x4  __attribute__((ext_vector_type(4)));

typedef __attribute__((address_space(1))) const void* gas_t;
typedef __attribute__((address_space(3))) void* las_t;

__device__ __forceinline__ void gload16(const bf16_t* g, bf16_t* l) {
    __builtin_amdgcn_global_load_lds((gas_t)g, (las_t)l, 16, 0, 0);
}

__device__ __forceinline__ float tanh_fast(float x) {
    return 1.0f - 2.0f / (__expf(2.0f * x) + 1.0f);
}

// ---------------------------------------------------------------------------
// rasterize (verified)
// ---------------------------------------------------------------------------
__global__ __launch_bounds__(128)
void raster_kernel(const float* __restrict__ lm, float* __restrict__ seg) {
    int b = blockIdx.x;
    int s = threadIdx.x;
    if (s >= 117) return;
    int seg0 = (s < 43) ? s : ((s < 92) ? s + 1 : s + 2);
    const float* p = lm + (size_t)b * 240;
    int p1x = min(max((int)(p[seg0*2 + 0] * 512.0f), 0), 511);
    int p1y = min(max((int)(p[seg0*2 + 1] * 512.0f), 0), 511);
    int p2x = min(max((int)(p[(seg0+1)*2 + 0] * 512.0f), 0), 511);
    int p2y = min(max((int)(p[(seg0+1)*2 + 1] * 512.0f), 0), 511);
    int dy = p2y - p1y, dx = p2x - p1x;
    int kmax = min(dy, dx);
    float* sb = seg + (size_t)b * (HH*WW);
    for (int k = 0; k < kmax; ++k) {
        int yi = min(p1y + k, 511);
        int xi = min(p1x + k, 511);
        sb[yi*WW + xi] = 1.0f;
    }
}

// ---------------------------------------------------------------------------
// pool (verified)
// ---------------------------------------------------------------------------
__global__ __launch_bounds__(256)
void pool_kernel(const float* __restrict__ seg, float* __restrict__ pooled) {
    int idx = blockIdx.x * 256 + threadIdx.x;
    int ox = idx & 31, oy = (idx >> 5) & 31, b = idx >> 10;
    const float* sb = seg + (size_t)b * (HH*WW) + (oy*16)*WW + ox*16;
    float s = 0.0f;
    for (int dy = 0; dy < 16; ++dy) {
        #pragma unroll
        for (int dx = 0; dx < 16; ++dx) s += sb[dy*WW + dx];
    }
    pooled[idx] = s * (1.0f/256.0f);
}

// ---------------------------------------------------------------------------
// w1 transpose (fp32): in[k*50+j] -> out[j*1024+k]
// ---------------------------------------------------------------------------
__global__ __launch_bounds__(256)
void transpose_w1_kernel(const float* __restrict__ in, float* __restrict__ out) {
    int idx = blockIdx.x * 256 + threadIdx.x;     // 50*1024 = 51200
    int j = idx >> 10, k = idx & 1023;
    out[idx] = in[k*50 + j];
}

// ---------------------------------------------------------------------------
// stn round 8: 16 blocks x 1024 threads (16 waves).
// wave w computes hidden units j = w + 16p (p=0..3, j<50): 64-lane coalesced
// reduction over k, shuffle-reduce, tanh. Then 6 threads finish theta.
// ---------------------------------------------------------------------------
__global__ __launch_bounds__(1024)
void stn2_kernel(const float* __restrict__ pooled, const float* __restrict__ w1t,
                 const float* __restrict__ b1, const float* __restrict__ w2,
                 const float* __restrict__ b2, float* __restrict__ theta) {
    __shared__ float pl[1024];
    __shared__ float hl[56];
    int b = blockIdx.x, tid = threadIdx.x;
    pl[tid] = pooled[b*1024 + tid];
    __syncthreads();
    int wave = tid >> 6, lane = tid & 63;
    #pragma unroll
    for (int p = 0; p < 4; ++p) {
        int j = wave + (p << 4);
        if (j < 50) {
            const float* wr = w1t + j*1024;
            float acc = 0.0f;
            #pragma unroll
            for (int i = 0; i < 16; ++i) {
                int k = lane + (i << 6);
                acc = fmaf(pl[k], wr[k], acc);
            }
            #pragma unroll
            for (int off = 32; off; off >>= 1) acc += __shfl_xor(acc, off);
            if (lane == 0) hl[j] = tanhf(acc + b1[j]);
        }
    }
    __syncthreads();
    if (tid < 6) {
        float acc = b2[tid];
        for (int k = 0; k < 50; ++k) acc = fmaf(hl[k], w2[k*6 + tid], acc);
        theta[b*6 + tid] = acc;
    }
}

// ---------------------------------------------------------------------------
// fused affine_grid + grid_sample; also emits bf16 copy of transformed img
// ---------------------------------------------------------------------------
__global__ __launch_bounds__(256)
void gridsample_kernel(const float* __restrict__ x, const float* __restrict__ seg,
                       const float* __restrict__ theta,
                       float* __restrict__ timg, float* __restrict__ tmask,
                       bf16_t* __restrict__ timgb) {
    size_t idx = (size_t)blockIdx.x * 256 + threadIdx.x;
    int xx = (int)(idx & 511);
    int yy = (int)((idx >> 9) & 511);
    int b  = (int)(idx >> 18);
    __shared__ float th[6];
    if (threadIdx.x < 6) th[threadIdx.x] = theta[b*6 + threadIdx.x];
    __syncthreads();
    float gx = (2.0f*xx + 1.0f) * (1.0f/512.0f) - 1.0f;
    float gy = (2.0f*yy + 1.0f) * (1.0f/512.0f) - 1.0f;
    float g0 = gx*th[0] + gy*th[1] + th[2];
    float g1 = gx*th[3] + gy*th[4] + th[5];
    float fx = ((g0 + 1.0f)*512.0f - 1.0f)*0.5f;
    float fy = ((g1 + 1.0f)*512.0f - 1.0f)*0.5f;
    float x0f = floorf(fx), y0f = floorf(fy);
    float wx1 = fx - x0f,  wy1 = fy - y0f;
    int ix0 = (int)x0f, iy0 = (int)y0f;
    int ix1 = ix0 + 1,  iy1 = iy0 + 1;
    float fy0ok = (iy0 >= 0 && iy0 < HH) ? 1.0f : 0.0f;
    float fy1ok = (iy1 >= 0 && iy1 < HH) ? 1.0f : 0.0f;
    float fx0ok = (ix0 >= 0 && ix0 < WW) ? 1.0f : 0.0f;
    float fx1ok = (ix1 >= 0 && ix1 < WW) ? 1.0f : 0.0f;
    float w00 = (1.0f-wy1)*(1.0f-wx1) * fy0ok * fx0ok;
    float w01 = (1.0f-wy1)*wx1        * fy0ok * fx1ok;
    float w10 = wy1*(1.0f-wx1)        * fy1ok * fx0ok;
    float w11 = wy1*wx1               * fy1ok * fx1ok;
    int cx0 = min(max(ix0,0),511), cx1 = min(max(ix1,0),511);
    int cy0 = min(max(iy0,0),511), cy1 = min(max(iy1,0),511);
    int i00 = cy0*WW + cx0, i01 = cy0*WW + cx1, i10 = cy1*WW + cx0, i11 = cy1*WW + cx1;
    size_t pix = (size_t)yy*WW + xx;
    #pragma unroll
    for (int c = 0; c < 3; ++c) {
        const float* pl = x + ((size_t)(b*3 + c)) * (HH*WW);
        float v = w00*pl[i00] + w01*pl[i01] + w10*pl[i10] + w11*pl[i11];
        timg [((size_t)(b*3 + c))*(HH*WW) + pix] = v;
        timgb[((size_t)(b*3 + c))*(HH*WW) + pix] = (bf16_t)v;
    }
    const float* sp = seg + (size_t)b * (HH*WW);
    float mv = w00*sp[i00] + w01*sp[i01] + w10*sp[i10] + w11*sp[i11];
    tmask[(size_t)b*(HH*WW) + pix] = mv;
}

// ---------------------------------------------------------------------------
// conversions
// ---------------------------------------------------------------------------
__global__ __launch_bounds__(256)
void convert_bf16_kernel(const float* __restrict__ in, bf16_t* __restrict__ out) {
    int idx = (blockIdx.x * 256 + threadIdx.x) * 8;
    float4 v0 = *reinterpret_cast<const float4*>(in + idx);
    float4 v1 = *reinterpret_cast<const float4*>(in + idx + 4);
    bf16x8 o;
    o[0]=(bf16_t)v0.x; o[1]=(bf16_t)v0.y; o[2]=(bf16_t)v0.z; o[3]=(bf16_t)v0.w;
    o[4]=(bf16_t)v1.x; o[5]=(bf16_t)v1.y; o[6]=(bf16_t)v1.z; o[7]=(bf16_t)v1.w;
    *reinterpret_cast<bf16x8*>(out + idx) = o;
}

__global__ __launch_bounds__(256)
void transpose_bf16_kernel(const float* __restrict__ in, bf16_t* __restrict__ out,
                           int K, int N) {   // in[K][N] -> out[N][K]
    __shared__ float tile[32][33];
    int bk = blockIdx.y * 32, bn = blockIdx.x * 32;
    int r = threadIdx.x >> 5, c = threadIdx.x & 31;
    #pragma unroll
    for (int i = 0; i < 4; ++i)
        tile[r + 8*i][c] = in[(size_t)(bk + r + 8*i) * N + bn + c];
    __syncthreads();
    #pragma unroll
    for (int i = 0; i < 4; ++i)
        out[(size_t)(bn + r + 8*i) * K + bk + c] = (bf16_t)tile[c][r + 8*i];
}

// ---------------------------------------------------------------------------
// bf16 MFMA GEMM round 7 structure (verified): 64x64 tile, BK=64,
// 4 waves of 32x32, row&7 XOR swizzle, XCD-chunked block swizzle.
// ---------------------------------------------------------------------------
enum { EPI_CONV=0, EPI_PE=1, EPI_QKV=2, EPI_PROJ=3, EPI_GELU=4, EPI_MLP2=5 };

template<int EPI>
__device__ __forceinline__ void gemm_epilogue64(
        f32x4 (&acc)[2][2], const float* bias, const float* extra,
        float* Cf, bf16_t* Cb, int bm, int bn, int wm, int wn,
        int rr, int g, int N) {
    #pragma unroll
    for (int i = 0; i < 2; ++i) {
        #pragma unroll
        for (int j = 0; j < 2; ++j) {
            #pragma unroll
            for (int r = 0; r < 4; ++r) {
                int m = bm + wm + i*16 + g*4 + r;
                int n = bn + wn + j*16 + rr;
                size_t o = (size_t)m * N + n;
                float v = acc[i][j][r] + bias[n];
                if (EPI == EPI_CONV) {
                    Cb[o] = (bf16_t)fmaxf(v, 0.0f);
                } else if (EPI == EPI_PE) {
                    Cf[o] = v + extra[(size_t)(m & 255)*N + n];
                } else if (EPI == EPI_QKV) {
                    Cb[o] = (bf16_t)v;
                } else if (EPI == EPI_PROJ || EPI == EPI_MLP2) {
                    Cf[o] = v + Cf[o];
                } else if (EPI == EPI_GELU) {
                    float u = v;
                    float gl = 0.5f*u*(1.0f + tanh_fast(0.7978845608028654f*(u + 0.044715f*u*u*u)));
                    Cb[o] = (bf16_t)gl;
                }
            }
        }
    }
}

template<int EPI>
__global__ __launch_bounds__(256)
void gemm64_kernel(const bf16_t* __restrict__ A, const bf16_t* __restrict__ Bt,
                   const float* __restrict__ bias, const float* __restrict__ extra,
                   float* __restrict__ Cf, bf16_t* __restrict__ Cb,
                   int M, int N, int K) {
    __shared__ __align__(16) bf16_t As[2][64*64];
    __shared__ __align__(16) bf16_t Bs[2][64*64];
    const int tid = threadIdx.x;
    const int nN   = N >> 6;
    const int nblk = (M >> 6) * nN;
    const int q    = nblk >> 3;
    const int id   = (blockIdx.x & 7) * q + (blockIdx.x >> 3);   // XCD chunk
    const int bm = (id / nN) * 64, bn = (id % nN) * 64;
    const int lane = tid & 63, w = tid >> 6;
    const int rr = lane & 15, g = lane >> 4;
    const int wm = (w & 1) * 32, wn = (w >> 1) * 32;
    const int sr = tid >> 3;                         // staging row 0..31
    const int sc = ((tid & 7) ^ (sr & 7)) * 8;       // swizzled source col
    const bf16_t* gA0 = A  + (size_t)(bm + sr)      * K + sc;
    const bf16_t* gA1 = A  + (size_t)(bm + 32 + sr) * K + sc;
    const bf16_t* gB0 = Bt + (size_t)(bn + sr)      * K + sc;
    const bf16_t* gB1 = Bt + (size_t)(bn + 32 + sr) * K + sc;

    auto STAGE = [&](int buf, int k0) {
        gload16(gA0 + k0, As[buf] + w*512);
        gload16(gA1 + k0, As[buf] + 2048 + w*512);
        gload16(gB0 + k0, Bs[buf] + w*512);
        gload16(gB1 + k0, Bs[buf] + 2048 + w*512);
    };

    const int s0 = (0*4 + g) ^ (rr & 7);
    const int s1 = (1*4 + g) ^ (rr & 7);

    f32x4 acc[2][2] = {};
    STAGE(0, 0);
    __syncthreads();
    int cur = 0;
    for (int k0 = 0; k0 < K; k0 += 64) {
        if (k0 + 64 < K) STAGE(cur ^ 1, k0 + 64);
        bf16x8 af[2][2], bfv[2][2];
        #pragma unroll
        for (int i = 0; i < 2; ++i) {
            int ra = (wm + i*16 + rr) * 64;
            af[i][0] = *reinterpret_cast<const bf16x8*>(As[cur] + ra + s0*8);
            af[i][1] = *reinterpret_cast<const bf16x8*>(As[cur] + ra + s1*8);
            int rb = (wn + i*16 + rr) * 64;
            bfv[i][0] = *reinterpret_cast<const bf16x8*>(Bs[cur] + rb + s0*8);
            bfv[i][1] = *reinterpret_cast<const bf16x8*>(Bs[cur] + rb + s1*8);
        }
        #pragma unroll
        for (int ks = 0; ks < 2; ++ks)
            #pragma unroll
            for (int i = 0; i < 2; ++i)
                #pragma unroll
                for (int j = 0; j < 2; ++j)
                    acc[i][j] = __builtin_amdgcn_mfma_f32_16x16x32_bf16(
                        af[i][ks], bfv[j][ks], acc[i][j], 0, 0, 0);
        __syncthreads();
        cur ^= 1;
    }
    gemm_epilogue64<EPI>(acc, bias, extra, Cf, Cb, bm, bn, wm, wn, rr, g, N);
}

// conv GEMM: implicit im2col from bf16 image. M=4096, N=1024, K=3072.
__global__ __launch_bounds__(256)
void gemm_conv64_kernel(const bf16_t* __restrict__ timgb, const bf16_t* __restrict__ Bt,
                        const float* __restrict__ bias, bf16_t* __restrict__ Cb) {
    const int N = NF_, K = KCONV;
    __shared__ __align__(16) bf16_t As[2][64*64];
    __shared__ __align__(16) bf16_t Bs[2][64*64];
    const int tid = threadIdx.x;
    const int nN   = N >> 6;                 // 16
    const int nblk = (M_ >> 6) * nN;         // 1024
    const int q    = nblk >> 3;
    const int id   = (blockIdx.x & 7) * q + (blockIdx.x >> 3);
    const int bm = (id / nN) * 64, bn = (id % nN) * 64;
    const int lane = tid & 63, w = tid >> 6;
    const int rr = lane & 15, g = lane >> 4;
    const int wm = (w & 1) * 32, wn = (w >> 1) * 32;
    const int sr = tid >> 3;
    const int s  = (tid & 7) ^ (sr & 7);
    int row0 = bm + sr, row1 = bm + 32 + sr;
    int b0 = row0 >> 8, py0 = (row0 >> 4) & 15, px0 = row0 & 15;
    int b1 = row1 >> 8, py1 = (row1 >> 4) & 15, px1 = row1 & 15;
    size_t off0 = (size_t)b0*786432 + py0*16384 + px0*32 + (s>>2)*512 + (s&3)*8;
    size_t off1 = (size_t)b1*786432 + py1*16384 + px1*32 + (s>>2)*512 + (s&3)*8;
    const bf16_t* gB0 = Bt + (size_t)(bn + sr)      * K + s*8;
    const bf16_t* gB1 = Bt + (size_t)(bn + 32 + sr) * K + s*8;

    auto STAGE = [&](int buf, int k0) {
        int c   = k0 >> 10;
        int ky0 = (k0 >> 5) & 31;
        size_t koff = (size_t)c*262144 + (size_t)ky0*512;
        gload16(timgb + off0 + koff, As[buf] + w*512);
        gload16(timgb + off1 + koff, As[buf] + 2048 + w*512);
        gload16(gB0 + k0, Bs[buf] + w*512);
        gload16(gB1 + k0, Bs[buf] + 2048 + w*512);
    };

    const int s0 = (0*4 + g) ^ (rr & 7);
    const int s1 = (1*4 + g) ^ (rr & 7);

    f32x4 acc[2][2] = {};
    STAGE(0, 0);
    __syncthreads();
    int cur = 0;
    for (int k0 = 0; k0 < K; k0 += 64) {
        if (k0 + 64 < K) STAGE(cur ^ 1, k0 + 64);
        bf16x8 af[2][2], bfv[2][2];
        #pragma unroll
        for (int i = 0; i < 2; ++i) {
            int ra = (wm + i*16 + rr) * 64;
            af[i][0] = *reinterpret_cast<const bf16x8*>(As[cur] + ra + s0*8);
            af[i][1] = *reinterpret_cast<const bf16x8*>(As[cur] + ra + s1*8);
            int rb = (wn + i*16 + rr) * 64;
            bfv[i][0] = *reinterpret_cast<const bf16x8*>(Bs[cur] + rb + s0*8);
            bfv[i][1] = *reinterpret_cast<const bf16x8*>(Bs[cur] + rb + s1*8);
        }
        #pragma unroll
        for (int ks = 0; ks < 2; ++ks)
            #pragma unroll
            for (int i = 0; i < 2; ++i)
                #pragma unroll
                for (int j = 0; j < 2; ++j)
                    acc[i][j] = __builtin_amdgcn_mfma_f32_16x16x32_bf16(
                        af[i][ks], bfv[j][ks], acc[i][j], 0, 0, 0);
        __syncthreads();
        cur ^= 1;
    }
    gemm_epilogue64<EPI_CONV>(acc, bias, nullptr, nullptr, Cb, bm, bn, wm, wn, rr, g, N);
}

// ---------------------------------------------------------------------------
// layernorm rows of 768, fp32 in -> bf16 out
// ---------------------------------------------------------------------------
__global__ __launch_bounds__(256)
void ln_kernel(const float* __restrict__ x, const float* __restrict__ g,
               const float* __restrict__ be, bf16_t* __restrict__ out) {
    int r = blockIdx.x, tid = threadIdx.x;
    const float* xr = x + (size_t)r * EMB_;
    float v0 = xr[tid], v1 = xr[tid+256], v2 = xr[tid+512];
    float s = v0+v1+v2, s2 = v0*v0 + v1*v1 + v2*v2;
    __shared__ float red[8];
    #pragma unroll
    for (int off = 32; off; off >>= 1) { s += __shfl_xor(s, off); s2 += __shfl_xor(s2, off); }
    if ((tid & 63) == 0) { red[tid>>6] = s; red[4 + (tid>>6)] = s2; }
    __syncthreads();
    s  = red[0]+red[1]+red[2]+red[3];
    s2 = red[4]+red[5]+red[6]+red[7];
    float mean = s * (1.0f/768.0f);
    float var  = s2 * (1.0f/768.0f) - mean*mean;
    float rstd = rsqrtf(var + 1e-5f);
    bf16_t* orow = out + (size_t)r * EMB_;
    orow[tid]     = (bf16_t)((v0-mean)*rstd*g[tid]     + be[tid]);
    orow[tid+256] = (bf16_t)((v1-mean)*rstd*g[tid+256] + be[tid+256]);
    orow[tid+512] = (bf16_t)((v2-mean)*rstd*g[tid+512] + be[tid+512]);
}

// ---------------------------------------------------------------------------
// attention: MFMA flash-chunked (verified r5-r7)
// ---------------------------------------------------------------------------
__global__ __launch_bounds__(256)
void attn_kernel5(const bf16_t* __restrict__ qkv, bf16_t* __restrict__ o) {
    __shared__ __align__(16) bf16_t Ks[256*72];
    __shared__ __align__(16) bf16_t Vt[64*264];
    __shared__ __align__(16) bf16_t Ps[4][64*72];
    const int tid  = threadIdx.x;
    const int lane = tid & 63, w = tid >> 6;
    const int rr   = lane & 15, g = lane >> 4;
    const int h = blockIdx.x % HEADS_;
    const int b = blockIdx.x / HEADS_;
    const bf16_t* base = qkv + (size_t)(b*256)*2304;

    {
        const bf16_t* kr = base + (size_t)tid*2304 + 768  + h*64;
        const bf16_t* vr = base + (size_t)tid*2304 + 1536 + h*64;
        bf16_t* kd = Ks + tid*72;
        #pragma unroll
        for (int c2 = 0; c2 < 8; ++c2) {
            *reinterpret_cast<bf16x8*>(kd + c2*8) =
                *reinterpret_cast<const bf16x8*>(kr + c2*8);
            bf16x8 v = *reinterpret_cast<const bf16x8*>(vr + c2*8);
            #pragma unroll
            for (int e = 0; e < 8; ++e)
                Vt[(c2*8 + e)*264 + tid] = v[e];
        }
    }

    bf16x8 qf[4][2];
    #pragma unroll
    for (int i = 0; i < 4; ++i)
        #pragma unroll
        for (int ks = 0; ks < 2; ++ks)
            qf[i][ks] = *reinterpret_cast<const bf16x8*>(
                base + (size_t)(w*64 + i*16 + rr)*2304 + h*64 + ks*32 + g*8);

    f32x4 oacc[4][4] = {};
    float lacc[4][4] = {};
    __syncthreads();

    bf16_t* Pw = Ps[w];
    for (int kc = 0; kc < 4; ++kc) {
        f32x4 sacc[4][4] = {};
        #pragma unroll
        for (int ks = 0; ks < 2; ++ks) {
            bf16x8 kf[4];
            #pragma unroll
            for (int j = 0; j < 4; ++j)
                kf[j] = *reinterpret_cast<const bf16x8*>(
                    Ks + (size_t)(kc*64 + j*16 + rr)*72 + ks*32 + g*8);
            #pragma unroll
            for (int i = 0; i < 4; ++i)
                #pragma unroll
                for (int j = 0; j < 4; ++j)
                    sacc[i][j] = __builtin_amdgcn_mfma_f32_16x16x32_bf16(
                        qf[i][ks], kf[j], sacc[i][j], 0, 0, 0);
        }
        #pragma unroll
        for (int i = 0; i < 4; ++i) {
            #pragma unroll
            for (int r = 0; r < 4; ++r) {
                int prow = i*16 + g*4 + r;
                float ps = 0.0f;
                #pragma unroll
                for (int j = 0; j < 4; ++j) {
                    float p = __expf(sacc[i][j][r] * 0.125f);
                    ps += p;
                    Pw[prow*72 + j*16 + rr] = (bf16_t)p;
                }
                lacc[i][r] += ps;
            }
        }
        #pragma unroll
        for (int ks = 0; ks < 2; ++ks) {
            bf16x8 pa[4], vb[4];
            #pragma unroll
            for (int i = 0; i < 4; ++i)
                pa[i] = *reinterpret_cast<const bf16x8*>(
                    Pw + (size_t)(i*16 + rr)*72 + ks*32 + g*8);
            #pragma unroll
            for (int n = 0; n < 4; ++n)
                vb[n] = *reinterpret_cast<const bf16x8*>(
                    Vt + (size_t)(n*16 + rr)*264 + kc*64 + ks*32 + g*8);
            #pragma unroll
            for (int i = 0; i < 4; ++i)
                #pragma unroll
                for (int n = 0; n < 4; ++n)
                    oacc[i][n] = __builtin_amdgcn_mfma_f32_16x16x32_bf16(
                        pa[i], vb[n], oacc[i][n], 0, 0, 0);
        }
    }

    #pragma unroll
    for (int i = 0; i < 4; ++i) {
        #pragma unroll
        for (int r = 0; r < 4; ++r) {
            float v = lacc[i][r];
            v += __shfl_xor(v, 1);
            v += __shfl_xor(v, 2);
            v += __shfl_xor(v, 4);
            v += __shfl_xor(v, 8);
            lacc[i][r] = 1.0f / v;
        }
    }
    #pragma unroll
    for (int i = 0; i < 4; ++i) {
        #pragma unroll
        for (int r = 0; r < 4; ++r) {
            int qrow = w*64 + i*16 + g*4 + r;
            bf16_t* orow = o + (size_t)(b*256 + qrow)*EMB_ + h*64;
            float inv = lacc[i][r];
            #pragma unroll
            for (int n = 0; n < 4; ++n)
                orow[n*16 + rr] = (bf16_t)(oacc[i][n][r] * inv);
        }
    }
}

// ---------------------------------------------------------------------------
// head (verified)
// ---------------------------------------------------------------------------
__global__ __launch_bounds__(256)
void head_kernel(const float* __restrict__ tok, const float* __restrict__ fcw,
                 const float* __restrict__ fcb, float* __restrict__ scores) {
    const int bx[6][4] = {{0,6,0,8},{4,11,0,8},{9,16,0,8},{0,6,8,16},{4,11,8,16},{9,16,8,16}};
    int box = blockIdx.x % 6, b = blockIdx.x / 6;
    int r0 = bx[box][0], r1 = bx[box][1], c0 = bx[box][2], c1 = bx[box][3];
    int rh = r1 - r0, rw = c1 - c0;
    __shared__ float wl[256];
    __shared__ float feats[768];
    __shared__ float red[4];
    int tid = threadIdx.x;
    int py = tid >> 4, px = tid & 15;
    float w = 0.0f;
    if (py >= r0 && py < r1 && px >= c0 && px < c1) {
        int ly = py - r0, lx = px - c0;
        float cy = 0.0f, cx = 0.0f;
        for (int o = 0; o < 16; ++o) {
            float sy = (o + 0.5f) * (float)rh * (1.0f/16.0f) - 0.5f;
            sy = fminf(fmaxf(sy, 0.0f), (float)(rh - 1));
            int i0 = (int)floorf(sy); float t = sy - (float)i0;
            if (ly == i0)     cy += 1.0f - t;
            if (ly == i0 + 1) cy += t;
            float sx = (o + 0.5f) * (float)rw * (1.0f/16.0f) - 0.5f;
            sx = fminf(fmaxf(sx, 0.0f), (float)(rw - 1));
            int j0 = (int)floorf(sx); float u = sx - (float)j0;
            if (lx == j0)     cx += 1.0f - u;
            if (lx == j0 + 1) cx += u;
        }
        w = (cy * (1.0f/16.0f)) * (cx * (1.0f/16.0f));
    }
    wl[tid] = w;
    __syncthreads();
    for (int e = tid; e < EMB_; e += 256) {
        float f = 0.0f;
        for (int iy = r0; iy < r1; ++iy)
            for (int ix = c0; ix < c1; ++ix) {
                int p = iy*16 + ix;
                f += wl[p] * tok[((size_t)(b*256 + p))*EMB_ + e];
            }
        feats[e] = f;
    }
    __syncthreads();
    float lg[4];
    #pragma unroll
    for (int cc = 0; cc < 4; ++cc) {
        float part = 0.0f;
        for (int e = tid; e < EMB_; e += 256) part += feats[e]*fcw[e*4 + cc];
        #pragma unroll
        for (int off = 32; off; off >>= 1) part += __shfl_xor(part, off);
        __syncthreads();
        if ((tid & 63) == 0) red[tid>>6] = part;
        __syncthreads();
        lg[cc] = red[0]+red[1]+red[2]+red[3] + fcb[cc];
    }
    if (tid == 0) {
        float mx = fmaxf(fmaxf(lg[0],lg[1]), fmaxf(lg[2],lg[3]));
        float e0 = expf(lg[0]-mx), e1 = expf(lg[1]-mx), e2 = expf(lg[2]-mx), e3 = expf(lg[3]-mx);
        float inv = 1.0f/(e0+e1+e2+e3);
        float* out = scores + (size_t)(b*6 + box)*4;
        out[0] = e0*inv; out[1] = e1*inv; out[2] = e2*inv; out[3] = e3*inv;
    }
}

// ===========================================================================
extern "C" void kernel_launch(void* const* d_in, const int* in_sizes, int n_in,
                              void* d_out, int out_size, void* d_ws, size_t ws_size,
                              hipStream_t stream) {
    (void)in_sizes; (void)n_in; (void)out_size; (void)ws_size;
    const float* x       = (const float*)d_in[0];
    const float* lm      = (const float*)d_in[1];
    const float* stn_w1  = (const float*)d_in[2];
    const float* stn_b1  = (const float*)d_in[3];
    const float* stn_w2  = (const float*)d_in[4];
    const float* stn_b2  = (const float*)d_in[5];
    const float* conv_w  = (const float*)d_in[6];
    const float* conv_b  = (const float*)d_in[7];
    const float* pe_w    = (const float*)d_in[8];
    const float* pe_b    = (const float*)d_in[9];
    const float* pos     = (const float*)d_in[10];
    const float* ln1_g   = (const float*)d_in[11];
    const float* ln1_b   = (const float*)d_in[12];
    const float* qkv_w   = (const float*)d_in[13];
    const float* qkv_b   = (const float*)d_in[14];
    const float* proj_w  = (const float*)d_in[15];
    const float* proj_b  = (const float*)d_in[16];
    const float* ln2_g   = (const float*)d_in[17];
    const float* ln2_b   = (const float*)d_in[18];
    const float* mlp_w1  = (const float*)d_in[19];
    const float* mlp_b1  = (const float*)d_in[20];
    const float* mlp_w2  = (const float*)d_in[21];
    const float* mlp_b2  = (const float*)d_in[22];
    const float* fc_w    = (const float*)d_in[23];
    const float* fc_b    = (const float*)d_in[24];

    float* out    = (float*)d_out;
    float* scores = out;
    float* timg   = out + 384;
    float* tmask  = out + 384 + (size_t)B_*3*HH*WW;

    char* ws = (char*)d_ws;
    size_t off = 0;
    auto alloc = [&](size_t bytes) {
        off = (off + 255) & ~(size_t)255;
        void* p = ws + off; off += bytes; return p;
    };
    // slotBig: seg(fp32,16MB) -> hidden(bf16,24MB)
    char*   slotBig = (char*)alloc(25165824);
    // slotT: timg_bf(25.2MB) -> qkvb(18.9MB)
    char*   slotT   = (char*)alloc((size_t)B_*3*HH*WW*2);
    // slotC: featC(8.4MB) -> obuf(6.3MB)
    char*   slotC   = (char*)alloc((size_t)M_*NF_*2);
    float*  tok     = (float*)alloc((size_t)M_*EMB_*4);
    bf16_t* tbuf    = (bf16_t*)alloc((size_t)M_*EMB_*2);
    bf16_t* conv_wb = (bf16_t*)alloc((size_t)NF_*KCONV*2);
    bf16_t* pe_wb   = (bf16_t*)alloc((size_t)EMB_*NF_*2);
    bf16_t* qkv_wb  = (bf16_t*)alloc((size_t)3*EMB_*EMB_*2);
    bf16_t* proj_wb = (bf16_t*)alloc((size_t)EMB_*EMB_*2);
    bf16_t* mlp1_wb = (bf16_t*)alloc((size_t)4*EMB_*EMB_*2);
    bf16_t* mlp2_wb = (bf16_t*)alloc((size_t)EMB_*4*EMB_*2);
    float*  w1t     = (float*)alloc(50*1024*4);
    float*  pooled  = (float*)alloc(16384*4);
    float*  theta   = (float*)alloc(96*4);

    float*  seg    = (float*)slotBig;
    bf16_t* hidden = (bf16_t*)slotBig;
    bf16_t* timgb  = (bf16_t*)slotT;
    bf16_t* qkvb   = (bf16_t*)slotT;
    bf16_t* featC  = (bf16_t*)slotC;
    bf16_t* obuf   = (bf16_t*)slotC;

    // weight conversions (independent of data path)
    convert_bf16_kernel<<<(NF_*KCONV)/8/256, 256, 0, stream>>>(conv_w, conv_wb);
    transpose_bf16_kernel<<<dim3(EMB_/32, NF_/32),    256, 0, stream>>>(pe_w,   pe_wb,   NF_,  EMB_);
    transpose_bf16_kernel<<<dim3(3*EMB_/32, EMB_/32), 256, 0, stream>>>(qkv_w,  qkv_wb,  EMB_, 3*EMB_);
    transpose_bf16_kernel<<<dim3(EMB_/32, EMB_/32),   256, 0, stream>>>(proj_w, proj_wb, EMB_, EMB_);
    transpose_bf16_kernel<<<dim3(4*EMB_/32, EMB_/32), 256, 0, stream>>>(mlp_w1, mlp1_wb, EMB_, 4*EMB_);
    transpose_bf16_kernel<<<dim3(EMB_/32, 4*EMB_/32), 256, 0, stream>>>(mlp_w2, mlp2_wb, 4*EMB_, EMB_);
    transpose_w1_kernel<<<200, 256, 0, stream>>>(stn_w1, w1t);

    // mask path
    hipMemsetAsync(seg, 0, (size_t)B_*HH*WW*sizeof(float), stream);
    raster_kernel<<<B_, 128, 0, stream>>>(lm, seg);
    pool_kernel<<<64, 256, 0, stream>>>(seg, pooled);
    stn2_kernel<<<B_, 1024, 0, stream>>>(pooled, w1t, stn_b1, stn_w2, stn_b2, theta);
    gridsample_kernel<<<(B_*HH*WW)/256, 256, 0, stream>>>(x, seg, theta, timg, tmask, timgb);

    // conv as implicit-im2col GEMM (64x64 tiles, 1024 blocks)
    gemm_conv64_kernel<<<(M_/64)*(NF_/64), 256, 0, stream>>>(
        timgb, conv_wb, conv_b, featC);

    // patch embed + pos -> tok (fp32 residual stream)   [768 blocks]
    gemm64_kernel<EPI_PE><<<(M_/64)*(EMB_/64), 256, 0, stream>>>(
        featC, pe_wb, pe_b, pos, tok, nullptr, M_, EMB_, NF_);

    // LN1 -> qkv   [2304 blocks]
    ln_kernel<<<M_, 256, 0, stream>>>(tok, ln1_g, ln1_b, tbuf);
    gemm64_kernel<EPI_QKV><<<(M_/64)*(3*EMB_/64), 256, 0, stream>>>(
        tbuf, qkv_wb, qkv_b, nullptr, nullptr, qkvb, M_, 3*EMB_, EMB_);

    // attention (MFMA)
    attn_kernel5<<<B_*HEADS_, 256, 0, stream>>>(qkvb, obuf);

    // proj + residual   [768 blocks]
    gemm64_kernel<EPI_PROJ><<<(M_/64)*(EMB_/64), 256, 0, stream>>>(
        obuf, proj_wb, proj_b, nullptr, tok, nullptr, M_, EMB_, EMB_);

    // LN2 -> mlp   [mlp1 3072 blocks; mlp2 768 blocks]
    ln_kernel<<<M_, 256, 0, stream>>>(tok, ln2_g, ln2_b, tbuf);
    gemm64_kernel<EPI_GELU><<<(M_/64)*(4*EMB_/64), 256, 0, stream>>>(
        tbuf, mlp1_wb, mlp_b1, nullptr, nullptr, hidden, M_, 4*EMB_, EMB_);
    gemm64_kernel<EPI_MLP2><<<(M_/64)*(EMB_/64), 256, 0, stream>>>(
        hidden, mlp2_wb, mlp_b2, nullptr, tok, nullptr, M_, EMB_, 4*EMB_);

    // head
    head_kernel<<<B_*6, 256, 0, stream>>>(tok, fc_w, fc_b, scores);
}

// Round 9
// 311.027 us; speedup vs baseline: 2.2096x; 1.0919x over previous
//
#include <hip/hip_runtime.h>
#include <hip/hip_bf16.h>
#include <cstdint>

// ============================================================================
// Hybrid e2e STN pipeline, round 9:
//  - head split: feats (96x3 blocks, coalesced per-channel gather) + logits
//    (was one 96-block latency-bound kernel: r8 PMC Occ 3.4%, VALU 1%)
//  - everything else identical to verified round 8
// ============================================================================

#define B_    16
#define HH    512
#define WW    512
#define NF_   1024
#define EMB_  768
#define HEADS_ 12
#define NTOK  256
#define M_    (B_*NTOK)      // 4096
#define KCONV 3072

typedef __bf16 bf16_t;
typedef __bf16 bf16x8 __attribute__((ext_vector_type(8)));
typedef float  f32x4  __attribute__((ext_vector_type(4)));

typedef __attribute__((address_space(1))) const void* gas_t;
typedef __attribute__((address_space(3))) void* las_t;

__device__ __forceinline__ void gload16(const bf16_t* g, bf16_t* l) {
    __builtin_amdgcn_global_load_lds((gas_t)g, (las_t)l, 16, 0, 0);
}

__device__ __forceinline__ float tanh_fast(float x) {
    return 1.0f - 2.0f / (__expf(2.0f * x) + 1.0f);
}

// ---------------------------------------------------------------------------
// rasterize (verified)
// ---------------------------------------------------------------------------
__global__ __launch_bounds__(128)
void raster_kernel(const float* __restrict__ lm, float* __restrict__ seg) {
    int b = blockIdx.x;
    int s = threadIdx.x;
    if (s >= 117) return;
    int seg0 = (s < 43) ? s : ((s < 92) ? s + 1 : s + 2);
    const float* p = lm + (size_t)b * 240;
    int p1x = min(max((int)(p[seg0*2 + 0] * 512.0f), 0), 511);
    int p1y = min(max((int)(p[seg0*2 + 1] * 512.0f), 0), 511);
    int p2x = min(max((int)(p[(seg0+1)*2 + 0] * 512.0f), 0), 511);
    int p2y = min(max((int)(p[(seg0+1)*2 + 1] * 512.0f), 0), 511);
    int dy = p2y - p1y, dx = p2x - p1x;
    int kmax = min(dy, dx);
    float* sb = seg + (size_t)b * (HH*WW);
    for (int k = 0; k < kmax; ++k) {
        int yi = min(p1y + k, 511);
        int xi = min(p1x + k, 511);
        sb[yi*WW + xi] = 1.0f;
    }
}

// ---------------------------------------------------------------------------
// pool (verified)
// ---------------------------------------------------------------------------
__global__ __launch_bounds__(256)
void pool_kernel(const float* __restrict__ seg, float* __restrict__ pooled) {
    int idx = blockIdx.x * 256 + threadIdx.x;
    int ox = idx & 31, oy = (idx >> 5) & 31, b = idx >> 10;
    const float* sb = seg + (size_t)b * (HH*WW) + (oy*16)*WW + ox*16;
    float s = 0.0f;
    for (int dy = 0; dy < 16; ++dy) {
        #pragma unroll
        for (int dx = 0; dx < 16; ++dx) s += sb[dy*WW + dx];
    }
    pooled[idx] = s * (1.0f/256.0f);
}

// ---------------------------------------------------------------------------
// w1 transpose (fp32): in[k*50+j] -> out[j*1024+k]
// ---------------------------------------------------------------------------
__global__ __launch_bounds__(256)
void transpose_w1_kernel(const float* __restrict__ in, float* __restrict__ out) {
    int idx = blockIdx.x * 256 + threadIdx.x;
    int j = idx >> 10, k = idx & 1023;
    out[idx] = in[k*50 + j];
}

// ---------------------------------------------------------------------------
// stn (verified r8): 16 blocks x 1024 threads
// ---------------------------------------------------------------------------
__global__ __launch_bounds__(1024)
void stn2_kernel(const float* __restrict__ pooled, const float* __restrict__ w1t,
                 const float* __restrict__ b1, const float* __restrict__ w2,
                 const float* __restrict__ b2, float* __restrict__ theta) {
    __shared__ float pl[1024];
    __shared__ float hl[56];
    int b = blockIdx.x, tid = threadIdx.x;
    pl[tid] = pooled[b*1024 + tid];
    __syncthreads();
    int wave = tid >> 6, lane = tid & 63;
    #pragma unroll
    for (int p = 0; p < 4; ++p) {
        int j = wave + (p << 4);
        if (j < 50) {
            const float* wr = w1t + j*1024;
            float acc = 0.0f;
            #pragma unroll
            for (int i = 0; i < 16; ++i) {
                int k = lane + (i << 6);
                acc = fmaf(pl[k], wr[k], acc);
            }
            #pragma unroll
            for (int off = 32; off; off >>= 1) acc += __shfl_xor(acc, off);
            if (lane == 0) hl[j] = tanhf(acc + b1[j]);
        }
    }
    __syncthreads();
    if (tid < 6) {
        float acc = b2[tid];
        for (int k = 0; k < 50; ++k) acc = fmaf(hl[k], w2[k*6 + tid], acc);
        theta[b*6 + tid] = acc;
    }
}

// ---------------------------------------------------------------------------
// fused affine_grid + grid_sample; also emits bf16 copy of transformed img
// ---------------------------------------------------------------------------
__global__ __launch_bounds__(256)
void gridsample_kernel(const float* __restrict__ x, const float* __restrict__ seg,
                       const float* __restrict__ theta,
                       float* __restrict__ timg, float* __restrict__ tmask,
                       bf16_t* __restrict__ timgb) {
    size_t idx = (size_t)blockIdx.x * 256 + threadIdx.x;
    int xx = (int)(idx & 511);
    int yy = (int)((idx >> 9) & 511);
    int b  = (int)(idx >> 18);
    __shared__ float th[6];
    if (threadIdx.x < 6) th[threadIdx.x] = theta[b*6 + threadIdx.x];
    __syncthreads();
    float gx = (2.0f*xx + 1.0f) * (1.0f/512.0f) - 1.0f;
    float gy = (2.0f*yy + 1.0f) * (1.0f/512.0f) - 1.0f;
    float g0 = gx*th[0] + gy*th[1] + th[2];
    float g1 = gx*th[3] + gy*th[4] + th[5];
    float fx = ((g0 + 1.0f)*512.0f - 1.0f)*0.5f;
    float fy = ((g1 + 1.0f)*512.0f - 1.0f)*0.5f;
    float x0f = floorf(fx), y0f = floorf(fy);
    float wx1 = fx - x0f,  wy1 = fy - y0f;
    int ix0 = (int)x0f, iy0 = (int)y0f;
    int ix1 = ix0 + 1,  iy1 = iy0 + 1;
    float fy0ok = (iy0 >= 0 && iy0 < HH) ? 1.0f : 0.0f;
    float fy1ok = (iy1 >= 0 && iy1 < HH) ? 1.0f : 0.0f;
    float fx0ok = (ix0 >= 0 && ix0 < WW) ? 1.0f : 0.0f;
    float fx1ok = (ix1 >= 0 && ix1 < WW) ? 1.0f : 0.0f;
    float w00 = (1.0f-wy1)*(1.0f-wx1) * fy0ok * fx0ok;
    float w01 = (1.0f-wy1)*wx1        * fy0ok * fx1ok;
    float w10 = wy1*(1.0f-wx1)        * fy1ok * fx0ok;
    float w11 = wy1*wx1               * fy1ok * fx1ok;
    int cx0 = min(max(ix0,0),511), cx1 = min(max(ix1,0),511);
    int cy0 = min(max(iy0,0),511), cy1 = min(max(iy1,0),511);
    int i00 = cy0*WW + cx0, i01 = cy0*WW + cx1, i10 = cy1*WW + cx0, i11 = cy1*WW + cx1;
    size_t pix = (size_t)yy*WW + xx;
    #pragma unroll
    for (int c = 0; c < 3; ++c) {
        const float* pl = x + ((size_t)(b*3 + c)) * (HH*WW);
        float v = w00*pl[i00] + w01*pl[i01] + w10*pl[i10] + w11*pl[i11];
        timg [((size_t)(b*3 + c))*(HH*WW) + pix] = v;
        timgb[((size_t)(b*3 + c))*(HH*WW) + pix] = (bf16_t)v;
    }
    const float* sp = seg + (size_t)b * (HH*WW);
    float mv = w00*sp[i00] + w01*sp[i01] + w10*sp[i10] + w11*sp[i11];
    tmask[(size_t)b*(HH*WW) + pix] = mv;
}

// ---------------------------------------------------------------------------
// conversions
// ---------------------------------------------------------------------------
__global__ __launch_bounds__(256)
void convert_bf16_kernel(const float* __restrict__ in, bf16_t* __restrict__ out) {
    int idx = (blockIdx.x * 256 + threadIdx.x) * 8;
    float4 v0 = *reinterpret_cast<const float4*>(in + idx);
    float4 v1 = *reinterpret_cast<const float4*>(in + idx + 4);
    bf16x8 o;
    o[0]=(bf16_t)v0.x; o[1]=(bf16_t)v0.y; o[2]=(bf16_t)v0.z; o[3]=(bf16_t)v0.w;
    o[4]=(bf16_t)v1.x; o[5]=(bf16_t)v1.y; o[6]=(bf16_t)v1.z; o[7]=(bf16_t)v1.w;
    *reinterpret_cast<bf16x8*>(out + idx) = o;
}

__global__ __launch_bounds__(256)
void transpose_bf16_kernel(const float* __restrict__ in, bf16_t* __restrict__ out,
                           int K, int N) {   // in[K][N] -> out[N][K]
    __shared__ float tile[32][33];
    int bk = blockIdx.y * 32, bn = blockIdx.x * 32;
    int r = threadIdx.x >> 5, c = threadIdx.x & 31;
    #pragma unroll
    for (int i = 0; i < 4; ++i)
        tile[r + 8*i][c] = in[(size_t)(bk + r + 8*i) * N + bn + c];
    __syncthreads();
    #pragma unroll
    for (int i = 0; i < 4; ++i)
        out[(size_t)(bn + r + 8*i) * K + bk + c] = (bf16_t)tile[c][r + 8*i];
}

// ---------------------------------------------------------------------------
// bf16 MFMA GEMM (verified r7/r8): 64x64 tile, BK=64, 4 waves of 32x32,
// row&7 XOR swizzle, XCD-chunked block swizzle.
// ---------------------------------------------------------------------------
enum { EPI_CONV=0, EPI_PE=1, EPI_QKV=2, EPI_PROJ=3, EPI_GELU=4, EPI_MLP2=5 };

template<int EPI>
__device__ __forceinline__ void gemm_epilogue64(
        f32x4 (&acc)[2][2], const float* bias, const float* extra,
        float* Cf, bf16_t* Cb, int bm, int bn, int wm, int wn,
        int rr, int g, int N) {
    #pragma unroll
    for (int i = 0; i < 2; ++i) {
        #pragma unroll
        for (int j = 0; j < 2; ++j) {
            #pragma unroll
            for (int r = 0; r < 4; ++r) {
                int m = bm + wm + i*16 + g*4 + r;
                int n = bn + wn + j*16 + rr;
                size_t o = (size_t)m * N + n;
                float v = acc[i][j][r] + bias[n];
                if (EPI == EPI_CONV) {
                    Cb[o] = (bf16_t)fmaxf(v, 0.0f);
                } else if (EPI == EPI_PE) {
                    Cf[o] = v + extra[(size_t)(m & 255)*N + n];
                } else if (EPI == EPI_QKV) {
                    Cb[o] = (bf16_t)v;
                } else if (EPI == EPI_PROJ || EPI == EPI_MLP2) {
                    Cf[o] = v + Cf[o];
                } else if (EPI == EPI_GELU) {
                    float u = v;
                    float gl = 0.5f*u*(1.0f + tanh_fast(0.7978845608028654f*(u + 0.044715f*u*u*u)));
                    Cb[o] = (bf16_t)gl;
                }
            }
        }
    }
}

template<int EPI>
__global__ __launch_bounds__(256)
void gemm64_kernel(const bf16_t* __restrict__ A, const bf16_t* __restrict__ Bt,
                   const float* __restrict__ bias, const float* __restrict__ extra,
                   float* __restrict__ Cf, bf16_t* __restrict__ Cb,
                   int M, int N, int K) {
    __shared__ __align__(16) bf16_t As[2][64*64];
    __shared__ __align__(16) bf16_t Bs[2][64*64];
    const int tid = threadIdx.x;
    const int nN   = N >> 6;
    const int nblk = (M >> 6) * nN;
    const int q    = nblk >> 3;
    const int id   = (blockIdx.x & 7) * q + (blockIdx.x >> 3);   // XCD chunk
    const int bm = (id / nN) * 64, bn = (id % nN) * 64;
    const int lane = tid & 63, w = tid >> 6;
    const int rr = lane & 15, g = lane >> 4;
    const int wm = (w & 1) * 32, wn = (w >> 1) * 32;
    const int sr = tid >> 3;
    const int sc = ((tid & 7) ^ (sr & 7)) * 8;
    const bf16_t* gA0 = A  + (size_t)(bm + sr)      * K + sc;
    const bf16_t* gA1 = A  + (size_t)(bm + 32 + sr) * K + sc;
    const bf16_t* gB0 = Bt + (size_t)(bn + sr)      * K + sc;
    const bf16_t* gB1 = Bt + (size_t)(bn + 32 + sr) * K + sc;

    auto STAGE = [&](int buf, int k0) {
        gload16(gA0 + k0, As[buf] + w*512);
        gload16(gA1 + k0, As[buf] + 2048 + w*512);
        gload16(gB0 + k0, Bs[buf] + w*512);
        gload16(gB1 + k0, Bs[buf] + 2048 + w*512);
    };

    const int s0 = (0*4 + g) ^ (rr & 7);
    const int s1 = (1*4 + g) ^ (rr & 7);

    f32x4 acc[2][2] = {};
    STAGE(0, 0);
    __syncthreads();
    int cur = 0;
    for (int k0 = 0; k0 < K; k0 += 64) {
        if (k0 + 64 < K) STAGE(cur ^ 1, k0 + 64);
        bf16x8 af[2][2], bfv[2][2];
        #pragma unroll
        for (int i = 0; i < 2; ++i) {
            int ra = (wm + i*16 + rr) * 64;
            af[i][0] = *reinterpret_cast<const bf16x8*>(As[cur] + ra + s0*8);
            af[i][1] = *reinterpret_cast<const bf16x8*>(As[cur] + ra + s1*8);
            int rb = (wn + i*16 + rr) * 64;
            bfv[i][0] = *reinterpret_cast<const bf16x8*>(Bs[cur] + rb + s0*8);
            bfv[i][1] = *reinterpret_cast<const bf16x8*>(Bs[cur] + rb + s1*8);
        }
        #pragma unroll
        for (int ks = 0; ks < 2; ++ks)
            #pragma unroll
            for (int i = 0; i < 2; ++i)
                #pragma unroll
                for (int j = 0; j < 2; ++j)
                    acc[i][j] = __builtin_amdgcn_mfma_f32_16x16x32_bf16(
                        af[i][ks], bfv[j][ks], acc[i][j], 0, 0, 0);
        __syncthreads();
        cur ^= 1;
    }
    gemm_epilogue64<EPI>(acc, bias, extra, Cf, Cb, bm, bn, wm, wn, rr, g, N);
}

// conv GEMM: implicit im2col from bf16 image. M=4096, N=1024, K=3072.
__global__ __launch_bounds__(256)
void gemm_conv64_kernel(const bf16_t* __restrict__ timgb, const bf16_t* __restrict__ Bt,
                        const float* __restrict__ bias, bf16_t* __restrict__ Cb) {
    const int N = NF_, K = KCONV;
    __shared__ __align__(16) bf16_t As[2][64*64];
    __shared__ __align__(16) bf16_t Bs[2][64*64];
    const int tid = threadIdx.x;
    const int nN   = N >> 6;
    const int nblk = (M_ >> 6) * nN;
    const int q    = nblk >> 3;
    const int id   = (blockIdx.x & 7) * q + (blockIdx.x >> 3);
    const int bm = (id / nN) * 64, bn = (id % nN) * 64;
    const int lane = tid & 63, w = tid >> 6;
    const int rr = lane & 15, g = lane >> 4;
    const int wm = (w & 1) * 32, wn = (w >> 1) * 32;
    const int sr = tid >> 3;
    const int s  = (tid & 7) ^ (sr & 7);
    int row0 = bm + sr, row1 = bm + 32 + sr;
    int b0 = row0 >> 8, py0 = (row0 >> 4) & 15, px0 = row0 & 15;
    int b1 = row1 >> 8, py1 = (row1 >> 4) & 15, px1 = row1 & 15;
    size_t off0 = (size_t)b0*786432 + py0*16384 + px0*32 + (s>>2)*512 + (s&3)*8;
    size_t off1 = (size_t)b1*786432 + py1*16384 + px1*32 + (s>>2)*512 + (s&3)*8;
    const bf16_t* gB0 = Bt + (size_t)(bn + sr)      * K + s*8;
    const bf16_t* gB1 = Bt + (size_t)(bn + 32 + sr) * K + s*8;

    auto STAGE = [&](int buf, int k0) {
        int c   = k0 >> 10;
        int ky0 = (k0 >> 5) & 31;
        size_t koff = (size_t)c*262144 + (size_t)ky0*512;
        gload16(timgb + off0 + koff, As[buf] + w*512);
        gload16(timgb + off1 + koff, As[buf] + 2048 + w*512);
        gload16(gB0 + k0, Bs[buf] + w*512);
        gload16(gB1 + k0, Bs[buf] + 2048 + w*512);
    };

    const int s0 = (0*4 + g) ^ (rr & 7);
    const int s1 = (1*4 + g) ^ (rr & 7);

    f32x4 acc[2][2] = {};
    STAGE(0, 0);
    __syncthreads();
    int cur = 0;
    for (int k0 = 0; k0 < K; k0 += 64) {
        if (k0 + 64 < K) STAGE(cur ^ 1, k0 + 64);
        bf16x8 af[2][2], bfv[2][2];
        #pragma unroll
        for (int i = 0; i < 2; ++i) {
            int ra = (wm + i*16 + rr) * 64;
            af[i][0] = *reinterpret_cast<const bf16x8*>(As[cur] + ra + s0*8);
            af[i][1] = *reinterpret_cast<const bf16x8*>(As[cur] + ra + s1*8);
            int rb = (wn + i*16 + rr) * 64;
            bfv[i][0] = *reinterpret_cast<const bf16x8*>(Bs[cur] + rb + s0*8);
            bfv[i][1] = *reinterpret_cast<const bf16x8*>(Bs[cur] + rb + s1*8);
        }
        #pragma unroll
        for (int ks = 0; ks < 2; ++ks)
            #pragma unroll
            for (int i = 0; i < 2; ++i)
                #pragma unroll
                for (int j = 0; j < 2; ++j)
                    acc[i][j] = __builtin_amdgcn_mfma_f32_16x16x32_bf16(
                        af[i][ks], bfv[j][ks], acc[i][j], 0, 0, 0);
        __syncthreads();
        cur ^= 1;
    }
    gemm_epilogue64<EPI_CONV>(acc, bias, nullptr, nullptr, Cb, bm, bn, wm, wn, rr, g, N);
}

// ---------------------------------------------------------------------------
// layernorm rows of 768, fp32 in -> bf16 out
// ---------------------------------------------------------------------------
__global__ __launch_bounds__(256)
void ln_kernel(const float* __restrict__ x, const float* __restrict__ g,
               const float* __restrict__ be, bf16_t* __restrict__ out) {
    int r = blockIdx.x, tid = threadIdx.x;
    const float* xr = x + (size_t)r * EMB_;
    float v0 = xr[tid], v1 = xr[tid+256], v2 = xr[tid+512];
    float s = v0+v1+v2, s2 = v0*v0 + v1*v1 + v2*v2;
    __shared__ float red[8];
    #pragma unroll
    for (int off = 32; off; off >>= 1) { s += __shfl_xor(s, off); s2 += __shfl_xor(s2, off); }
    if ((tid & 63) == 0) { red[tid>>6] = s; red[4 + (tid>>6)] = s2; }
    __syncthreads();
    s  = red[0]+red[1]+red[2]+red[3];
    s2 = red[4]+red[5]+red[6]+red[7];
    float mean = s * (1.0f/768.0f);
    float var  = s2 * (1.0f/768.0f) - mean*mean;
    float rstd = rsqrtf(var + 1e-5f);
    bf16_t* orow = out + (size_t)r * EMB_;
    orow[tid]     = (bf16_t)((v0-mean)*rstd*g[tid]     + be[tid]);
    orow[tid+256] = (bf16_t)((v1-mean)*rstd*g[tid+256] + be[tid+256]);
    orow[tid+512] = (bf16_t)((v2-mean)*rstd*g[tid+512] + be[tid+512]);
}

// ---------------------------------------------------------------------------
// attention: MFMA flash-chunked (verified r5-r8)
// ---------------------------------------------------------------------------
__global__ __launch_bounds__(256)
void attn_kernel5(const bf16_t* __restrict__ qkv, bf16_t* __restrict__ o) {
    __shared__ __align__(16) bf16_t Ks[256*72];
    __shared__ __align__(16) bf16_t Vt[64*264];
    __shared__ __align__(16) bf16_t Ps[4][64*72];
    const int tid  = threadIdx.x;
    const int lane = tid & 63, w = tid >> 6;
    const int rr   = lane & 15, g = lane >> 4;
    const int h = blockIdx.x % HEADS_;
    const int b = blockIdx.x / HEADS_;
    const bf16_t* base = qkv + (size_t)(b*256)*2304;

    {
        const bf16_t* kr = base + (size_t)tid*2304 + 768  + h*64;
        const bf16_t* vr = base + (size_t)tid*2304 + 1536 + h*64;
        bf16_t* kd = Ks + tid*72;
        #pragma unroll
        for (int c2 = 0; c2 < 8; ++c2) {
            *reinterpret_cast<bf16x8*>(kd + c2*8) =
                *reinterpret_cast<const bf16x8*>(kr + c2*8);
            bf16x8 v = *reinterpret_cast<const bf16x8*>(vr + c2*8);
            #pragma unroll
            for (int e = 0; e < 8; ++e)
                Vt[(c2*8 + e)*264 + tid] = v[e];
        }
    }

    bf16x8 qf[4][2];
    #pragma unroll
    for (int i = 0; i < 4; ++i)
        #pragma unroll
        for (int ks = 0; ks < 2; ++ks)
            qf[i][ks] = *reinterpret_cast<const bf16x8*>(
                base + (size_t)(w*64 + i*16 + rr)*2304 + h*64 + ks*32 + g*8);

    f32x4 oacc[4][4] = {};
    float lacc[4][4] = {};
    __syncthreads();

    bf16_t* Pw = Ps[w];
    for (int kc = 0; kc < 4; ++kc) {
        f32x4 sacc[4][4] = {};
        #pragma unroll
        for (int ks = 0; ks < 2; ++ks) {
            bf16x8 kf[4];
            #pragma unroll
            for (int j = 0; j < 4; ++j)
                kf[j] = *reinterpret_cast<const bf16x8*>(
                    Ks + (size_t)(kc*64 + j*16 + rr)*72 + ks*32 + g*8);
            #pragma unroll
            for (int i = 0; i < 4; ++i)
                #pragma unroll
                for (int j = 0; j < 4; ++j)
                    sacc[i][j] = __builtin_amdgcn_mfma_f32_16x16x32_bf16(
                        qf[i][ks], kf[j], sacc[i][j], 0, 0, 0);
        }
        #pragma unroll
        for (int i = 0; i < 4; ++i) {
            #pragma unroll
            for (int r = 0; r < 4; ++r) {
                int prow = i*16 + g*4 + r;
                float ps = 0.0f;
                #pragma unroll
                for (int j = 0; j < 4; ++j) {
                    float p = __expf(sacc[i][j][r] * 0.125f);
                    ps += p;
                    Pw[prow*72 + j*16 + rr] = (bf16_t)p;
                }
                lacc[i][r] += ps;
            }
        }
        #pragma unroll
        for (int ks = 0; ks < 2; ++ks) {
            bf16x8 pa[4], vb[4];
            #pragma unroll
            for (int i = 0; i < 4; ++i)
                pa[i] = *reinterpret_cast<const bf16x8*>(
                    Pw + (size_t)(i*16 + rr)*72 + ks*32 + g*8);
            #pragma unroll
            for (int n = 0; n < 4; ++n)
                vb[n] = *reinterpret_cast<const bf16x8*>(
                    Vt + (size_t)(n*16 + rr)*264 + kc*64 + ks*32 + g*8);
            #pragma unroll
            for (int i = 0; i < 4; ++i)
                #pragma unroll
                for (int n = 0; n < 4; ++n)
                    oacc[i][n] = __builtin_amdgcn_mfma_f32_16x16x32_bf16(
                        pa[i], vb[n], oacc[i][n], 0, 0, 0);
        }
    }

    #pragma unroll
    for (int i = 0; i < 4; ++i) {
        #pragma unroll
        for (int r = 0; r < 4; ++r) {
            float v = lacc[i][r];
            v += __shfl_xor(v, 1);
            v += __shfl_xor(v, 2);
            v += __shfl_xor(v, 4);
            v += __shfl_xor(v, 8);
            lacc[i][r] = 1.0f / v;
        }
    }
    #pragma unroll
    for (int i = 0; i < 4; ++i) {
        #pragma unroll
        for (int r = 0; r < 4; ++r) {
            int qrow = w*64 + i*16 + g*4 + r;
            bf16_t* orow = o + (size_t)(b*256 + qrow)*EMB_ + h*64;
            float inv = lacc[i][r];
            #pragma unroll
            for (int n = 0; n < 4; ++n)
                orow[n*16 + rr] = (bf16_t)(oacc[i][n][r] * inv);
        }
    }
}

// ---------------------------------------------------------------------------
// head round 9, stage 1: feats[(b*6+box)*768 + e]
// grid = (b,box,chunk) = 96*3 blocks; thread owns channel e (coalesced tok).
// Weight math identical to verified r8 head.
// ---------------------------------------------------------------------------
__global__ __launch_bounds__(256)
void head_feats_kernel(const float* __restrict__ tok, float* __restrict__ feats) {
    const int bx[6][4] = {{0,6,0,8},{4,11,0,8},{9,16,0,8},{0,6,8,16},{4,11,8,16},{9,16,8,16}};
    int chunk = blockIdx.x % 3;
    int box   = (blockIdx.x / 3) % 6;
    int b     = blockIdx.x / 18;
    int r0 = bx[box][0], r1 = bx[box][1], c0 = bx[box][2], c1 = bx[box][3];
    int rh = r1 - r0, rw = c1 - c0;
    __shared__ float wl[256];
    int tid = threadIdx.x;
    int py = tid >> 4, px = tid & 15;
    float w = 0.0f;
    if (py >= r0 && py < r1 && px >= c0 && px < c1) {
        int ly = py - r0, lx = px - c0;
        float cy = 0.0f, cx = 0.0f;
        for (int o = 0; o < 16; ++o) {
            float sy = (o + 0.5f) * (float)rh * (1.0f/16.0f) - 0.5f;
            sy = fminf(fmaxf(sy, 0.0f), (float)(rh - 1));
            int i0 = (int)floorf(sy); float t = sy - (float)i0;
            if (ly == i0)     cy += 1.0f - t;
            if (ly == i0 + 1) cy += t;
            float sx = (o + 0.5f) * (float)rw * (1.0f/16.0f) - 0.5f;
            sx = fminf(fmaxf(sx, 0.0f), (float)(rw - 1));
            int j0 = (int)floorf(sx); float u = sx - (float)j0;
            if (lx == j0)     cx += 1.0f - u;
            if (lx == j0 + 1) cx += u;
        }
        w = (cy * (1.0f/16.0f)) * (cx * (1.0f/16.0f));
    }
    wl[tid] = w;
    __syncthreads();
    int e = chunk*256 + tid;
    float f = 0.0f;
    for (int iy = r0; iy < r1; ++iy)
        for (int ix = c0; ix < c1; ++ix) {
            int p = iy*16 + ix;
            f = fmaf(wl[p], tok[((size_t)(b*256 + p))*EMB_ + e], f);
        }
    feats[(size_t)(b*6 + box)*EMB_ + e] = f;
}

// head round 9, stage 2: fc + softmax from feats (96 blocks)
__global__ __launch_bounds__(256)
void head_logits_kernel(const float* __restrict__ feats, const float* __restrict__ fcw,
                        const float* __restrict__ fcb, float* __restrict__ scores) {
    int tid = threadIdx.x;
    const float* fr = feats + (size_t)blockIdx.x * EMB_;
    __shared__ float red[4];
    float lg[4];
    #pragma unroll
    for (int cc = 0; cc < 4; ++cc) {
        float part = 0.0f;
        for (int e = tid; e < EMB_; e += 256) part = fmaf(fr[e], fcw[e*4 + cc], part);
        #pragma unroll
        for (int off = 32; off; off >>= 1) part += __shfl_xor(part, off);
        __syncthreads();
        if ((tid & 63) == 0) red[tid>>6] = part;
        __syncthreads();
        lg[cc] = red[0]+red[1]+red[2]+red[3] + fcb[cc];
    }
    if (tid == 0) {
        float mx = fmaxf(fmaxf(lg[0],lg[1]), fmaxf(lg[2],lg[3]));
        float e0 = expf(lg[0]-mx), e1 = expf(lg[1]-mx), e2 = expf(lg[2]-mx), e3 = expf(lg[3]-mx);
        float inv = 1.0f/(e0+e1+e2+e3);
        float* out = scores + (size_t)blockIdx.x * 4;
        out[0] = e0*inv; out[1] = e1*inv; out[2] = e2*inv; out[3] = e3*inv;
    }
}

// ===========================================================================
extern "C" void kernel_launch(void* const* d_in, const int* in_sizes, int n_in,
                              void* d_out, int out_size, void* d_ws, size_t ws_size,
                              hipStream_t stream) {
    (void)in_sizes; (void)n_in; (void)out_size; (void)ws_size;
    const float* x       = (const float*)d_in[0];
    const float* lm      = (const float*)d_in[1];
    const float* stn_w1  = (const float*)d_in[2];
    const float* stn_b1  = (const float*)d_in[3];
    const float* stn_w2  = (const float*)d_in[4];
    const float* stn_b2  = (const float*)d_in[5];
    const float* conv_w  = (const float*)d_in[6];
    const float* conv_b  = (const float*)d_in[7];
    const float* pe_w    = (const float*)d_in[8];
    const float* pe_b    = (const float*)d_in[9];
    const float* pos     = (const float*)d_in[10];
    const float* ln1_g   = (const float*)d_in[11];
    const float* ln1_b   = (const float*)d_in[12];
    const float* qkv_w   = (const float*)d_in[13];
    const float* qkv_b   = (const float*)d_in[14];
    const float* proj_w  = (const float*)d_in[15];
    const float* proj_b  = (const float*)d_in[16];
    const float* ln2_g   = (const float*)d_in[17];
    const float* ln2_b   = (const float*)d_in[18];
    const float* mlp_w1  = (const float*)d_in[19];
    const float* mlp_b1  = (const float*)d_in[20];
    const float* mlp_w2  = (const float*)d_in[21];
    const float* mlp_b2  = (const float*)d_in[22];
    const float* fc_w    = (const float*)d_in[23];
    const float* fc_b    = (const float*)d_in[24];

    float* out    = (float*)d_out;
    float* scores = out;
    float* timg   = out + 384;
    float* tmask  = out + 384 + (size_t)B_*3*HH*WW;

    char* ws = (char*)d_ws;
    size_t off = 0;
    auto alloc = [&](size_t bytes) {
        off = (off + 255) & ~(size_t)255;
        void* p = ws + off; off += bytes; return p;
    };
    // slotBig: seg(fp32,16MB) -> hidden(bf16,24MB)
    char*   slotBig = (char*)alloc(25165824);
    // slotT: timg_bf(25.2MB) -> qkvb(18.9MB)
    char*   slotT   = (char*)alloc((size_t)B_*3*HH*WW*2);
    // slotC: featC(8.4MB) -> obuf(6.3MB)
    char*   slotC   = (char*)alloc((size_t)M_*NF_*2);
    float*  tok     = (float*)alloc((size_t)M_*EMB_*4);
    bf16_t* tbuf    = (bf16_t*)alloc((size_t)M_*EMB_*2);
    bf16_t* conv_wb = (bf16_t*)alloc((size_t)NF_*KCONV*2);
    bf16_t* pe_wb   = (bf16_t*)alloc((size_t)EMB_*NF_*2);
    bf16_t* qkv_wb  = (bf16_t*)alloc((size_t)3*EMB_*EMB_*2);
    bf16_t* proj_wb = (bf16_t*)alloc((size_t)EMB_*EMB_*2);
    bf16_t* mlp1_wb = (bf16_t*)alloc((size_t)4*EMB_*EMB_*2);
    bf16_t* mlp2_wb = (bf16_t*)alloc((size_t)EMB_*4*EMB_*2);
    float*  w1t     = (float*)alloc(50*1024*4);
    float*  pooled  = (float*)alloc(16384*4);
    float*  theta   = (float*)alloc(96*4);
    float*  feats   = (float*)alloc((size_t)B_*6*EMB_*4);

    float*  seg    = (float*)slotBig;
    bf16_t* hidden = (bf16_t*)slotBig;
    bf16_t* timgb  = (bf16_t*)slotT;
    bf16_t* qkvb   = (bf16_t*)slotT;
    bf16_t* featC  = (bf16_t*)slotC;
    bf16_t* obuf   = (bf16_t*)slotC;

    // weight conversions (independent of data path)
    convert_bf16_kernel<<<(NF_*KCONV)/8/256, 256, 0, stream>>>(conv_w, conv_wb);
    transpose_bf16_kernel<<<dim3(EMB_/32, NF_/32),    256, 0, stream>>>(pe_w,   pe_wb,   NF_,  EMB_);
    transpose_bf16_kernel<<<dim3(3*EMB_/32, EMB_/32), 256, 0, stream>>>(qkv_w,  qkv_wb,  EMB_, 3*EMB_);
    transpose_bf16_kernel<<<dim3(EMB_/32, EMB_/32),   256, 0, stream>>>(proj_w, proj_wb, EMB_, EMB_);
    transpose_bf16_kernel<<<dim3(4*EMB_/32, EMB_/32), 256, 0, stream>>>(mlp_w1, mlp1_wb, EMB_, 4*EMB_);
    transpose_bf16_kernel<<<dim3(EMB_/32, 4*EMB_/32), 256, 0, stream>>>(mlp_w2, mlp2_wb, 4*EMB_, EMB_);
    transpose_w1_kernel<<<200, 256, 0, stream>>>(stn_w1, w1t);

    // mask path
    hipMemsetAsync(seg, 0, (size_t)B_*HH*WW*sizeof(float), stream);
    raster_kernel<<<B_, 128, 0, stream>>>(lm, seg);
    pool_kernel<<<64, 256, 0, stream>>>(seg, pooled);
    stn2_kernel<<<B_, 1024, 0, stream>>>(pooled, w1t, stn_b1, stn_w2, stn_b2, theta);
    gridsample_kernel<<<(B_*HH*WW)/256, 256, 0, stream>>>(x, seg, theta, timg, tmask, timgb);

    // conv as implicit-im2col GEMM (64x64 tiles, 1024 blocks)
    gemm_conv64_kernel<<<(M_/64)*(NF_/64), 256, 0, stream>>>(
        timgb, conv_wb, conv_b, featC);

    // patch embed + pos -> tok (fp32 residual stream)   [768 blocks]
    gemm64_kernel<EPI_PE><<<(M_/64)*(EMB_/64), 256, 0, stream>>>(
        featC, pe_wb, pe_b, pos, tok, nullptr, M_, EMB_, NF_);

    // LN1 -> qkv   [2304 blocks]
    ln_kernel<<<M_, 256, 0, stream>>>(tok, ln1_g, ln1_b, tbuf);
    gemm64_kernel<EPI_QKV><<<(M_/64)*(3*EMB_/64), 256, 0, stream>>>(
        tbuf, qkv_wb, qkv_b, nullptr, nullptr, qkvb, M_, 3*EMB_, EMB_);

    // attention (MFMA)
    attn_kernel5<<<B_*HEADS_, 256, 0, stream>>>(qkvb, obuf);

    // proj + residual   [768 blocks]
    gemm64_kernel<EPI_PROJ><<<(M_/64)*(EMB_/64), 256, 0, stream>>>(
        obuf, proj_wb, proj_b, nullptr, tok, nullptr, M_, EMB_, EMB_);

    // LN2 -> mlp   [mlp1 3072 blocks; mlp2 768 blocks]
    ln_kernel<<<M_, 256, 0, stream>>>(tok, ln2_g, ln2_b, tbuf);
    gemm64_kernel<EPI_GELU><<<(M_/64)*(4*EMB_/64), 256, 0, stream>>>(
        tbuf, mlp1_wb, mlp_b1, nullptr, nullptr, hidden, M_, 4*EMB_, EMB_);
    gemm64_kernel<EPI_MLP2><<<(M_/64)*(EMB_/64), 256, 0, stream>>>(
        hidden, mlp2_wb, mlp_b2, nullptr, tok, nullptr, M_, EMB_, 4*EMB_);

    // head: feats (288 blocks, coalesced) + logits (96 blocks)
    head_feats_kernel<<<B_*6*3, 256, 0, stream>>>(tok, feats);
    head_logits_kernel<<<B_*6, 256, 0, stream>>>(feats, fc_w, fc_b, scores);
}